// Round 9
// baseline (449.393 us; speedup 1.0000x reference)
//
#include <hip/hip_runtime.h>
#include <hip/hip_bf16.h>
#include <float.h>

#define N_NODES 100000
#define N_EDGES 1600000
#define HIDDEN 64
#define N_GRAPHS 128
#define NEG_SLOPE 0.2f
#define ETOT (N_EDGES + N_NODES)

#define BSHIFT 10
#define NB ((N_NODES + 1023) >> BSHIFT)   // 98 buckets of 1024 nodes
#define PAIR_CHUNK 4096
#define PAIR_BLOCKS ((N_EDGES + PAIR_CHUNK - 1) / PAIR_CHUNK)  // 391

#define NREP 64           // pool accumulator replicas (atomic contention spreading)
#define REP_STRIDE 272    // 256 floats + 16 pad

__device__ __forceinline__ unsigned short f2bf(float f) {
    unsigned u = __float_as_uint(f);
    unsigned r = (u + 0x7FFFu + ((u >> 16) & 1u)) >> 16;  // RNE
    return (unsigned short)r;
}
__device__ __forceinline__ float blo(unsigned u) { return __uint_as_float(u << 16); }
__device__ __forceinline__ float bhi(unsigned u) { return __uint_as_float(u & 0xFFFF0000u); }

// ---------------- CSR build: per-chunk bucket counts (also zeroes pool_acc) ----------------

__global__ __launch_bounds__(256) void k_count(const int* __restrict__ e1,
                                               int* __restrict__ blockcnt,
                                               float* __restrict__ pool_acc) {
    __shared__ int h[NB];
    int t = threadIdx.x, b = blockIdx.x;
    if (t < NB) h[t] = 0;
    if (b < NREP && t < 2 * N_GRAPHS) pool_acc[b * REP_STRIDE + t] = 0.f;
    __syncthreads();
    int ebase = b * PAIR_CHUNK;
    int ecount = min(PAIR_CHUNK, N_EDGES - ebase);
    for (int i = t; i < ecount; i += 256)
        atomicAdd(&h[e1[ebase + i] >> BSHIFT], 1);
    __syncthreads();
    if (t < NB) blockcnt[b * NB + t] = h[t];
}

// one wave per bucket: exclusive scan over its chunk counts (in place) + total
__global__ __launch_bounds__(64) void k_scan_bases(int* __restrict__ blockcnt,
                                                   int* __restrict__ btot) {
    int b = blockIdx.x;
    int lane = threadIdx.x;
    int s = 0;
    for (int base = 0; base < PAIR_BLOCKS; base += 64) {
        int c = base + lane;
        int v = (c < PAIR_BLOCKS) ? blockcnt[c * NB + b] : 0;
        int xv = v;
#pragma unroll
        for (int off = 1; off < 64; off <<= 1) {
            int y = __shfl_up(xv, off);
            if (lane >= off) xv += y;
        }
        if (c < PAIR_BLOCKS) blockcnt[c * NB + b] = s + xv - v;
        s += __shfl(xv, 63);
    }
    if (lane == 0) btot[b] = s;
}

__global__ void k_scan_buckets(const int* __restrict__ btot, int* __restrict__ pair_start) {
    __shared__ int tot[128];
    int t = threadIdx.x;
    int v = (t < NB) ? btot[t] : 0;
    tot[t] = v;
    __syncthreads();
    for (int off = 1; off < 128; off <<= 1) {
        int u = (t >= off) ? tot[t - off] : 0;
        __syncthreads();
        tot[t] += u;
        __syncthreads();
    }
    if (t < NB) pair_start[t] = tot[t] - v;
    if (t == 0) pair_start[NB] = N_EDGES;
}

__global__ __launch_bounds__(256) void k_pair_scatter(
    const int* __restrict__ e0, const int* __restrict__ e1,
    const int* __restrict__ blockcnt, const int* __restrict__ pair_start,
    int* __restrict__ pairs)
{
    __shared__ int cnt[NB];
    __shared__ int base[NB];
    int t = threadIdx.x, b = blockIdx.x;
    if (t < NB) {
        cnt[t] = 0;
        base[t] = pair_start[t] + blockcnt[b * NB + t];
    }
    __syncthreads();
    int ebase = b * PAIR_CHUNK;
    int ecount = min(PAIR_CHUNK, N_EDGES - ebase);
    for (int i = t; i < ecount; i += 256) {
        int s = e0[ebase + i];
        int d = e1[ebase + i];
        int B = d >> BSHIFT;
        int idx = atomicAdd(&cnt[B], 1);
        pairs[base[B] + idx] = ((d & 1023) << 17) | s;   // 10b local dst | 17b src
    }
}

// One block per bucket: local degree histogram + wave-scan + col scatter in LDS.
// Self loop occupies slot 0 of each row.
__global__ __launch_bounds__(1024) void k_csr_bucket(
    const int* __restrict__ pairs, const int* __restrict__ pair_start,
    int* __restrict__ rowptr, int* __restrict__ col)
{
    __shared__ int deg[1024];
    __shared__ int excl[1024];
    __shared__ int wsum[16];
    int b = blockIdx.x;
    int t = threadIdx.x;
    int nb = b << BSHIFT;
    int nodes = min(1024, N_NODES - nb);

    deg[t] = (t < nodes) ? 1 : 0;   // self loop
    __syncthreads();
    int p0 = pair_start[b], p1 = pair_start[b + 1];
    for (int i = p0 + t; i < p1; i += 1024)
        atomicAdd(&deg[pairs[i] >> 17], 1);
    __syncthreads();

    int val = deg[t];
    int x = val;
#pragma unroll
    for (int off = 1; off < 64; off <<= 1) {
        int y = __shfl_up(x, off);
        if ((t & 63) >= off) x += y;
    }
    if ((t & 63) == 63) wsum[t >> 6] = x;
    __syncthreads();
    if (t == 0) {
        int s = 0;
#pragma unroll
        for (int i = 0; i < 16; ++i) { int v = wsum[i]; wsum[i] = s; s += v; }
    }
    __syncthreads();
    int ex = x - val + wsum[t >> 6];  // exclusive prefix of local degrees
    excl[t] = ex;

    int colbase = p0 + nb;  // nb == #self-loops in preceding buckets
    if (t < nodes) {
        rowptr[nb + t] = colbase + ex;
        col[colbase + ex] = nb + t;  // self loop at slot 0
    }
    if (b == NB - 1 && t == 0) rowptr[N_NODES] = ETOT;

    deg[t] = 1;  // slot 0 taken by self loop
    __syncthreads();
    for (int i = p0 + t; i < p1; i += 1024) {
        int p = pairs[i];
        int li = p >> 17;
        int pos = colbase + excl[li] + atomicAdd(&deg[li], 1);
        col[pos] = p & 0x1FFFF;
    }
}

// ---------------- layer-0 GEMM + attention scores (from embeddings) ----------------

__global__ __launch_bounds__(256) void k_gemm_score(
    const int* __restrict__ x, const float* __restrict__ embed,
    const float* __restrict__ W, const float* __restrict__ a_s,
    const float* __restrict__ a_d, unsigned short* __restrict__ hWb,
    float* __restrict__ s_src, float* __restrict__ s_dst)
{
    __shared__ float Wl[64 * 64];
    __shared__ float hT[64 * 68];  // [k][r], pitch 68
    int t = threadIdx.x;
    int r0 = blockIdx.x * 64;

    for (int i = t; i < 4096; i += 256) Wl[i] = W[i];
    for (int i = t; i < 4096; i += 256) {
        int r = i >> 6, k = i & 63;
        int row = r0 + r;
        float v = (row < N_NODES) ? embed[x[row] * 64 + k] : 0.f;
        hT[k * 68 + r] = v;
    }
    __syncthreads();

    int tcol = t & 15;
    int trow = t >> 4;
    float acc[4][4];
#pragma unroll
    for (int i = 0; i < 4; ++i)
#pragma unroll
        for (int j = 0; j < 4; ++j) acc[i][j] = 0.f;

    for (int k = 0; k < 64; ++k) {
        float4 va = *(const float4*)&hT[k * 68 + trow * 4];
        float4 vb = *(const float4*)&Wl[k * 64 + tcol * 4];
        float a[4] = {va.x, va.y, va.z, va.w};
        float bb[4] = {vb.x, vb.y, vb.z, vb.w};
#pragma unroll
        for (int i = 0; i < 4; ++i)
#pragma unroll
            for (int j = 0; j < 4; ++j) acc[i][j] = fmaf(a[i], bb[j], acc[i][j]);
    }

    float4 as4 = *(const float4*)&a_s[tcol * 4];
    float4 ad4 = *(const float4*)&a_d[tcol * 4];
    float asr[4] = {as4.x, as4.y, as4.z, as4.w};
    float adr[4] = {ad4.x, ad4.y, ad4.z, ad4.w};

#pragma unroll
    for (int i = 0; i < 4; ++i) {
        int row = r0 + trow * 4 + i;
        float ps = 0.f, pd = 0.f;
#pragma unroll
        for (int j = 0; j < 4; ++j) {
            ps = fmaf(acc[i][j], asr[j], ps);
            pd = fmaf(acc[i][j], adr[j], pd);
        }
#pragma unroll
        for (int off = 8; off >= 1; off >>= 1) {
            ps += __shfl_xor(ps, off);
            pd += __shfl_xor(pd, off);
        }
        if (row < N_NODES) {
            ushort4 o;
            o.x = f2bf(acc[i][0]); o.y = f2bf(acc[i][1]);
            o.z = f2bf(acc[i][2]); o.w = f2bf(acc[i][3]);
            *(ushort4*)&hWb[row * 64 + tcol * 4] = o;
            if (tcol == 0) { s_src[row] = ps; s_dst[row] = pd; }
        }
    }
}

// ---------------- fused agg + next-layer GEMM + next scores (layers 0,1) ----------------
// TWO nodes per wave (half-wave each, fast path deg<=32); persistent grid-stride blocks.
// W' staged bf16-packed in LDS (8 KB). Epilogue: each lane computes 2 output columns.

__global__ __launch_bounds__(256) void k_agg_fused(
    const unsigned short* __restrict__ hWb_in, const int* __restrict__ col,
    const int* __restrict__ rowptr, const float* __restrict__ s_src_in,
    const float* __restrict__ s_dst_in, const float* __restrict__ bias,
    const float* __restrict__ Wn, const float* __restrict__ a_s_n,
    const float* __restrict__ a_d_n, unsigned short* __restrict__ hWb_out,
    float* __restrict__ s_src_out, float* __restrict__ s_dst_out)
{
    __shared__ unsigned Wlp[64 * 32];   // bf16-packed W': Wlp[k*32+c] = (W[k][2c], W[k][2c+1])
    __shared__ float2 stash[4][64];     // (p, row byte-offset bits), 32 slots per half-wave
    __shared__ float oSt[4][2][64];     // per-wave per-node activation staging
    int t = threadIdx.x;
    for (int i = t; i < 2048; i += 256) {
        int k = i >> 5, c2 = i & 31;
        float2 w = *(const float2*)&Wn[k * 64 + 2 * c2];
        Wlp[i] = (unsigned)f2bf(w.x) | ((unsigned)f2bf(w.y) << 16);
    }
    __syncthreads();

    int wave = t >> 6, lane = t & 63;
    int h = lane >> 5, hl = lane & 31;
    const char* hb = (const char*)hWb_in;
    float2 as2 = ((const float2*)a_s_n)[hl];
    float2 ad2 = ((const float2*)a_d_n)[hl];

    for (int base = (blockIdx.x * 4 + wave) * 2; base < N_NODES; base += gridDim.x * 8) {
        int node = base + h;
        bool valid = (node < N_NODES);
        int row = 0, end = 0;
        if (valid) { row = rowptr[node]; end = rowptr[node + 1]; }
        int deg = end - row;
        int degOther = __shfl_xor(deg, 32);
        bool fast = (deg <= 32) && (degOther <= 32);   // wave-uniform

        if (fast) {
            float sdi = valid ? s_dst_in[node] : 0.f;
            int c = 0;
            float p = 0.f;
            if (hl < deg) {
                c = col[row + hl];
                float ee = s_src_in[c] + sdi;
                ee = (ee >= 0.f) ? ee : NEG_SLOPE * ee;
                p = __expf(ee);   // no max-sub: |e| small, fp32-safe
            }
            stash[wave][h * 32 + hl] = make_float2(p, __int_as_float(c * 128));

            int q = hl >> 4, f = hl & 15, f8 = f * 8;
            int sb = h * 32;
            float a0 = 0.f, a1 = 0.f, a2 = 0.f, a3 = 0.f;
            int degr = (deg + 7) & ~7;
            for (int j = q; j < degr; j += 8) {
                float2 e0 = stash[wave][sb + j];
                float2 e1 = stash[wave][sb + j + 2];
                float2 e2 = stash[wave][sb + j + 4];
                float2 e3 = stash[wave][sb + j + 6];
                uint2 v0 = *(const uint2*)(hb + (__float_as_int(e0.y) + f8));
                uint2 v1 = *(const uint2*)(hb + (__float_as_int(e1.y) + f8));
                uint2 v2 = *(const uint2*)(hb + (__float_as_int(e2.y) + f8));
                uint2 v3 = *(const uint2*)(hb + (__float_as_int(e3.y) + f8));
                a0 = fmaf(e0.x, blo(v0.x), a0); a1 = fmaf(e0.x, bhi(v0.x), a1);
                a2 = fmaf(e0.x, blo(v0.y), a2); a3 = fmaf(e0.x, bhi(v0.y), a3);
                a0 = fmaf(e1.x, blo(v1.x), a0); a1 = fmaf(e1.x, bhi(v1.x), a1);
                a2 = fmaf(e1.x, blo(v1.y), a2); a3 = fmaf(e1.x, bhi(v1.y), a3);
                a0 = fmaf(e2.x, blo(v2.x), a0); a1 = fmaf(e2.x, bhi(v2.x), a1);
                a2 = fmaf(e2.x, blo(v2.y), a2); a3 = fmaf(e2.x, bhi(v2.y), a3);
                a0 = fmaf(e3.x, blo(v3.x), a0); a1 = fmaf(e3.x, bhi(v3.x), a1);
                a2 = fmaf(e3.x, blo(v3.y), a2); a3 = fmaf(e3.x, bhi(v3.y), a3);
            }
            float denom = p;
#pragma unroll
            for (int off = 16; off >= 1; off >>= 1) denom += __shfl_xor(denom, off);
            float inv = 1.f / denom;
            a0 += __shfl_xor(a0, 16);
            a1 += __shfl_xor(a1, 16);
            a2 += __shfl_xor(a2, 16);
            a3 += __shfl_xor(a3, 16);
            if (hl < 16) {
                float4 bb = *(const float4*)&bias[4 * f];
                float4 o4;
                o4.x = fmaxf(fmaf(a0, inv, bb.x), 0.f);
                o4.y = fmaxf(fmaf(a1, inv, bb.y), 0.f);
                o4.z = fmaxf(fmaf(a2, inv, bb.z), 0.f);
                o4.w = fmaxf(fmaf(a3, inv, bb.w), 0.f);
                *(float4*)&oSt[wave][h][4 * f] = o4;
            }
        } else {
            // rare fallback: each node of the pair via full wave, generic path
            for (int s = 0; s < 2; ++s) {
                int nd = base + s;
                if (nd >= N_NODES) continue;
                int r0 = rowptr[nd], e0i = rowptr[nd + 1];
                float sdi = s_dst_in[nd];
                float m = -FLT_MAX;
                for (int j = r0 + lane; j < e0i; j += 64) {
                    float ee = s_src_in[col[j]] + sdi;
                    ee = (ee >= 0.f) ? ee : NEG_SLOPE * ee;
                    m = fmaxf(m, ee);
                }
#pragma unroll
                for (int off = 32; off >= 1; off >>= 1) m = fmaxf(m, __shfl_xor(m, off));
                float denom = 0.f;
                for (int j = r0 + lane; j < e0i; j += 64) {
                    float ee = s_src_in[col[j]] + sdi;
                    ee = (ee >= 0.f) ? ee : NEG_SLOPE * ee;
                    denom += __expf(ee - m);
                }
#pragma unroll
                for (int off = 32; off >= 1; off >>= 1) denom += __shfl_xor(denom, off);
                float inv = 1.f / denom;
                float acc = 0.f;
                for (int j = r0; j < e0i; ++j) {
                    int cc = col[j];
                    float ee = s_src_in[cc] + sdi;
                    ee = (ee >= 0.f) ? ee : NEG_SLOPE * ee;
                    acc = fmaf(__expf(ee - m) * inv, blo(hWb_in[cc * 64 + lane]), acc);
                }
                oSt[wave][s][lane] = fmaxf(acc + bias[lane], 0.f);
            }
        }

        // column GEMM: node h, columns 2*hl and 2*hl+1
        float r0 = 0.f, r1 = 0.f;
#pragma unroll
        for (int kq = 0; kq < 16; ++kq) {
            float4 o4 = *(const float4*)&oSt[wave][h][4 * kq];
            unsigned u0 = Wlp[(4 * kq + 0) * 32 + hl];
            unsigned u1 = Wlp[(4 * kq + 1) * 32 + hl];
            unsigned u2 = Wlp[(4 * kq + 2) * 32 + hl];
            unsigned u3 = Wlp[(4 * kq + 3) * 32 + hl];
            r0 = fmaf(o4.x, blo(u0), r0); r1 = fmaf(o4.x, bhi(u0), r1);
            r0 = fmaf(o4.y, blo(u1), r0); r1 = fmaf(o4.y, bhi(u1), r1);
            r0 = fmaf(o4.z, blo(u2), r0); r1 = fmaf(o4.z, bhi(u2), r1);
            r0 = fmaf(o4.w, blo(u3), r0); r1 = fmaf(o4.w, bhi(u3), r1);
        }
        float ss = r0 * as2.x + r1 * as2.y;
        float sd = r0 * ad2.x + r1 * ad2.y;
#pragma unroll
        for (int off = 16; off >= 1; off >>= 1) {
            ss += __shfl_xor(ss, off);
            sd += __shfl_xor(sd, off);
        }
        if (valid) {
            ((unsigned*)hWb_out)[node * 32 + hl] =
                (unsigned)f2bf(r0) | ((unsigned)f2bf(r1) << 16);
            if (hl == 0) { s_src_out[node] = ss; s_dst_out[node] = sd; }
        }
    }
}

// ---------------- last-layer agg + pool projection (two nodes per wave) ----------------

__global__ __launch_bounds__(256) void k_agg_pool(
    const unsigned short* __restrict__ hWb_in, const int* __restrict__ col,
    const int* __restrict__ rowptr, const float* __restrict__ s_src_in,
    const float* __restrict__ s_dst_in, const float* __restrict__ bias,
    const int* __restrict__ batch, const float* __restrict__ W_out,
    float* __restrict__ pool_acc)
{
    __shared__ float2 stash[4][64];
    int t = threadIdx.x;
    int wave = t >> 6, lane = t & 63;
    int h = lane >> 5, hl = lane & 31;
    int base = (blockIdx.x * 4 + wave) * 2;
    if (base >= N_NODES) return;
    int node = base + h;
    bool valid = (node < N_NODES);
    int row = 0, end = 0;
    if (valid) { row = rowptr[node]; end = rowptr[node + 1]; }
    int deg = end - row;
    int degOther = __shfl_xor(deg, 32);
    bool fast = (deg <= 32) && (degOther <= 32);
    float* rep = pool_acc + (blockIdx.x & (NREP - 1)) * REP_STRIDE;
    const char* hb = (const char*)hWb_in;

    if (fast) {
        float sdi = valid ? s_dst_in[node] : 0.f;
        int c = 0;
        float p = 0.f;
        if (hl < deg) {
            c = col[row + hl];
            float ee = s_src_in[c] + sdi;
            ee = (ee >= 0.f) ? ee : NEG_SLOPE * ee;
            p = __expf(ee);
        }
        stash[wave][h * 32 + hl] = make_float2(p, __int_as_float(c * 128));

        int q = hl >> 4, f = hl & 15, f8 = f * 8;
        int sb = h * 32;
        float a0 = 0.f, a1 = 0.f, a2 = 0.f, a3 = 0.f;
        int degr = (deg + 7) & ~7;
        for (int j = q; j < degr; j += 8) {
            float2 e0 = stash[wave][sb + j];
            float2 e1 = stash[wave][sb + j + 2];
            float2 e2 = stash[wave][sb + j + 4];
            float2 e3 = stash[wave][sb + j + 6];
            uint2 v0 = *(const uint2*)(hb + (__float_as_int(e0.y) + f8));
            uint2 v1 = *(const uint2*)(hb + (__float_as_int(e1.y) + f8));
            uint2 v2 = *(const uint2*)(hb + (__float_as_int(e2.y) + f8));
            uint2 v3 = *(const uint2*)(hb + (__float_as_int(e3.y) + f8));
            a0 = fmaf(e0.x, blo(v0.x), a0); a1 = fmaf(e0.x, bhi(v0.x), a1);
            a2 = fmaf(e0.x, blo(v0.y), a2); a3 = fmaf(e0.x, bhi(v0.y), a3);
            a0 = fmaf(e1.x, blo(v1.x), a0); a1 = fmaf(e1.x, bhi(v1.x), a1);
            a2 = fmaf(e1.x, blo(v1.y), a2); a3 = fmaf(e1.x, bhi(v1.y), a3);
            a0 = fmaf(e2.x, blo(v2.x), a0); a1 = fmaf(e2.x, bhi(v2.x), a1);
            a2 = fmaf(e2.x, blo(v2.y), a2); a3 = fmaf(e2.x, bhi(v2.y), a3);
            a0 = fmaf(e3.x, blo(v3.x), a0); a1 = fmaf(e3.x, bhi(v3.x), a1);
            a2 = fmaf(e3.x, blo(v3.y), a2); a3 = fmaf(e3.x, bhi(v3.y), a3);
        }
        float denom = p;
#pragma unroll
        for (int off = 16; off >= 1; off >>= 1) denom += __shfl_xor(denom, off);
        float inv = 1.f / denom;
        a0 += __shfl_xor(a0, 16);
        a1 += __shfl_xor(a1, 16);
        a2 += __shfl_xor(a2, 16);
        a3 += __shfl_xor(a3, 16);

        float p0 = 0.f, p1 = 0.f;
        if (hl < 16) {
            float4 bb = *(const float4*)&bias[4 * f];
            float o0 = fmaf(a0, inv, bb.x), o1 = fmaf(a1, inv, bb.y);
            float o2 = fmaf(a2, inv, bb.z), o3 = fmaf(a3, inv, bb.w);
            float4 wa = *(const float4*)&W_out[8 * f];
            float4 wb = *(const float4*)&W_out[8 * f + 4];
            p0 = o0 * wa.x + o1 * wa.z + o2 * wb.x + o3 * wb.z;
            p1 = o0 * wa.y + o1 * wa.w + o2 * wb.y + o3 * wb.w;
        }
#pragma unroll
        for (int off = 8; off >= 1; off >>= 1) {
            p0 += __shfl_xor(p0, off);
            p1 += __shfl_xor(p1, off);
        }
        if (valid && hl == 0) {
            int g = batch[node];
            atomicAdd(&rep[g * 2], p0);
            atomicAdd(&rep[g * 2 + 1], p1);
        }
    } else {
        for (int s = 0; s < 2; ++s) {
            int nd = base + s;
            if (nd >= N_NODES) continue;
            int r0i = rowptr[nd], e0i = rowptr[nd + 1];
            float sdi = s_dst_in[nd];
            float m = -FLT_MAX;
            for (int j = r0i + lane; j < e0i; j += 64) {
                float ee = s_src_in[col[j]] + sdi;
                ee = (ee >= 0.f) ? ee : NEG_SLOPE * ee;
                m = fmaxf(m, ee);
            }
#pragma unroll
            for (int off = 32; off >= 1; off >>= 1) m = fmaxf(m, __shfl_xor(m, off));
            float denom = 0.f;
            for (int j = r0i + lane; j < e0i; j += 64) {
                float ee = s_src_in[col[j]] + sdi;
                ee = (ee >= 0.f) ? ee : NEG_SLOPE * ee;
                denom += __expf(ee - m);
            }
#pragma unroll
            for (int off = 32; off >= 1; off >>= 1) denom += __shfl_xor(denom, off);
            float inv = 1.f / denom;
            float acc = 0.f;
            for (int j = r0i; j < e0i; ++j) {
                int cc = col[j];
                float ee = s_src_in[cc] + sdi;
                ee = (ee >= 0.f) ? ee : NEG_SLOPE * ee;
                acc = fmaf(__expf(ee - m) * inv, blo(hWb_in[cc * 64 + lane]), acc);
            }
            float o = acc + bias[lane];
            float p0 = o * W_out[lane * 2];
            float p1 = o * W_out[lane * 2 + 1];
#pragma unroll
            for (int off = 32; off >= 1; off >>= 1) {
                p0 += __shfl_xor(p0, off);
                p1 += __shfl_xor(p1, off);
            }
            if (lane == 0) {
                int g = batch[nd];
                atomicAdd(&rep[g * 2], p0);
                atomicAdd(&rep[g * 2 + 1], p1);
            }
        }
    }
}

// ---------------- head: reduce replicas, divide by count, add b_out ----------------

__device__ __forceinline__ int lower_bound_dev(const int* __restrict__ a, int n, int v) {
    int lo = 0, hi = n;
    while (lo < hi) {
        int mid = (lo + hi) >> 1;
        if (a[mid] < v) lo = mid + 1; else hi = mid;
    }
    return lo;
}

__global__ void k_head(const float* __restrict__ pool_acc,
                       const int* __restrict__ batch,
                       const float* __restrict__ b_out,
                       float* __restrict__ out)
{
    int t = threadIdx.x;
    if (t < 2 * N_GRAPHS) {
        float s = 0.f;
#pragma unroll 8
        for (int r = 0; r < NREP; ++r) s += pool_acc[r * REP_STRIDE + t];
        int g = t >> 1, c = t & 1;
        int start = lower_bound_dev(batch, N_NODES, g);
        int end = lower_bound_dev(batch, N_NODES, g + 1);
        float cnt = fmaxf((float)(end - start), 1.f);
        out[t] = s / cnt + b_out[c];
    }
}

// ---------------- launch ----------------

extern "C" void kernel_launch(void* const* d_in, const int* in_sizes, int n_in,
                              void* d_out, int out_size, void* d_ws, size_t ws_size,
                              hipStream_t stream) {
    const int*   x       = (const int*)d_in[0];
    const int*   edge    = (const int*)d_in[1];   // [2][E]
    const int*   batch   = (const int*)d_in[2];
    const float* embed   = (const float*)d_in[3];
    const float* Ws      = (const float*)d_in[4];
    const float* a_srcs  = (const float*)d_in[5];
    const float* a_dsts  = (const float*)d_in[6];
    const float* biases  = (const float*)d_in[7];
    const float* W_out   = (const float*)d_in[8];
    const float* b_out   = (const float*)d_in[9];
    float* out = (float*)d_out;

    char* ws = (char*)d_ws;
    size_t off = 0;
    auto alloc = [&](size_t bytes) -> void* {
        void* p = ws + off;
        off += (bytes + 255) & ~(size_t)255;
        return p;
    };
    unsigned short* hA     = (unsigned short*)alloc((size_t)N_NODES * 64 * sizeof(unsigned short));
    unsigned short* hB     = (unsigned short*)alloc((size_t)N_NODES * 64 * sizeof(unsigned short));
    float* s_src0   = (float*)alloc((size_t)N_NODES * sizeof(float));
    float* s_dst0   = (float*)alloc((size_t)N_NODES * sizeof(float));
    float* s_src1   = (float*)alloc((size_t)N_NODES * sizeof(float));
    float* s_dst1   = (float*)alloc((size_t)N_NODES * sizeof(float));
    int*   rowptr   = (int*)alloc((size_t)(N_NODES + 1) * sizeof(int));
    int*   colA     = (int*)alloc((size_t)ETOT * sizeof(int));
    int*   blockcnt = (int*)alloc((size_t)PAIR_BLOCKS * NB * sizeof(int));
    int*   btot     = (int*)alloc((size_t)NB * sizeof(int));
    int*   pstart   = (int*)alloc((size_t)(NB + 1) * sizeof(int));
    float* pool_acc = (float*)alloc((size_t)(NREP * REP_STRIDE) * sizeof(float));
    int*   pairs    = (int*)alloc((size_t)N_EDGES * sizeof(int));  // dead after CSR build

    const int* e0 = edge;
    const int* e1 = edge + N_EDGES;

    // bucketed CSR build (by dst, self loops at slot 0 of each row)
    k_count<<<PAIR_BLOCKS, 256, 0, stream>>>(e1, blockcnt, pool_acc);
    k_scan_bases<<<NB, 64, 0, stream>>>(blockcnt, btot);
    k_scan_buckets<<<1, 128, 0, stream>>>(btot, pstart);
    k_pair_scatter<<<PAIR_BLOCKS, 256, 0, stream>>>(e0, e1, blockcnt, pstart, pairs);
    k_csr_bucket<<<NB, 1024, 0, stream>>>(pairs, pstart, rowptr, colA);

    const int gemm_blocks = (N_NODES + 63) / 64;
    // layer 0 GEMM from embeddings
    k_gemm_score<<<gemm_blocks, 256, 0, stream>>>(
        x, embed, Ws, a_srcs, a_dsts, hA, s_src0, s_dst0);
    // layer 0 agg fused with layer-1 GEMM+scores
    k_agg_fused<<<2048, 256, 0, stream>>>(
        hA, colA, rowptr, s_src0, s_dst0, biases,
        Ws + 4096, a_srcs + 64, a_dsts + 64, hB, s_src1, s_dst1);
    // layer 1 agg fused with layer-2 GEMM+scores
    k_agg_fused<<<2048, 256, 0, stream>>>(
        hB, colA, rowptr, s_src1, s_dst1, biases + 64,
        Ws + 8192, a_srcs + 128, a_dsts + 128, hA, s_src0, s_dst0);
    // layer 2 agg + pool projection (2 nodes per wave -> 8 nodes per block)
    k_agg_pool<<<(N_NODES + 7) / 8, 256, 0, stream>>>(
        hA, colA, rowptr, s_src0, s_dst0, biases + 128, batch, W_out, pool_acc);
    k_head<<<1, 256, 0, stream>>>(pool_acc, batch, b_out, out);
}

// Round 10
// 368.494 us; speedup vs baseline: 1.2195x; 1.2195x over previous
//
#include <hip/hip_runtime.h>
#include <hip/hip_bf16.h>
#include <float.h>

#define N_NODES 100000
#define N_EDGES 1600000
#define HIDDEN 64
#define N_GRAPHS 128
#define NEG_SLOPE 0.2f
#define ETOT (N_EDGES + N_NODES)

#define BSHIFT 10
#define NB ((N_NODES + 1023) >> BSHIFT)   // 98 buckets of 1024 nodes
#define PAIR_CHUNK 4096
#define PAIR_BLOCKS ((N_EDGES + PAIR_CHUNK - 1) / PAIR_CHUNK)  // 391

#define NREP 64           // pool accumulator replicas (atomic contention spreading)
#define REP_STRIDE 272    // 256 floats + 16 pad

__device__ __forceinline__ float blo(unsigned u) { return __uint_as_float(u << 16); }
__device__ __forceinline__ float bhi(unsigned u) { return __uint_as_float(u & 0xFFFF0000u); }
__device__ __forceinline__ int sb0(unsigned u) { return (int)((unsigned)(u << 24)) >> 24; }
__device__ __forceinline__ int sb1(unsigned u) { return (int)((unsigned)(u << 16)) >> 24; }
__device__ __forceinline__ int sb2(unsigned u) { return (int)((unsigned)(u << 8)) >> 24; }
__device__ __forceinline__ int sb3(unsigned u) { return (int)u >> 24; }

// ---------------- CSR build: per-chunk bucket counts (also zeroes pool_acc) ----------------

__global__ __launch_bounds__(256) void k_count(const int* __restrict__ e1,
                                               int* __restrict__ blockcnt,
                                               float* __restrict__ pool_acc) {
    __shared__ int h[NB];
    int t = threadIdx.x, b = blockIdx.x;
    if (t < NB) h[t] = 0;
    if (b < NREP && t < 2 * N_GRAPHS) pool_acc[b * REP_STRIDE + t] = 0.f;
    __syncthreads();
    int ebase = b * PAIR_CHUNK;
    int ecount = min(PAIR_CHUNK, N_EDGES - ebase);
    for (int i = t; i < ecount; i += 256)
        atomicAdd(&h[e1[ebase + i] >> BSHIFT], 1);
    __syncthreads();
    if (t < NB) blockcnt[b * NB + t] = h[t];
}

// one wave per bucket: exclusive scan over its chunk counts (in place) + total
__global__ __launch_bounds__(64) void k_scan_bases(int* __restrict__ blockcnt,
                                                   int* __restrict__ btot) {
    int b = blockIdx.x;
    int lane = threadIdx.x;
    int s = 0;
    for (int base = 0; base < PAIR_BLOCKS; base += 64) {
        int c = base + lane;
        int v = (c < PAIR_BLOCKS) ? blockcnt[c * NB + b] : 0;
        int xv = v;
#pragma unroll
        for (int off = 1; off < 64; off <<= 1) {
            int y = __shfl_up(xv, off);
            if (lane >= off) xv += y;
        }
        if (c < PAIR_BLOCKS) blockcnt[c * NB + b] = s + xv - v;
        s += __shfl(xv, 63);
    }
    if (lane == 0) btot[b] = s;
}

__global__ void k_scan_buckets(const int* __restrict__ btot, int* __restrict__ pair_start) {
    __shared__ int tot[128];
    int t = threadIdx.x;
    int v = (t < NB) ? btot[t] : 0;
    tot[t] = v;
    __syncthreads();
    for (int off = 1; off < 128; off <<= 1) {
        int u = (t >= off) ? tot[t - off] : 0;
        __syncthreads();
        tot[t] += u;
        __syncthreads();
    }
    if (t < NB) pair_start[t] = tot[t] - v;
    if (t == 0) pair_start[NB] = N_EDGES;
}

__global__ __launch_bounds__(256) void k_pair_scatter(
    const int* __restrict__ e0, const int* __restrict__ e1,
    const int* __restrict__ blockcnt, const int* __restrict__ pair_start,
    int* __restrict__ pairs)
{
    __shared__ int cnt[NB];
    __shared__ int base[NB];
    int t = threadIdx.x, b = blockIdx.x;
    if (t < NB) {
        cnt[t] = 0;
        base[t] = pair_start[t] + blockcnt[b * NB + t];
    }
    __syncthreads();
    int ebase = b * PAIR_CHUNK;
    int ecount = min(PAIR_CHUNK, N_EDGES - ebase);
    for (int i = t; i < ecount; i += 256) {
        int s = e0[ebase + i];
        int d = e1[ebase + i];
        int B = d >> BSHIFT;
        int idx = atomicAdd(&cnt[B], 1);
        pairs[base[B] + idx] = ((d & 1023) << 17) | s;   // 10b local dst | 17b src
    }
}

// One block per bucket: local degree histogram + wave-scan + col scatter in LDS.
// Self loop occupies slot 0 of each row.
__global__ __launch_bounds__(1024) void k_csr_bucket(
    const int* __restrict__ pairs, const int* __restrict__ pair_start,
    int* __restrict__ rowptr, int* __restrict__ col)
{
    __shared__ int deg[1024];
    __shared__ int excl[1024];
    __shared__ int wsum[16];
    int b = blockIdx.x;
    int t = threadIdx.x;
    int nb = b << BSHIFT;
    int nodes = min(1024, N_NODES - nb);

    deg[t] = (t < nodes) ? 1 : 0;   // self loop
    __syncthreads();
    int p0 = pair_start[b], p1 = pair_start[b + 1];
    for (int i = p0 + t; i < p1; i += 1024)
        atomicAdd(&deg[pairs[i] >> 17], 1);
    __syncthreads();

    int val = deg[t];
    int x = val;
#pragma unroll
    for (int off = 1; off < 64; off <<= 1) {
        int y = __shfl_up(x, off);
        if ((t & 63) >= off) x += y;
    }
    if ((t & 63) == 63) wsum[t >> 6] = x;
    __syncthreads();
    if (t == 0) {
        int s = 0;
#pragma unroll
        for (int i = 0; i < 16; ++i) { int v = wsum[i]; wsum[i] = s; s += v; }
    }
    __syncthreads();
    int ex = x - val + wsum[t >> 6];  // exclusive prefix of local degrees
    excl[t] = ex;

    int colbase = p0 + nb;  // nb == #self-loops in preceding buckets
    if (t < nodes) {
        rowptr[nb + t] = colbase + ex;
        col[colbase + ex] = nb + t;  // self loop at slot 0
    }
    if (b == NB - 1 && t == 0) rowptr[N_NODES] = ETOT;

    deg[t] = 1;  // slot 0 taken by self loop
    __syncthreads();
    for (int i = p0 + t; i < p1; i += 1024) {
        int p = pairs[i];
        int li = p >> 17;
        int pos = colbase + excl[li] + atomicAdd(&deg[li], 1);
        col[pos] = p & 0x1FFFF;
    }
}

// ---------------- layer-0 GEMM + attention scores (from embeddings) ----------------
// Emits q8 (int8, per-row scale scl) + fp32 scores.

__global__ __launch_bounds__(256) void k_gemm_score(
    const int* __restrict__ x, const float* __restrict__ embed,
    const float* __restrict__ W, const float* __restrict__ a_s,
    const float* __restrict__ a_d, unsigned char* __restrict__ q8,
    float* __restrict__ scl, float* __restrict__ s_src, float* __restrict__ s_dst)
{
    __shared__ float Wl[64 * 64];
    __shared__ float hT[64 * 68];  // [k][r], pitch 68
    int t = threadIdx.x;
    int r0 = blockIdx.x * 64;

    for (int i = t; i < 4096; i += 256) Wl[i] = W[i];
    for (int i = t; i < 4096; i += 256) {
        int r = i >> 6, k = i & 63;
        int row = r0 + r;
        float v = (row < N_NODES) ? embed[x[row] * 64 + k] : 0.f;
        hT[k * 68 + r] = v;
    }
    __syncthreads();

    int tcol = t & 15;
    int trow = t >> 4;
    float acc[4][4];
#pragma unroll
    for (int i = 0; i < 4; ++i)
#pragma unroll
        for (int j = 0; j < 4; ++j) acc[i][j] = 0.f;

    for (int k = 0; k < 64; ++k) {
        float4 va = *(const float4*)&hT[k * 68 + trow * 4];
        float4 vb = *(const float4*)&Wl[k * 64 + tcol * 4];
        float a[4] = {va.x, va.y, va.z, va.w};
        float bb[4] = {vb.x, vb.y, vb.z, vb.w};
#pragma unroll
        for (int i = 0; i < 4; ++i)
#pragma unroll
            for (int j = 0; j < 4; ++j) acc[i][j] = fmaf(a[i], bb[j], acc[i][j]);
    }

    float4 as4 = *(const float4*)&a_s[tcol * 4];
    float4 ad4 = *(const float4*)&a_d[tcol * 4];
    float asr[4] = {as4.x, as4.y, as4.z, as4.w};
    float adr[4] = {ad4.x, ad4.y, ad4.z, ad4.w};

#pragma unroll
    for (int i = 0; i < 4; ++i) {
        int row = r0 + trow * 4 + i;
        float ps = 0.f, pd = 0.f;
#pragma unroll
        for (int j = 0; j < 4; ++j) {
            ps = fmaf(acc[i][j], asr[j], ps);
            pd = fmaf(acc[i][j], adr[j], pd);
        }
#pragma unroll
        for (int off = 8; off >= 1; off >>= 1) {
            ps += __shfl_xor(ps, off);
            pd += __shfl_xor(pd, off);
        }
        // per-row amax across 16 lanes
        float am = fmaxf(fmaxf(fabsf(acc[i][0]), fabsf(acc[i][1])),
                         fmaxf(fabsf(acc[i][2]), fabsf(acc[i][3])));
#pragma unroll
        for (int off = 8; off >= 1; off >>= 1) am = fmaxf(am, __shfl_xor(am, off));
        float iscl = (am > 0.f) ? 127.f / am : 0.f;
        if (row < N_NODES) {
            int q0 = __float2int_rn(acc[i][0] * iscl);
            int q1 = __float2int_rn(acc[i][1] * iscl);
            int q2 = __float2int_rn(acc[i][2] * iscl);
            int q3 = __float2int_rn(acc[i][3] * iscl);
            unsigned pk = (q0 & 255) | ((q1 & 255) << 8) | ((q2 & 255) << 16)
                        | ((q3 & 255) << 24);
            ((unsigned*)q8)[row * 16 + tcol] = pk;
            if (tcol == 0) {
                scl[row] = am * (1.f / 127.f);
                s_src[row] = ps; s_dst[row] = pd;
            }
        }
    }
}

// ---------------- fused agg + next-layer GEMM + next scores (layers 0,1) ----------------
// One node per wave; persistent grid-stride blocks; W' staged fp32 in LDS.
// Gather: 16 lanes/edge x uint = 64-B int8 row (one cache line); scale folded into alpha.

__global__ __launch_bounds__(256) void k_agg_fused(
    const unsigned char* __restrict__ q8_in, const float* __restrict__ scl_in,
    const int* __restrict__ col, const int* __restrict__ rowptr,
    const float* __restrict__ s_src_in, const float* __restrict__ s_dst_in,
    const float* __restrict__ bias, const float* __restrict__ Wn,
    const float* __restrict__ a_s_n, const float* __restrict__ a_d_n,
    unsigned char* __restrict__ q8_out, float* __restrict__ scl_out,
    float* __restrict__ s_src_out, float* __restrict__ s_dst_out)
{
    __shared__ float Wl[64 * 64];    // next-layer weight (fp32)
    __shared__ float2 stash[4][64];  // (p*scl, row byte-offset bits)
    __shared__ float oSt[4][64];     // per-wave activation staging
    int t = threadIdx.x;
    for (int i = t; i < 4096; i += 256) Wl[i] = Wn[i];
    __syncthreads();

    int wave = t >> 6, lane = t & 63;
    const char* hb = (const char*)q8_in;
    float asl = a_s_n[lane], adl = a_d_n[lane];

    for (int node = blockIdx.x * 4 + wave; node < N_NODES; node += gridDim.x * 4) {
        int row = rowptr[node];
        int end = rowptr[node + 1];
        int deg = end - row;
        float sdi = s_dst_in[node];

        if (deg <= 64) {
            int c = 0;
            float p = 0.f, sc = 0.f;
            if (lane < deg) {
                c = col[row + lane];
                float ee = s_src_in[c] + sdi;
                ee = (ee >= 0.f) ? ee : NEG_SLOPE * ee;
                p = __expf(ee);   // no max-sub: |e| small, fp32-safe
                sc = scl_in[c];
            }
            stash[wave][lane] = make_float2(p * sc, __int_as_float(c * 64));

            int q = lane >> 4;
            int f = lane & 15;
            int f4 = f * 4;
            float a0 = 0.f, a1 = 0.f, a2 = 0.f, a3 = 0.f;
            int degr = (deg + 15) & ~15;
            for (int j = q; j < degr; j += 16) {
                float2 e0 = stash[wave][j];
                float2 e1 = stash[wave][j + 4];
                float2 e2 = stash[wave][j + 8];
                float2 e3 = stash[wave][j + 12];
                unsigned v0 = *(const unsigned*)(hb + (__float_as_int(e0.y) + f4));
                unsigned v1 = *(const unsigned*)(hb + (__float_as_int(e1.y) + f4));
                unsigned v2 = *(const unsigned*)(hb + (__float_as_int(e2.y) + f4));
                unsigned v3 = *(const unsigned*)(hb + (__float_as_int(e3.y) + f4));
                a0 = fmaf(e0.x, (float)sb0(v0), a0);
                a1 = fmaf(e0.x, (float)sb1(v0), a1);
                a2 = fmaf(e0.x, (float)sb2(v0), a2);
                a3 = fmaf(e0.x, (float)sb3(v0), a3);
                a0 = fmaf(e1.x, (float)sb0(v1), a0);
                a1 = fmaf(e1.x, (float)sb1(v1), a1);
                a2 = fmaf(e1.x, (float)sb2(v1), a2);
                a3 = fmaf(e1.x, (float)sb3(v1), a3);
                a0 = fmaf(e2.x, (float)sb0(v2), a0);
                a1 = fmaf(e2.x, (float)sb1(v2), a1);
                a2 = fmaf(e2.x, (float)sb2(v2), a2);
                a3 = fmaf(e2.x, (float)sb3(v2), a3);
                a0 = fmaf(e3.x, (float)sb0(v3), a0);
                a1 = fmaf(e3.x, (float)sb1(v3), a1);
                a2 = fmaf(e3.x, (float)sb2(v3), a2);
                a3 = fmaf(e3.x, (float)sb3(v3), a3);
            }
            float denom = p;
#pragma unroll
            for (int off = 32; off >= 1; off >>= 1) denom += __shfl_xor(denom, off);
            float inv = 1.f / denom;
            a0 += __shfl_xor(a0, 16); a0 += __shfl_xor(a0, 32);
            a1 += __shfl_xor(a1, 16); a1 += __shfl_xor(a1, 32);
            a2 += __shfl_xor(a2, 16); a2 += __shfl_xor(a2, 32);
            a3 += __shfl_xor(a3, 16); a3 += __shfl_xor(a3, 32);
            if (lane < 16) {
                float4 bb = *(const float4*)&bias[4 * f];
                float4 o4;
                o4.x = fmaxf(fmaf(a0, inv, bb.x), 0.f);
                o4.y = fmaxf(fmaf(a1, inv, bb.y), 0.f);
                o4.z = fmaxf(fmaf(a2, inv, bb.z), 0.f);
                o4.w = fmaxf(fmaf(a3, inv, bb.w), 0.f);
                *(float4*)&oSt[wave][4 * f] = o4;
            }
        } else {
            // generic path (deg > 64): statistically never hit
            float m = -FLT_MAX;
            for (int j = row + lane; j < end; j += 64) {
                float ee = s_src_in[col[j]] + sdi;
                ee = (ee >= 0.f) ? ee : NEG_SLOPE * ee;
                m = fmaxf(m, ee);
            }
#pragma unroll
            for (int off = 32; off >= 1; off >>= 1) m = fmaxf(m, __shfl_xor(m, off));
            float denom = 0.f;
            for (int j = row + lane; j < end; j += 64) {
                float ee = s_src_in[col[j]] + sdi;
                ee = (ee >= 0.f) ? ee : NEG_SLOPE * ee;
                denom += __expf(ee - m);
            }
#pragma unroll
            for (int off = 32; off >= 1; off >>= 1) denom += __shfl_xor(denom, off);
            float inv = 1.f / denom;
            float acc = 0.f;
            for (int j = row; j < end; ++j) {
                int cc = col[j];
                float ee = s_src_in[cc] + sdi;
                ee = (ee >= 0.f) ? ee : NEG_SLOPE * ee;
                float v = (float)((int)(signed char)q8_in[cc * 64 + lane]) * scl_in[cc];
                acc = fmaf(__expf(ee - m) * inv, v, acc);
            }
            oSt[wave][lane] = fmaxf(acc + bias[lane], 0.f);
        }

        // column GEMM: r = o @ Wn (this lane's column = lane)
        float r = 0.f;
#pragma unroll
        for (int qq = 0; qq < 16; ++qq) {
            float4 o4 = *(const float4*)&oSt[wave][4 * qq];
            r = fmaf(o4.x, Wl[(4 * qq + 0) * 64 + lane], r);
            r = fmaf(o4.y, Wl[(4 * qq + 1) * 64 + lane], r);
            r = fmaf(o4.z, Wl[(4 * qq + 2) * 64 + lane], r);
            r = fmaf(o4.w, Wl[(4 * qq + 3) * 64 + lane], r);
        }
        float ss = r * asl, sd = r * adl;
        float am = fabsf(r);
#pragma unroll
        for (int off = 32; off >= 1; off >>= 1) {
            ss += __shfl_xor(ss, off);
            sd += __shfl_xor(sd, off);
            am = fmaxf(am, __shfl_xor(am, off));
        }
        float iscl = (am > 0.f) ? 127.f / am : 0.f;
        int qv = __float2int_rn(r * iscl);
        q8_out[node * 64 + lane] = (unsigned char)qv;
        if (lane == 0) {
            scl_out[node] = am * (1.f / 127.f);
            s_src_out[node] = ss; s_dst_out[node] = sd;
        }
    }
}

// ---------------- last-layer agg + pool projection (one node per wave) ----------------

__global__ __launch_bounds__(256) void k_agg_pool(
    const unsigned char* __restrict__ q8_in, const float* __restrict__ scl_in,
    const int* __restrict__ col, const int* __restrict__ rowptr,
    const float* __restrict__ s_src_in, const float* __restrict__ s_dst_in,
    const float* __restrict__ bias, const int* __restrict__ batch,
    const float* __restrict__ W_out, float* __restrict__ pool_acc)
{
    __shared__ float2 stash[4][64];
    int wave = threadIdx.x >> 6;
    int lane = threadIdx.x & 63;
    int node = blockIdx.x * 4 + wave;
    if (node >= N_NODES) return;

    int row = rowptr[node];
    int end = rowptr[node + 1];
    int deg = end - row;
    float sdi = s_dst_in[node];
    float* rep = pool_acc + (blockIdx.x & (NREP - 1)) * REP_STRIDE;
    const char* hb = (const char*)q8_in;

    if (deg <= 64) {
        int c = 0;
        float p = 0.f, sc = 0.f;
        if (lane < deg) {
            c = col[row + lane];
            float ee = s_src_in[c] + sdi;
            ee = (ee >= 0.f) ? ee : NEG_SLOPE * ee;
            p = __expf(ee);
            sc = scl_in[c];
        }
        stash[wave][lane] = make_float2(p * sc, __int_as_float(c * 64));

        int q = lane >> 4;
        int f = lane & 15;
        int f4 = f * 4;
        float a0 = 0.f, a1 = 0.f, a2 = 0.f, a3 = 0.f;
        int degr = (deg + 15) & ~15;
        for (int j = q; j < degr; j += 16) {
            float2 e0 = stash[wave][j];
            float2 e1 = stash[wave][j + 4];
            float2 e2 = stash[wave][j + 8];
            float2 e3 = stash[wave][j + 12];
            unsigned v0 = *(const unsigned*)(hb + (__float_as_int(e0.y) + f4));
            unsigned v1 = *(const unsigned*)(hb + (__float_as_int(e1.y) + f4));
            unsigned v2 = *(const unsigned*)(hb + (__float_as_int(e2.y) + f4));
            unsigned v3 = *(const unsigned*)(hb + (__float_as_int(e3.y) + f4));
            a0 = fmaf(e0.x, (float)sb0(v0), a0);
            a1 = fmaf(e0.x, (float)sb1(v0), a1);
            a2 = fmaf(e0.x, (float)sb2(v0), a2);
            a3 = fmaf(e0.x, (float)sb3(v0), a3);
            a0 = fmaf(e1.x, (float)sb0(v1), a0);
            a1 = fmaf(e1.x, (float)sb1(v1), a1);
            a2 = fmaf(e1.x, (float)sb2(v1), a2);
            a3 = fmaf(e1.x, (float)sb3(v1), a3);
            a0 = fmaf(e2.x, (float)sb0(v2), a0);
            a1 = fmaf(e2.x, (float)sb1(v2), a1);
            a2 = fmaf(e2.x, (float)sb2(v2), a2);
            a3 = fmaf(e2.x, (float)sb3(v2), a3);
            a0 = fmaf(e3.x, (float)sb0(v3), a0);
            a1 = fmaf(e3.x, (float)sb1(v3), a1);
            a2 = fmaf(e3.x, (float)sb2(v3), a2);
            a3 = fmaf(e3.x, (float)sb3(v3), a3);
        }
        float denom = p;
#pragma unroll
        for (int off = 32; off >= 1; off >>= 1) denom += __shfl_xor(denom, off);
        float inv = 1.f / denom;
        a0 += __shfl_xor(a0, 16); a0 += __shfl_xor(a0, 32);
        a1 += __shfl_xor(a1, 16); a1 += __shfl_xor(a1, 32);
        a2 += __shfl_xor(a2, 16); a2 += __shfl_xor(a2, 32);
        a3 += __shfl_xor(a3, 16); a3 += __shfl_xor(a3, 32);

        float p0 = 0.f, p1 = 0.f;
        if (lane < 16) {
            float4 bb = *(const float4*)&bias[4 * f];
            float o0 = fmaf(a0, inv, bb.x), o1 = fmaf(a1, inv, bb.y);
            float o2 = fmaf(a2, inv, bb.z), o3 = fmaf(a3, inv, bb.w);
            float4 wa = *(const float4*)&W_out[8 * f];      // rows 4f, 4f+1
            float4 wb = *(const float4*)&W_out[8 * f + 4];  // rows 4f+2, 4f+3
            p0 = o0 * wa.x + o1 * wa.z + o2 * wb.x + o3 * wb.z;
            p1 = o0 * wa.y + o1 * wa.w + o2 * wb.y + o3 * wb.w;
        }
#pragma unroll
        for (int off = 8; off >= 1; off >>= 1) {
            p0 += __shfl_xor(p0, off);
            p1 += __shfl_xor(p1, off);
        }
        if (lane == 0) {
            int g = batch[node];
            atomicAdd(&rep[g * 2], p0);
            atomicAdd(&rep[g * 2 + 1], p1);
        }
    } else {
        float m = -FLT_MAX;
        for (int j = row + lane; j < end; j += 64) {
            float ee = s_src_in[col[j]] + sdi;
            ee = (ee >= 0.f) ? ee : NEG_SLOPE * ee;
            m = fmaxf(m, ee);
        }
#pragma unroll
        for (int off = 32; off >= 1; off >>= 1) m = fmaxf(m, __shfl_xor(m, off));
        float denom = 0.f;
        for (int j = row + lane; j < end; j += 64) {
            float ee = s_src_in[col[j]] + sdi;
            ee = (ee >= 0.f) ? ee : NEG_SLOPE * ee;
            denom += __expf(ee - m);
        }
#pragma unroll
        for (int off = 32; off >= 1; off >>= 1) denom += __shfl_xor(denom, off);
        float inv = 1.f / denom;
        float acc = 0.f;
        for (int j = row; j < end; ++j) {
            int cc = col[j];
            float ee = s_src_in[cc] + sdi;
            ee = (ee >= 0.f) ? ee : NEG_SLOPE * ee;
            float v = (float)((int)(signed char)q8_in[cc * 64 + lane]) * scl_in[cc];
            acc = fmaf(__expf(ee - m) * inv, v, acc);
        }
        float o = acc + bias[lane];
        float p0 = o * W_out[lane * 2];
        float p1 = o * W_out[lane * 2 + 1];
#pragma unroll
        for (int off = 32; off >= 1; off >>= 1) {
            p0 += __shfl_xor(p0, off);
            p1 += __shfl_xor(p1, off);
        }
        if (lane == 0) {
            int g = batch[node];
            atomicAdd(&rep[g * 2], p0);
            atomicAdd(&rep[g * 2 + 1], p1);
        }
    }
}

// ---------------- head: reduce replicas, divide by count, add b_out ----------------

__device__ __forceinline__ int lower_bound_dev(const int* __restrict__ a, int n, int v) {
    int lo = 0, hi = n;
    while (lo < hi) {
        int mid = (lo + hi) >> 1;
        if (a[mid] < v) lo = mid + 1; else hi = mid;
    }
    return lo;
}

__global__ void k_head(const float* __restrict__ pool_acc,
                       const int* __restrict__ batch,
                       const float* __restrict__ b_out,
                       float* __restrict__ out)
{
    int t = threadIdx.x;
    if (t < 2 * N_GRAPHS) {
        float s = 0.f;
#pragma unroll 8
        for (int r = 0; r < NREP; ++r) s += pool_acc[r * REP_STRIDE + t];
        int g = t >> 1, c = t & 1;
        int start = lower_bound_dev(batch, N_NODES, g);
        int end = lower_bound_dev(batch, N_NODES, g + 1);
        float cnt = fmaxf((float)(end - start), 1.f);
        out[t] = s / cnt + b_out[c];
    }
}

// ---------------- launch ----------------

extern "C" void kernel_launch(void* const* d_in, const int* in_sizes, int n_in,
                              void* d_out, int out_size, void* d_ws, size_t ws_size,
                              hipStream_t stream) {
    const int*   x       = (const int*)d_in[0];
    const int*   edge    = (const int*)d_in[1];   // [2][E]
    const int*   batch   = (const int*)d_in[2];
    const float* embed   = (const float*)d_in[3];
    const float* Ws      = (const float*)d_in[4];
    const float* a_srcs  = (const float*)d_in[5];
    const float* a_dsts  = (const float*)d_in[6];
    const float* biases  = (const float*)d_in[7];
    const float* W_out   = (const float*)d_in[8];
    const float* b_out   = (const float*)d_in[9];
    float* out = (float*)d_out;

    char* ws = (char*)d_ws;
    size_t off = 0;
    auto alloc = [&](size_t bytes) -> void* {
        void* p = ws + off;
        off += (bytes + 255) & ~(size_t)255;
        return p;
    };
    unsigned char* qA   = (unsigned char*)alloc((size_t)N_NODES * 64);
    unsigned char* qB   = (unsigned char*)alloc((size_t)N_NODES * 64);
    float* sclA     = (float*)alloc((size_t)N_NODES * sizeof(float));
    float* sclB     = (float*)alloc((size_t)N_NODES * sizeof(float));
    float* s_src0   = (float*)alloc((size_t)N_NODES * sizeof(float));
    float* s_dst0   = (float*)alloc((size_t)N_NODES * sizeof(float));
    float* s_src1   = (float*)alloc((size_t)N_NODES * sizeof(float));
    float* s_dst1   = (float*)alloc((size_t)N_NODES * sizeof(float));
    int*   rowptr   = (int*)alloc((size_t)(N_NODES + 1) * sizeof(int));
    int*   colA     = (int*)alloc((size_t)ETOT * sizeof(int));
    int*   blockcnt = (int*)alloc((size_t)PAIR_BLOCKS * NB * sizeof(int));
    int*   btot     = (int*)alloc((size_t)NB * sizeof(int));
    int*   pstart   = (int*)alloc((size_t)(NB + 1) * sizeof(int));
    float* pool_acc = (float*)alloc((size_t)(NREP * REP_STRIDE) * sizeof(float));
    int*   pairs    = (int*)alloc((size_t)N_EDGES * sizeof(int));  // dead after CSR build

    const int* e0 = edge;
    const int* e1 = edge + N_EDGES;

    // bucketed CSR build (by dst, self loops at slot 0 of each row)
    k_count<<<PAIR_BLOCKS, 256, 0, stream>>>(e1, blockcnt, pool_acc);
    k_scan_bases<<<NB, 64, 0, stream>>>(blockcnt, btot);
    k_scan_buckets<<<1, 128, 0, stream>>>(btot, pstart);
    k_pair_scatter<<<PAIR_BLOCKS, 256, 0, stream>>>(e0, e1, blockcnt, pstart, pairs);
    k_csr_bucket<<<NB, 1024, 0, stream>>>(pairs, pstart, rowptr, colA);

    const int gemm_blocks = (N_NODES + 63) / 64;
    // layer 0 GEMM from embeddings -> int8 rows
    k_gemm_score<<<gemm_blocks, 256, 0, stream>>>(
        x, embed, Ws, a_srcs, a_dsts, qA, sclA, s_src0, s_dst0);
    // layer 0 agg fused with layer-1 GEMM+scores
    k_agg_fused<<<2048, 256, 0, stream>>>(
        qA, sclA, colA, rowptr, s_src0, s_dst0, biases,
        Ws + 4096, a_srcs + 64, a_dsts + 64, qB, sclB, s_src1, s_dst1);
    // layer 1 agg fused with layer-2 GEMM+scores
    k_agg_fused<<<2048, 256, 0, stream>>>(
        qB, sclB, colA, rowptr, s_src1, s_dst1, biases + 64,
        Ws + 8192, a_srcs + 128, a_dsts + 128, qA, sclA, s_src0, s_dst0);
    // layer 2 agg + pool projection
    k_agg_pool<<<(N_NODES + 3) / 4, 256, 0, stream>>>(
        qA, sclA, colA, rowptr, s_src0, s_dst0, biases + 128, batch, W_out, pool_acc);
    k_head<<<1, 256, 0, stream>>>(pool_acc, batch, b_out, out);
}

// Round 11
// 338.207 us; speedup vs baseline: 1.3288x; 1.0896x over previous
//
#include <hip/hip_runtime.h>
#include <hip/hip_bf16.h>
#include <float.h>

#define N_NODES 100000
#define N_EDGES 1600000
#define HIDDEN 64
#define N_GRAPHS 128
#define NEG_SLOPE 0.2f
#define ETOT (N_EDGES + N_NODES)

#define BSHIFT 9
#define NB ((N_NODES + 511) >> BSHIFT)    // 196 buckets of 512 nodes
#define PAIR_CHUNK 4096
#define PAIR_BLOCKS ((N_EDGES + PAIR_CHUNK - 1) / PAIR_CHUNK)  // 391

#define NREP 64           // pool accumulator replicas (atomic contention spreading)
#define REP_STRIDE 272    // 256 floats + 16 pad

__device__ __forceinline__ unsigned short f2bf(float f) {
    unsigned u = __float_as_uint(f);
    unsigned r = (u + 0x7FFFu + ((u >> 16) & 1u)) >> 16;  // RNE
    return (unsigned short)r;
}
__device__ __forceinline__ float blo(unsigned u) { return __uint_as_float(u << 16); }
__device__ __forceinline__ float bhi(unsigned u) { return __uint_as_float(u & 0xFFFF0000u); }
__device__ __forceinline__ int sb0(unsigned u) { return (int)((unsigned)(u << 24)) >> 24; }
__device__ __forceinline__ int sb1(unsigned u) { return (int)((unsigned)(u << 16)) >> 24; }
__device__ __forceinline__ int sb2(unsigned u) { return (int)((unsigned)(u << 8)) >> 24; }
__device__ __forceinline__ int sb3(unsigned u) { return (int)u >> 24; }

// ---------------- CSR build: per-chunk bucket counts (also zeroes pool_acc) ----------------

__global__ __launch_bounds__(256) void k_count(const int* __restrict__ e1,
                                               int* __restrict__ blockcnt,
                                               float* __restrict__ pool_acc) {
    __shared__ int h[NB];
    int t = threadIdx.x, b = blockIdx.x;
    if (t < NB) h[t] = 0;
    if (b < NREP && t < 2 * N_GRAPHS) pool_acc[b * REP_STRIDE + t] = 0.f;
    __syncthreads();
    int ebase = b * PAIR_CHUNK;
    int ecount = min(PAIR_CHUNK, N_EDGES - ebase);
    for (int i = t; i < ecount; i += 256)
        atomicAdd(&h[e1[ebase + i] >> BSHIFT], 1);
    __syncthreads();
    if (t < NB) blockcnt[b * NB + t] = h[t];
}

// one wave per bucket: exclusive scan over its chunk counts (in place) + total
__global__ __launch_bounds__(64) void k_scan_bases(int* __restrict__ blockcnt,
                                                   int* __restrict__ btot) {
    int b = blockIdx.x;
    int lane = threadIdx.x;
    int s = 0;
    for (int base = 0; base < PAIR_BLOCKS; base += 64) {
        int c = base + lane;
        int v = (c < PAIR_BLOCKS) ? blockcnt[c * NB + b] : 0;
        int xv = v;
#pragma unroll
        for (int off = 1; off < 64; off <<= 1) {
            int y = __shfl_up(xv, off);
            if (lane >= off) xv += y;
        }
        if (c < PAIR_BLOCKS) blockcnt[c * NB + b] = s + xv - v;
        s += __shfl(xv, 63);
    }
    if (lane == 0) btot[b] = s;
}

__global__ void k_scan_buckets(const int* __restrict__ btot, int* __restrict__ pair_start) {
    __shared__ int tot[256];
    int t = threadIdx.x;
    int v = (t < NB) ? btot[t] : 0;
    tot[t] = v;
    __syncthreads();
    for (int off = 1; off < 256; off <<= 1) {
        int u = (t >= off) ? tot[t - off] : 0;
        __syncthreads();
        tot[t] += u;
        __syncthreads();
    }
    if (t < NB) pair_start[t] = tot[t] - v;
    if (t == 0) pair_start[NB] = N_EDGES;
}

__global__ __launch_bounds__(256) void k_pair_scatter(
    const int* __restrict__ e0, const int* __restrict__ e1,
    const int* __restrict__ blockcnt, const int* __restrict__ pair_start,
    int* __restrict__ pairs)
{
    __shared__ int cnt[NB];
    __shared__ int base[NB];
    int t = threadIdx.x, b = blockIdx.x;
    if (t < NB) {
        cnt[t] = 0;
        base[t] = pair_start[t] + blockcnt[b * NB + t];
    }
    __syncthreads();
    int ebase = b * PAIR_CHUNK;
    int ecount = min(PAIR_CHUNK, N_EDGES - ebase);
    for (int i = t; i < ecount; i += 256) {
        int s = e0[ebase + i];
        int d = e1[ebase + i];
        int B = d >> BSHIFT;
        int idx = atomicAdd(&cnt[B], 1);
        pairs[base[B] + idx] = ((d & 511) << 17) | s;   // 9b local dst | 17b src
    }
}

// One block (512 thr) per bucket: degree histogram + wave-scan + col scatter in LDS.
// Self loop occupies slot 0 of each row.
__global__ __launch_bounds__(512) void k_csr_bucket(
    const int* __restrict__ pairs, const int* __restrict__ pair_start,
    int* __restrict__ rowptr, int* __restrict__ col)
{
    __shared__ int deg[512];
    __shared__ int excl[512];
    __shared__ int wsum[8];
    int b = blockIdx.x;
    int t = threadIdx.x;
    int nb = b << BSHIFT;
    int nodes = min(512, N_NODES - nb);

    deg[t] = (t < nodes) ? 1 : 0;   // self loop
    __syncthreads();
    int p0 = pair_start[b], p1 = pair_start[b + 1];
    for (int i = p0 + t; i < p1; i += 512)
        atomicAdd(&deg[pairs[i] >> 17], 1);
    __syncthreads();

    int val = deg[t];
    int x = val;
#pragma unroll
    for (int off = 1; off < 64; off <<= 1) {
        int y = __shfl_up(x, off);
        if ((t & 63) >= off) x += y;
    }
    if ((t & 63) == 63) wsum[t >> 6] = x;
    __syncthreads();
    if (t == 0) {
        int s = 0;
#pragma unroll
        for (int i = 0; i < 8; ++i) { int v = wsum[i]; wsum[i] = s; s += v; }
    }
    __syncthreads();
    int ex = x - val + wsum[t >> 6];  // exclusive prefix of local degrees
    excl[t] = ex;

    int colbase = p0 + nb;  // nb == #self-loops in preceding buckets
    if (t < nodes) {
        rowptr[nb + t] = colbase + ex;
        col[colbase + ex] = nb + t;  // self loop at slot 0
    }
    if (b == NB - 1 && t == 0) rowptr[N_NODES] = ETOT;

    deg[t] = 1;  // slot 0 taken by self loop
    __syncthreads();
    for (int i = p0 + t; i < p1; i += 512) {
        int p = pairs[i];
        int li = p >> 17;
        int pos = colbase + excl[li] + atomicAdd(&deg[li], 1);
        col[pos] = p & 0x1FFFF;
    }
}

// ---------------- per-layer GEMM + attention scores ----------------
// Input: fp32 embed gather (layer0) or bf16 activations. Output: int8 rows + scale + scores.

__global__ __launch_bounds__(256) void k_gemm_score(
    const void* __restrict__ hvoid, const int* __restrict__ x,
    const float* __restrict__ embed, const float* __restrict__ W,
    const float* __restrict__ a_s, const float* __restrict__ a_d,
    unsigned char* __restrict__ q8, float* __restrict__ scl,
    float* __restrict__ s_src, float* __restrict__ s_dst, int layer0)
{
    __shared__ float Wl[64 * 64];
    __shared__ float hT[64 * 68];  // [k][r], pitch 68
    int t = threadIdx.x;
    int r0 = blockIdx.x * 64;

    for (int i = t; i < 4096; i += 256) Wl[i] = W[i];
    if (layer0) {
        for (int i = t; i < 4096; i += 256) {
            int r = i >> 6, k = i & 63;
            int row = r0 + r;
            float v = (row < N_NODES) ? embed[x[row] * 64 + k] : 0.f;
            hT[k * 68 + r] = v;
        }
    } else {
        const unsigned* h32 = (const unsigned*)hvoid;
        for (int i = t; i < 2048; i += 256) {
            int r = i >> 5, m = i & 31;   // features 2m, 2m+1
            int row = r0 + r;
            unsigned u = (row < N_NODES) ? h32[row * 32 + m] : 0u;
            hT[(2 * m) * 68 + r]     = blo(u);
            hT[(2 * m + 1) * 68 + r] = bhi(u);
        }
    }
    __syncthreads();

    int tcol = t & 15;
    int trow = t >> 4;
    float acc[4][4];
#pragma unroll
    for (int i = 0; i < 4; ++i)
#pragma unroll
        for (int j = 0; j < 4; ++j) acc[i][j] = 0.f;

    for (int k = 0; k < 64; ++k) {
        float4 va = *(const float4*)&hT[k * 68 + trow * 4];
        float4 vb = *(const float4*)&Wl[k * 64 + tcol * 4];
        float a[4] = {va.x, va.y, va.z, va.w};
        float bb[4] = {vb.x, vb.y, vb.z, vb.w};
#pragma unroll
        for (int i = 0; i < 4; ++i)
#pragma unroll
            for (int j = 0; j < 4; ++j) acc[i][j] = fmaf(a[i], bb[j], acc[i][j]);
    }

    float4 as4 = *(const float4*)&a_s[tcol * 4];
    float4 ad4 = *(const float4*)&a_d[tcol * 4];
    float asr[4] = {as4.x, as4.y, as4.z, as4.w};
    float adr[4] = {ad4.x, ad4.y, ad4.z, ad4.w};

#pragma unroll
    for (int i = 0; i < 4; ++i) {
        int row = r0 + trow * 4 + i;
        float ps = 0.f, pd = 0.f;
#pragma unroll
        for (int j = 0; j < 4; ++j) {
            ps = fmaf(acc[i][j], asr[j], ps);
            pd = fmaf(acc[i][j], adr[j], pd);
        }
#pragma unroll
        for (int off = 8; off >= 1; off >>= 1) {
            ps += __shfl_xor(ps, off);
            pd += __shfl_xor(pd, off);
        }
        // per-row amax across the 16 lanes owning this row
        float am = fmaxf(fmaxf(fabsf(acc[i][0]), fabsf(acc[i][1])),
                         fmaxf(fabsf(acc[i][2]), fabsf(acc[i][3])));
#pragma unroll
        for (int off = 8; off >= 1; off >>= 1) am = fmaxf(am, __shfl_xor(am, off));
        float iscl = (am > 0.f) ? 127.f / am : 0.f;
        if (row < N_NODES) {
            int q0 = __float2int_rn(acc[i][0] * iscl);
            int q1 = __float2int_rn(acc[i][1] * iscl);
            int q2 = __float2int_rn(acc[i][2] * iscl);
            int q3 = __float2int_rn(acc[i][3] * iscl);
            unsigned pk = (q0 & 255) | ((q1 & 255) << 8) | ((q2 & 255) << 16)
                        | ((q3 & 255) << 24);
            ((unsigned*)q8)[row * 16 + tcol] = pk;
            if (tcol == 0) {
                scl[row] = am * (1.f / 127.f);
                s_src[row] = ps; s_dst[row] = pd;
            }
        }
    }
}

// ---------------- attention agg (slim, one node per wave, int8 gather) ----------------
// Gather: 16 lanes/edge x uint = 64-B int8 row (one cache line); scale folded into alpha.
// Writes o = relu(agg + bias) as bf16.

__global__ __launch_bounds__(256) void k_agg(
    const unsigned char* __restrict__ q8_in, const float* __restrict__ scl_in,
    const int* __restrict__ col, const int* __restrict__ rowptr,
    const float* __restrict__ s_src_in, const float* __restrict__ s_dst_in,
    const float* __restrict__ bias, unsigned short* __restrict__ hout)
{
    __shared__ float2 stash[4][64];  // (p*scl, row byte-offset bits)
    int wave = threadIdx.x >> 6;
    int lane = threadIdx.x & 63;
    int node = blockIdx.x * 4 + wave;
    if (node >= N_NODES) return;

    int row = rowptr[node];
    int end = rowptr[node + 1];
    int deg = end - row;
    float sdi = s_dst_in[node];
    const char* hb = (const char*)q8_in;

    if (deg <= 64) {
        int c = 0;
        float p = 0.f, sc = 0.f;
        if (lane < deg) {
            c = col[row + lane];
            float ee = s_src_in[c] + sdi;
            ee = (ee >= 0.f) ? ee : NEG_SLOPE * ee;
            p = __expf(ee);   // no max-sub: |e| small, fp32-safe
            sc = scl_in[c];
        }
        stash[wave][lane] = make_float2(p * sc, __int_as_float(c * 64));

        int q = lane >> 4;
        int f = lane & 15;
        int f4 = f * 4;
        float a0 = 0.f, a1 = 0.f, a2 = 0.f, a3 = 0.f;
        int degr = (deg + 15) & ~15;
        for (int j = q; j < degr; j += 16) {
            float2 e0 = stash[wave][j];
            float2 e1 = stash[wave][j + 4];
            float2 e2 = stash[wave][j + 8];
            float2 e3 = stash[wave][j + 12];
            unsigned v0 = *(const unsigned*)(hb + (__float_as_int(e0.y) + f4));
            unsigned v1 = *(const unsigned*)(hb + (__float_as_int(e1.y) + f4));
            unsigned v2 = *(const unsigned*)(hb + (__float_as_int(e2.y) + f4));
            unsigned v3 = *(const unsigned*)(hb + (__float_as_int(e3.y) + f4));
            a0 = fmaf(e0.x, (float)sb0(v0), a0);
            a1 = fmaf(e0.x, (float)sb1(v0), a1);
            a2 = fmaf(e0.x, (float)sb2(v0), a2);
            a3 = fmaf(e0.x, (float)sb3(v0), a3);
            a0 = fmaf(e1.x, (float)sb0(v1), a0);
            a1 = fmaf(e1.x, (float)sb1(v1), a1);
            a2 = fmaf(e1.x, (float)sb2(v1), a2);
            a3 = fmaf(e1.x, (float)sb3(v1), a3);
            a0 = fmaf(e2.x, (float)sb0(v2), a0);
            a1 = fmaf(e2.x, (float)sb1(v2), a1);
            a2 = fmaf(e2.x, (float)sb2(v2), a2);
            a3 = fmaf(e2.x, (float)sb3(v2), a3);
            a0 = fmaf(e3.x, (float)sb0(v3), a0);
            a1 = fmaf(e3.x, (float)sb1(v3), a1);
            a2 = fmaf(e3.x, (float)sb2(v3), a2);
            a3 = fmaf(e3.x, (float)sb3(v3), a3);
        }
        float denom = p;
#pragma unroll
        for (int off = 32; off >= 1; off >>= 1) denom += __shfl_xor(denom, off);
        float inv = 1.f / denom;
        a0 += __shfl_xor(a0, 16); a0 += __shfl_xor(a0, 32);
        a1 += __shfl_xor(a1, 16); a1 += __shfl_xor(a1, 32);
        a2 += __shfl_xor(a2, 16); a2 += __shfl_xor(a2, 32);
        a3 += __shfl_xor(a3, 16); a3 += __shfl_xor(a3, 32);
        if (lane < 16) {
            float4 bb = *(const float4*)&bias[4 * f];
            ushort4 pk;
            pk.x = f2bf(fmaxf(fmaf(a0, inv, bb.x), 0.f));
            pk.y = f2bf(fmaxf(fmaf(a1, inv, bb.y), 0.f));
            pk.z = f2bf(fmaxf(fmaf(a2, inv, bb.z), 0.f));
            pk.w = f2bf(fmaxf(fmaf(a3, inv, bb.w), 0.f));
            *(ushort4*)&hout[node * 64 + 4 * f] = pk;
        }
    } else {
        // generic path (deg > 64): statistically never hit
        float m = -FLT_MAX;
        for (int j = row + lane; j < end; j += 64) {
            float ee = s_src_in[col[j]] + sdi;
            ee = (ee >= 0.f) ? ee : NEG_SLOPE * ee;
            m = fmaxf(m, ee);
        }
#pragma unroll
        for (int off = 32; off >= 1; off >>= 1) m = fmaxf(m, __shfl_xor(m, off));
        float denom = 0.f;
        for (int j = row + lane; j < end; j += 64) {
            float ee = s_src_in[col[j]] + sdi;
            ee = (ee >= 0.f) ? ee : NEG_SLOPE * ee;
            denom += __expf(ee - m);
        }
#pragma unroll
        for (int off = 32; off >= 1; off >>= 1) denom += __shfl_xor(denom, off);
        float inv = 1.f / denom;
        float acc = 0.f;
        for (int j = row; j < end; ++j) {
            int cc = col[j];
            float ee = s_src_in[cc] + sdi;
            ee = (ee >= 0.f) ? ee : NEG_SLOPE * ee;
            float v = (float)((int)(signed char)q8_in[cc * 64 + lane]) * scl_in[cc];
            acc = fmaf(__expf(ee - m) * inv, v, acc);
        }
        hout[node * 64 + lane] = f2bf(fmaxf(acc + bias[lane], 0.f));
    }
}

// ---------------- last-layer agg + pool projection (one node per wave) ----------------

__global__ __launch_bounds__(256) void k_agg_pool(
    const unsigned char* __restrict__ q8_in, const float* __restrict__ scl_in,
    const int* __restrict__ col, const int* __restrict__ rowptr,
    const float* __restrict__ s_src_in, const float* __restrict__ s_dst_in,
    const float* __restrict__ bias, const int* __restrict__ batch,
    const float* __restrict__ W_out, float* __restrict__ pool_acc)
{
    __shared__ float2 stash[4][64];
    int wave = threadIdx.x >> 6;
    int lane = threadIdx.x & 63;
    int node = blockIdx.x * 4 + wave;
    if (node >= N_NODES) return;

    int row = rowptr[node];
    int end = rowptr[node + 1];
    int deg = end - row;
    float sdi = s_dst_in[node];
    float* rep = pool_acc + (blockIdx.x & (NREP - 1)) * REP_STRIDE;
    const char* hb = (const char*)q8_in;

    if (deg <= 64) {
        int c = 0;
        float p = 0.f, sc = 0.f;
        if (lane < deg) {
            c = col[row + lane];
            float ee = s_src_in[c] + sdi;
            ee = (ee >= 0.f) ? ee : NEG_SLOPE * ee;
            p = __expf(ee);
            sc = scl_in[c];
        }
        stash[wave][lane] = make_float2(p * sc, __int_as_float(c * 64));

        int q = lane >> 4;
        int f = lane & 15;
        int f4 = f * 4;
        float a0 = 0.f, a1 = 0.f, a2 = 0.f, a3 = 0.f;
        int degr = (deg + 15) & ~15;
        for (int j = q; j < degr; j += 16) {
            float2 e0 = stash[wave][j];
            float2 e1 = stash[wave][j + 4];
            float2 e2 = stash[wave][j + 8];
            float2 e3 = stash[wave][j + 12];
            unsigned v0 = *(const unsigned*)(hb + (__float_as_int(e0.y) + f4));
            unsigned v1 = *(const unsigned*)(hb + (__float_as_int(e1.y) + f4));
            unsigned v2 = *(const unsigned*)(hb + (__float_as_int(e2.y) + f4));
            unsigned v3 = *(const unsigned*)(hb + (__float_as_int(e3.y) + f4));
            a0 = fmaf(e0.x, (float)sb0(v0), a0);
            a1 = fmaf(e0.x, (float)sb1(v0), a1);
            a2 = fmaf(e0.x, (float)sb2(v0), a2);
            a3 = fmaf(e0.x, (float)sb3(v0), a3);
            a0 = fmaf(e1.x, (float)sb0(v1), a0);
            a1 = fmaf(e1.x, (float)sb1(v1), a1);
            a2 = fmaf(e1.x, (float)sb2(v1), a2);
            a3 = fmaf(e1.x, (float)sb3(v1), a3);
            a0 = fmaf(e2.x, (float)sb0(v2), a0);
            a1 = fmaf(e2.x, (float)sb1(v2), a1);
            a2 = fmaf(e2.x, (float)sb2(v2), a2);
            a3 = fmaf(e2.x, (float)sb3(v2), a3);
            a0 = fmaf(e3.x, (float)sb0(v3), a0);
            a1 = fmaf(e3.x, (float)sb1(v3), a1);
            a2 = fmaf(e3.x, (float)sb2(v3), a2);
            a3 = fmaf(e3.x, (float)sb3(v3), a3);
        }
        float denom = p;
#pragma unroll
        for (int off = 32; off >= 1; off >>= 1) denom += __shfl_xor(denom, off);
        float inv = 1.f / denom;
        a0 += __shfl_xor(a0, 16); a0 += __shfl_xor(a0, 32);
        a1 += __shfl_xor(a1, 16); a1 += __shfl_xor(a1, 32);
        a2 += __shfl_xor(a2, 16); a2 += __shfl_xor(a2, 32);
        a3 += __shfl_xor(a3, 16); a3 += __shfl_xor(a3, 32);

        float p0 = 0.f, p1 = 0.f;
        if (lane < 16) {
            float4 bb = *(const float4*)&bias[4 * f];
            float o0 = fmaf(a0, inv, bb.x), o1 = fmaf(a1, inv, bb.y);
            float o2 = fmaf(a2, inv, bb.z), o3 = fmaf(a3, inv, bb.w);
            float4 wa = *(const float4*)&W_out[8 * f];      // rows 4f, 4f+1
            float4 wb = *(const float4*)&W_out[8 * f + 4];  // rows 4f+2, 4f+3
            p0 = o0 * wa.x + o1 * wa.z + o2 * wb.x + o3 * wb.z;
            p1 = o0 * wa.y + o1 * wa.w + o2 * wb.y + o3 * wb.w;
        }
#pragma unroll
        for (int off = 8; off >= 1; off >>= 1) {
            p0 += __shfl_xor(p0, off);
            p1 += __shfl_xor(p1, off);
        }
        if (lane == 0) {
            int g = batch[node];
            atomicAdd(&rep[g * 2], p0);
            atomicAdd(&rep[g * 2 + 1], p1);
        }
    } else {
        float m = -FLT_MAX;
        for (int j = row + lane; j < end; j += 64) {
            float ee = s_src_in[col[j]] + sdi;
            ee = (ee >= 0.f) ? ee : NEG_SLOPE * ee;
            m = fmaxf(m, ee);
        }
#pragma unroll
        for (int off = 32; off >= 1; off >>= 1) m = fmaxf(m, __shfl_xor(m, off));
        float denom = 0.f;
        for (int j = row + lane; j < end; j += 64) {
            float ee = s_src_in[col[j]] + sdi;
            ee = (ee >= 0.f) ? ee : NEG_SLOPE * ee;
            denom += __expf(ee - m);
        }
#pragma unroll
        for (int off = 32; off >= 1; off >>= 1) denom += __shfl_xor(denom, off);
        float inv = 1.f / denom;
        float acc = 0.f;
        for (int j = row; j < end; ++j) {
            int cc = col[j];
            float ee = s_src_in[cc] + sdi;
            ee = (ee >= 0.f) ? ee : NEG_SLOPE * ee;
            float v = (float)((int)(signed char)q8_in[cc * 64 + lane]) * scl_in[cc];
            acc = fmaf(__expf(ee - m) * inv, v, acc);
        }
        float o = acc + bias[lane];
        float p0 = o * W_out[lane * 2];
        float p1 = o * W_out[lane * 2 + 1];
#pragma unroll
        for (int off = 32; off >= 1; off >>= 1) {
            p0 += __shfl_xor(p0, off);
            p1 += __shfl_xor(p1, off);
        }
        if (lane == 0) {
            int g = batch[node];
            atomicAdd(&rep[g * 2], p0);
            atomicAdd(&rep[g * 2 + 1], p1);
        }
    }
}

// ---------------- head: reduce replicas, divide by count, add b_out ----------------

__device__ __forceinline__ int lower_bound_dev(const int* __restrict__ a, int n, int v) {
    int lo = 0, hi = n;
    while (lo < hi) {
        int mid = (lo + hi) >> 1;
        if (a[mid] < v) lo = mid + 1; else hi = mid;
    }
    return lo;
}

__global__ void k_head(const float* __restrict__ pool_acc,
                       const int* __restrict__ batch,
                       const float* __restrict__ b_out,
                       float* __restrict__ out)
{
    int t = threadIdx.x;
    if (t < 2 * N_GRAPHS) {
        float s = 0.f;
#pragma unroll 8
        for (int r = 0; r < NREP; ++r) s += pool_acc[r * REP_STRIDE + t];
        int g = t >> 1, c = t & 1;
        int start = lower_bound_dev(batch, N_NODES, g);
        int end = lower_bound_dev(batch, N_NODES, g + 1);
        float cnt = fmaxf((float)(end - start), 1.f);
        out[t] = s / cnt + b_out[c];
    }
}

// ---------------- launch ----------------

extern "C" void kernel_launch(void* const* d_in, const int* in_sizes, int n_in,
                              void* d_out, int out_size, void* d_ws, size_t ws_size,
                              hipStream_t stream) {
    const int*   x       = (const int*)d_in[0];
    const int*   edge    = (const int*)d_in[1];   // [2][E]
    const int*   batch   = (const int*)d_in[2];
    const float* embed   = (const float*)d_in[3];
    const float* Ws      = (const float*)d_in[4];
    const float* a_srcs  = (const float*)d_in[5];
    const float* a_dsts  = (const float*)d_in[6];
    const float* biases  = (const float*)d_in[7];
    const float* W_out   = (const float*)d_in[8];
    const float* b_out   = (const float*)d_in[9];
    float* out = (float*)d_out;

    char* ws = (char*)d_ws;
    size_t off = 0;
    auto alloc = [&](size_t bytes) -> void* {
        void* p = ws + off;
        off += (bytes + 255) & ~(size_t)255;
        return p;
    };
    unsigned char*  qA   = (unsigned char*)alloc((size_t)N_NODES * 64);
    unsigned char*  qB   = (unsigned char*)alloc((size_t)N_NODES * 64);
    unsigned short* hout = (unsigned short*)alloc((size_t)N_NODES * 64 * sizeof(unsigned short));
    float* sclA     = (float*)alloc((size_t)N_NODES * sizeof(float));
    float* sclB     = (float*)alloc((size_t)N_NODES * sizeof(float));
    float* s_src0   = (float*)alloc((size_t)N_NODES * sizeof(float));
    float* s_dst0   = (float*)alloc((size_t)N_NODES * sizeof(float));
    float* s_src1   = (float*)alloc((size_t)N_NODES * sizeof(float));
    float* s_dst1   = (float*)alloc((size_t)N_NODES * sizeof(float));
    int*   rowptr   = (int*)alloc((size_t)(N_NODES + 1) * sizeof(int));
    int*   colA     = (int*)alloc((size_t)ETOT * sizeof(int));
    int*   blockcnt = (int*)alloc((size_t)PAIR_BLOCKS * NB * sizeof(int));
    int*   btot     = (int*)alloc((size_t)NB * sizeof(int));
    int*   pstart   = (int*)alloc((size_t)(NB + 1) * sizeof(int));
    float* pool_acc = (float*)alloc((size_t)(NREP * REP_STRIDE) * sizeof(float));
    int*   pairs    = (int*)alloc((size_t)N_EDGES * sizeof(int));  // dead after CSR build

    const int* e0 = edge;
    const int* e1 = edge + N_EDGES;

    // bucketed CSR build (by dst, self loops at slot 0 of each row)
    k_count<<<PAIR_BLOCKS, 256, 0, stream>>>(e1, blockcnt, pool_acc);
    k_scan_bases<<<NB, 64, 0, stream>>>(blockcnt, btot);
    k_scan_buckets<<<1, 256, 0, stream>>>(btot, pstart);
    k_pair_scatter<<<PAIR_BLOCKS, 256, 0, stream>>>(e0, e1, blockcnt, pstart, pairs);
    k_csr_bucket<<<NB, 512, 0, stream>>>(pairs, pstart, rowptr, colA);

    const int gemm_blocks = (N_NODES + 63) / 64;
    const int agg_blocks = (N_NODES + 3) / 4;
    // layer 0
    k_gemm_score<<<gemm_blocks, 256, 0, stream>>>(
        nullptr, x, embed, Ws, a_srcs, a_dsts, qA, sclA, s_src0, s_dst0, 1);
    k_agg<<<agg_blocks, 256, 0, stream>>>(
        qA, sclA, colA, rowptr, s_src0, s_dst0, biases, hout);
    // layer 1
    k_gemm_score<<<gemm_blocks, 256, 0, stream>>>(
        hout, x, embed, Ws + 4096, a_srcs + 64, a_dsts + 64, qB, sclB, s_src1, s_dst1, 0);
    k_agg<<<agg_blocks, 256, 0, stream>>>(
        qB, sclB, colA, rowptr, s_src1, s_dst1, biases + 64, hout);
    // layer 2
    k_gemm_score<<<gemm_blocks, 256, 0, stream>>>(
        hout, x, embed, Ws + 8192, a_srcs + 128, a_dsts + 128, qA, sclA, s_src0, s_dst0, 0);
    k_agg_pool<<<agg_blocks, 256, 0, stream>>>(
        qA, sclA, colA, rowptr, s_src0, s_dst0, biases + 128, batch, W_out, pool_acc);
    k_head<<<1, 256, 0, stream>>>(pool_acc, batch, b_out, out);
}

// Round 12
// 278.873 us; speedup vs baseline: 1.6115x; 1.2128x over previous
//
#include <hip/hip_runtime.h>
#include <hip/hip_bf16.h>
#include <float.h>

#define N_NODES 100000
#define N_EDGES 1600000
#define HIDDEN 64
#define N_GRAPHS 128
#define NEG_SLOPE 0.2f
#define ETOT (N_EDGES + N_NODES)

#define BSHIFT 9
#define NB ((N_NODES + 511) >> BSHIFT)    // 196 buckets of 512 nodes
#define PAIR_CHUNK 4096
#define PAIR_BLOCKS ((N_EDGES + PAIR_CHUNK - 1) / PAIR_CHUNK)  // 391

#define NREP 64           // pool accumulator replicas (atomic contention spreading)
#define REP_STRIDE 272    // 256 floats + 16 pad
#define NLVL 512          // c1 quantization levels (layer-1 table)

__device__ __forceinline__ unsigned short f2bf(float f) {
    unsigned u = __float_as_uint(f);
    unsigned r = (u + 0x7FFFu + ((u >> 16) & 1u)) >> 16;  // RNE
    return (unsigned short)r;
}
__device__ __forceinline__ float blo(unsigned u) { return __uint_as_float(u << 16); }
__device__ __forceinline__ float bhi(unsigned u) { return __uint_as_float(u & 0xFFFF0000u); }
__device__ __forceinline__ int sb0(unsigned u) { return (int)((unsigned)(u << 24)) >> 24; }
__device__ __forceinline__ int sb1(unsigned u) { return (int)((unsigned)(u << 16)) >> 24; }
__device__ __forceinline__ int sb2(unsigned u) { return (int)((unsigned)(u << 8)) >> 24; }
__device__ __forceinline__ int sb3(unsigned u) { return (int)u >> 24; }

// ---------------- x bitmask ----------------

__global__ __launch_bounds__(256) void k_xbit(const int* __restrict__ x,
                                              unsigned* __restrict__ xb) {
    int i = blockIdx.x * blockDim.x + threadIdx.x;
    int lane = threadIdx.x & 63;
    bool b = (i < N_NODES) && (x[i] != 0);
    unsigned long long m = __ballot(b);
    int wid = i >> 6;
    if (lane == 0) xb[wid * 2] = (unsigned)m;
    if (lane == 32) xb[wid * 2 + 1] = (unsigned)(m >> 32);
}

// ---------------- CSR build: per-chunk bucket counts (also zeroes pool_acc) ----------------

__global__ __launch_bounds__(256) void k_count(const int* __restrict__ e1,
                                               int* __restrict__ blockcnt,
                                               float* __restrict__ pool_acc) {
    __shared__ int h[NB];
    int t = threadIdx.x, b = blockIdx.x;
    if (t < NB) h[t] = 0;
    if (b < NREP && t < 2 * N_GRAPHS) pool_acc[b * REP_STRIDE + t] = 0.f;
    __syncthreads();
    int ebase = b * PAIR_CHUNK;
    int ecount = min(PAIR_CHUNK, N_EDGES - ebase);
    for (int i = t; i < ecount; i += 256)
        atomicAdd(&h[e1[ebase + i] >> BSHIFT], 1);
    __syncthreads();
    if (t < NB) blockcnt[b * NB + t] = h[t];
}

__global__ __launch_bounds__(64) void k_scan_bases(int* __restrict__ blockcnt,
                                                   int* __restrict__ btot) {
    int b = blockIdx.x;
    int lane = threadIdx.x;
    int s = 0;
    for (int base = 0; base < PAIR_BLOCKS; base += 64) {
        int c = base + lane;
        int v = (c < PAIR_BLOCKS) ? blockcnt[c * NB + b] : 0;
        int xv = v;
#pragma unroll
        for (int off = 1; off < 64; off <<= 1) {
            int y = __shfl_up(xv, off);
            if (lane >= off) xv += y;
        }
        if (c < PAIR_BLOCKS) blockcnt[c * NB + b] = s + xv - v;
        s += __shfl(xv, 63);
    }
    if (lane == 0) btot[b] = s;
}

__global__ void k_scan_buckets(const int* __restrict__ btot, int* __restrict__ pair_start) {
    __shared__ int tot[256];
    int t = threadIdx.x;
    int v = (t < NB) ? btot[t] : 0;
    tot[t] = v;
    __syncthreads();
    for (int off = 1; off < 256; off <<= 1) {
        int u = (t >= off) ? tot[t - off] : 0;
        __syncthreads();
        tot[t] += u;
        __syncthreads();
    }
    if (t < NB) pair_start[t] = tot[t] - v;
    if (t == 0) pair_start[NB] = N_EDGES;
}

__global__ __launch_bounds__(256) void k_pair_scatter(
    const int* __restrict__ e0, const int* __restrict__ e1,
    const unsigned* __restrict__ xb,
    const int* __restrict__ blockcnt, const int* __restrict__ pair_start,
    int* __restrict__ pairs)
{
    __shared__ int cnt[NB];
    __shared__ int base[NB];
    int t = threadIdx.x, b = blockIdx.x;
    if (t < NB) {
        cnt[t] = 0;
        base[t] = pair_start[t] + blockcnt[b * NB + t];
    }
    __syncthreads();
    int ebase = b * PAIR_CHUNK;
    int ecount = min(PAIR_CHUNK, N_EDGES - ebase);
    for (int i = t; i < ecount; i += 256) {
        int s = e0[ebase + i];
        int d = e1[ebase + i];
        int xv = (xb[s >> 5] >> (s & 31)) & 1;
        int B = d >> BSHIFT;
        int idx = atomicAdd(&cnt[B], 1);
        pairs[base[B] + idx] = (xv << 26) | ((d & 511) << 17) | s;  // x|9b dst|17b src
    }
}

// One block (512 thr) per bucket. Self loop at slot 0. col carries x-bit at bit 17.
__global__ __launch_bounds__(512) void k_csr_bucket(
    const int* __restrict__ pairs, const int* __restrict__ pair_start,
    const int* __restrict__ x,
    int* __restrict__ rowptr, int* __restrict__ col)
{
    __shared__ int deg[512];
    __shared__ int excl[512];
    __shared__ int wsum[8];
    int b = blockIdx.x;
    int t = threadIdx.x;
    int nb = b << BSHIFT;
    int nodes = min(512, N_NODES - nb);

    deg[t] = (t < nodes) ? 1 : 0;   // self loop
    __syncthreads();
    int p0 = pair_start[b], p1 = pair_start[b + 1];
    for (int i = p0 + t; i < p1; i += 512)
        atomicAdd(&deg[(pairs[i] >> 17) & 511], 1);
    __syncthreads();

    int val = deg[t];
    int xx = val;
#pragma unroll
    for (int off = 1; off < 64; off <<= 1) {
        int y = __shfl_up(xx, off);
        if ((t & 63) >= off) xx += y;
    }
    if ((t & 63) == 63) wsum[t >> 6] = xx;
    __syncthreads();
    if (t == 0) {
        int s = 0;
#pragma unroll
        for (int i = 0; i < 8; ++i) { int v = wsum[i]; wsum[i] = s; s += v; }
    }
    __syncthreads();
    int ex = xx - val + wsum[t >> 6];
    excl[t] = ex;

    int colbase = p0 + nb;
    if (t < nodes) {
        rowptr[nb + t] = colbase + ex;
        col[colbase + ex] = (nb + t) | ((x[nb + t] & 1) << 17);  // self loop
    }
    if (b == NB - 1 && t == 0) rowptr[N_NODES] = ETOT;

    deg[t] = 1;
    __syncthreads();
    for (int i = p0 + t; i < p1; i += 512) {
        int p = pairs[i];
        int li = (p >> 17) & 511;
        int pos = colbase + excl[li] + atomicAdd(&deg[li], 1);
        col[pos] = (p & 0x1FFFF) | (((p >> 26) & 1) << 17);
    }
}

// ---------------- layer-1 table build (512 levels of c1) + layer-0 score scalars ----------------

__global__ __launch_bounds__(64) void k_table(
    const float* __restrict__ embed, const float* __restrict__ Ws,
    const float* __restrict__ biases, const float* __restrict__ a_srcs,
    const float* __restrict__ a_dsts,
    unsigned char* __restrict__ Tq8, float* __restrict__ Tscl,
    float* __restrict__ Ts1s, float* __restrict__ Ts1d,
    float* __restrict__ sparams)
{
    __shared__ float o[64];
    int f = threadIdx.x;
    int l = blockIdx.x;
    float r0 = 0.f, r1 = 0.f;
#pragma unroll 8
    for (int k = 0; k < 64; ++k) {
        float w = Ws[k * 64 + f];
        r0 = fmaf(embed[k], w, r0);
        r1 = fmaf(embed[64 + k], w, r1);
    }
    if (l == 0) {  // layer-0 score scalars ss0, ss1, sd0, sd1
        float as = a_srcs[f], ad = a_dsts[f];
        float t0 = r0 * as, t1 = r1 * as, t2 = r0 * ad, t3 = r1 * ad;
#pragma unroll
        for (int off = 32; off >= 1; off >>= 1) {
            t0 += __shfl_xor(t0, off); t1 += __shfl_xor(t1, off);
            t2 += __shfl_xor(t2, off); t3 += __shfl_xor(t3, off);
        }
        if (f == 0) { sparams[0] = t0; sparams[1] = t1; sparams[2] = t2; sparams[3] = t3; }
    }
    float c1 = (float)l * (1.f / (NLVL - 1));
    o[f] = fmaxf(biases[f] + r0 + c1 * (r1 - r0), 0.f);
    __syncthreads();
    const float* W1 = Ws + 4096;
    float h = 0.f;
#pragma unroll 8
    for (int k = 0; k < 64; ++k) h = fmaf(o[k], W1[k * 64 + f], h);
    float ss = h * a_srcs[64 + f];
    float sd = h * a_dsts[64 + f];
    float am = fabsf(h);
#pragma unroll
    for (int off = 32; off >= 1; off >>= 1) {
        ss += __shfl_xor(ss, off);
        sd += __shfl_xor(sd, off);
        am = fmaxf(am, __shfl_xor(am, off));
    }
    float iscl = (am > 0.f) ? 127.f / am : 0.f;
    Tq8[l * 64 + f] = (unsigned char)(__float2int_rn(h * iscl) & 255);
    if (f == 0) { Tscl[l] = am * (1.f / 127.f); Ts1s[l] = ss; Ts1d[l] = sd; }
}

// ---------------- layer 0: count x=1 neighbors -> c1 index per node ----------------

__global__ __launch_bounds__(256) void k_l0(
    const int* __restrict__ col, const int* __restrict__ rowptr,
    const float* __restrict__ sparams, unsigned short* __restrict__ cidx)
{
    int wave = threadIdx.x >> 6, lane = threadIdx.x & 63;
    int node = blockIdx.x * 4 + wave;
    if (node >= N_NODES) return;
    int row = rowptr[node], end = rowptr[node + 1];
    int deg = end - row;
    int k, xi;
    if (deg <= 64) {
        int cw = (lane < deg) ? col[row + lane] : 0;
        unsigned long long m = __ballot((lane < deg) && (((cw >> 17) & 1) != 0));
        k = __popcll(m);
        xi = (__shfl(cw, 0) >> 17) & 1;
    } else {
        int acc = 0;
        for (int j = row + lane; j < end; j += 64) acc += (col[j] >> 17) & 1;
#pragma unroll
        for (int off = 32; off >= 1; off >>= 1) acc += __shfl_xor(acc, off);
        k = acc;
        xi = (col[row] >> 17) & 1;
    }
    if (lane == 0) {
        float ss0 = sparams[0], ss1 = sparams[1];
        float sd = xi ? sparams[3] : sparams[2];
        float e0 = ss0 + sd; e0 = (e0 >= 0.f) ? e0 : NEG_SLOPE * e0;
        float e1 = ss1 + sd; e1 = (e1 >= 0.f) ? e1 : NEG_SLOPE * e1;
        float p0 = __expf(e0), p1 = __expf(e1);
        float kn = (float)k, dn = (float)(deg - k);
        float c1 = kn * p1 / (dn * p0 + kn * p1);
        cidx[node] = (unsigned short)__float2int_rn(c1 * (float)(NLVL - 1));
    }
}

// ---------------- layer-1 agg via LDS table (zero global row gather) ----------------
// Persistent blocks; Tq8/Tscl/Ts1s/Ts1d staged in LDS (40 KB). One node per wave.
// Writes o1 = agg + bias (no relu? relu applies between layers 1 and 2 -> yes relu) as bf16.

__global__ __launch_bounds__(256) void k_agg1(
    const unsigned char* __restrict__ Tq8, const float* __restrict__ Tscl,
    const float* __restrict__ Ts1s, const float* __restrict__ Ts1d,
    const unsigned short* __restrict__ cidx, const int* __restrict__ col,
    const int* __restrict__ rowptr, const float* __restrict__ bias,
    unsigned short* __restrict__ hout)
{
    __shared__ unsigned TqL[NLVL * 16];   // 32 KB
    __shared__ float TsclL[NLVL];
    __shared__ float Ts1sL[NLVL];
    __shared__ float Ts1dL[NLVL];
    __shared__ float2 stash[4][64];
    int t = threadIdx.x;
    for (int i = t; i < NLVL * 16; i += 256) TqL[i] = ((const unsigned*)Tq8)[i];
    for (int i = t; i < NLVL; i += 256) {
        TsclL[i] = Tscl[i]; Ts1sL[i] = Ts1s[i]; Ts1dL[i] = Ts1d[i];
    }
    __syncthreads();

    int wave = t >> 6, lane = t & 63;
    for (int node = blockIdx.x * 4 + wave; node < N_NODES; node += gridDim.x * 4) {
        int row = rowptr[node], end = rowptr[node + 1];
        int deg = end - row;
        if (deg <= 64) {
            int idx = 0;
            float p = 0.f;
            if (lane < deg) idx = cidx[col[row + lane] & 0x1FFFF];
            float sdi = Ts1dL[__shfl(idx, 0)];   // slot 0 = self loop
            if (lane < deg) {
                float ee = Ts1sL[idx] + sdi;
                ee = (ee >= 0.f) ? ee : NEG_SLOPE * ee;
                p = __expf(ee);
            }
            stash[wave][lane] = make_float2(p * TsclL[idx], __int_as_float(idx * 16));

            int q = lane >> 4;
            int f = lane & 15;
            float a0 = 0.f, a1 = 0.f, a2 = 0.f, a3 = 0.f;
            int degr = (deg + 15) & ~15;
            for (int j = q; j < degr; j += 16) {
                float2 e0 = stash[wave][j];
                float2 e1 = stash[wave][j + 4];
                float2 e2 = stash[wave][j + 8];
                float2 e3 = stash[wave][j + 12];
                unsigned v0 = TqL[__float_as_int(e0.y) + f];
                unsigned v1 = TqL[__float_as_int(e1.y) + f];
                unsigned v2 = TqL[__float_as_int(e2.y) + f];
                unsigned v3 = TqL[__float_as_int(e3.y) + f];
                a0 = fmaf(e0.x, (float)sb0(v0), a0);
                a1 = fmaf(e0.x, (float)sb1(v0), a1);
                a2 = fmaf(e0.x, (float)sb2(v0), a2);
                a3 = fmaf(e0.x, (float)sb3(v0), a3);
                a0 = fmaf(e1.x, (float)sb0(v1), a0);
                a1 = fmaf(e1.x, (float)sb1(v1), a1);
                a2 = fmaf(e1.x, (float)sb2(v1), a2);
                a3 = fmaf(e1.x, (float)sb3(v1), a3);
                a0 = fmaf(e2.x, (float)sb0(v2), a0);
                a1 = fmaf(e2.x, (float)sb1(v2), a1);
                a2 = fmaf(e2.x, (float)sb2(v2), a2);
                a3 = fmaf(e2.x, (float)sb3(v2), a3);
                a0 = fmaf(e3.x, (float)sb0(v3), a0);
                a1 = fmaf(e3.x, (float)sb1(v3), a1);
                a2 = fmaf(e3.x, (float)sb2(v3), a2);
                a3 = fmaf(e3.x, (float)sb3(v3), a3);
            }
            float denom = p;
#pragma unroll
            for (int off = 32; off >= 1; off >>= 1) denom += __shfl_xor(denom, off);
            float inv = 1.f / denom;
            a0 += __shfl_xor(a0, 16); a0 += __shfl_xor(a0, 32);
            a1 += __shfl_xor(a1, 16); a1 += __shfl_xor(a1, 32);
            a2 += __shfl_xor(a2, 16); a2 += __shfl_xor(a2, 32);
            a3 += __shfl_xor(a3, 16); a3 += __shfl_xor(a3, 32);
            if (lane < 16) {
                float4 bb = *(const float4*)&bias[4 * f];
                ushort4 pk;
                pk.x = f2bf(fmaxf(fmaf(a0, inv, bb.x), 0.f));
                pk.y = f2bf(fmaxf(fmaf(a1, inv, bb.y), 0.f));
                pk.z = f2bf(fmaxf(fmaf(a2, inv, bb.z), 0.f));
                pk.w = f2bf(fmaxf(fmaf(a3, inv, bb.w), 0.f));
                *(ushort4*)&hout[node * 64 + 4 * f] = pk;
            }
        } else {
            // generic path (deg > 64): statistically never hit
            float sdi = Ts1dL[cidx[node]];
            float m = -FLT_MAX;
            for (int j = row + lane; j < end; j += 64) {
                float ee = Ts1sL[cidx[col[j] & 0x1FFFF]] + sdi;
                ee = (ee >= 0.f) ? ee : NEG_SLOPE * ee;
                m = fmaxf(m, ee);
            }
#pragma unroll
            for (int off = 32; off >= 1; off >>= 1) m = fmaxf(m, __shfl_xor(m, off));
            float denom = 0.f;
            for (int j = row + lane; j < end; j += 64) {
                float ee = Ts1sL[cidx[col[j] & 0x1FFFF]] + sdi;
                ee = (ee >= 0.f) ? ee : NEG_SLOPE * ee;
                denom += __expf(ee - m);
            }
#pragma unroll
            for (int off = 32; off >= 1; off >>= 1) denom += __shfl_xor(denom, off);
            float inv = 1.f / denom;
            float acc = 0.f;
            for (int j = row; j < end; ++j) {
                int idxj = cidx[col[j] & 0x1FFFF];
                float ee = Ts1sL[idxj] + sdi;
                ee = (ee >= 0.f) ? ee : NEG_SLOPE * ee;
                float w = __expf(ee - m) * inv * TsclL[idxj];
                unsigned wv = TqL[idxj * 16 + (lane >> 2)];
                int bq = (int)(signed char)((wv >> ((lane & 3) * 8)) & 255);
                acc = fmaf(w, (float)bq, acc);
            }
            hout[node * 64 + lane] = f2bf(fmaxf(acc + bias[lane], 0.f));
        }
    }
}

// ---------------- layer-2 GEMM + attention scores (bf16 in, int8 out) ----------------

__global__ __launch_bounds__(256) void k_gemm_score(
    const unsigned* __restrict__ h32, const float* __restrict__ W,
    const float* __restrict__ a_s, const float* __restrict__ a_d,
    unsigned char* __restrict__ q8, float* __restrict__ scl,
    float* __restrict__ s_src, float* __restrict__ s_dst)
{
    __shared__ float Wl[64 * 64];
    __shared__ float hT[64 * 68];  // [k][r], pitch 68
    int t = threadIdx.x;
    int r0 = blockIdx.x * 64;

    for (int i = t; i < 4096; i += 256) Wl[i] = W[i];
    for (int i = t; i < 2048; i += 256) {
        int r = i >> 5, m = i & 31;
        int row = r0 + r;
        unsigned u = (row < N_NODES) ? h32[row * 32 + m] : 0u;
        hT[(2 * m) * 68 + r]     = blo(u);
        hT[(2 * m + 1) * 68 + r] = bhi(u);
    }
    __syncthreads();

    int tcol = t & 15;
    int trow = t >> 4;
    float acc[4][4];
#pragma unroll
    for (int i = 0; i < 4; ++i)
#pragma unroll
        for (int j = 0; j < 4; ++j) acc[i][j] = 0.f;

    for (int k = 0; k < 64; ++k) {
        float4 va = *(const float4*)&hT[k * 68 + trow * 4];
        float4 vb = *(const float4*)&Wl[k * 64 + tcol * 4];
        float a[4] = {va.x, va.y, va.z, va.w};
        float bb[4] = {vb.x, vb.y, vb.z, vb.w};
#pragma unroll
        for (int i = 0; i < 4; ++i)
#pragma unroll
            for (int j = 0; j < 4; ++j) acc[i][j] = fmaf(a[i], bb[j], acc[i][j]);
    }

    float4 as4 = *(const float4*)&a_s[tcol * 4];
    float4 ad4 = *(const float4*)&a_d[tcol * 4];
    float asr[4] = {as4.x, as4.y, as4.z, as4.w};
    float adr[4] = {ad4.x, ad4.y, ad4.z, ad4.w};

#pragma unroll
    for (int i = 0; i < 4; ++i) {
        int row = r0 + trow * 4 + i;
        float ps = 0.f, pd = 0.f;
#pragma unroll
        for (int j = 0; j < 4; ++j) {
            ps = fmaf(acc[i][j], asr[j], ps);
            pd = fmaf(acc[i][j], adr[j], pd);
        }
#pragma unroll
        for (int off = 8; off >= 1; off >>= 1) {
            ps += __shfl_xor(ps, off);
            pd += __shfl_xor(pd, off);
        }
        float am = fmaxf(fmaxf(fabsf(acc[i][0]), fabsf(acc[i][1])),
                         fmaxf(fabsf(acc[i][2]), fabsf(acc[i][3])));
#pragma unroll
        for (int off = 8; off >= 1; off >>= 1) am = fmaxf(am, __shfl_xor(am, off));
        float iscl = (am > 0.f) ? 127.f / am : 0.f;
        if (row < N_NODES) {
            int q0 = __float2int_rn(acc[i][0] * iscl);
            int q1 = __float2int_rn(acc[i][1] * iscl);
            int q2 = __float2int_rn(acc[i][2] * iscl);
            int q3 = __float2int_rn(acc[i][3] * iscl);
            unsigned pk = (q0 & 255) | ((q1 & 255) << 8) | ((q2 & 255) << 16)
                        | ((q3 & 255) << 24);
            ((unsigned*)q8)[row * 16 + tcol] = pk;
            if (tcol == 0) {
                scl[row] = am * (1.f / 127.f);
                s_src[row] = ps; s_dst[row] = pd;
            }
        }
    }
}

// ---------------- last-layer agg + pool projection (one node per wave) ----------------

__global__ __launch_bounds__(256) void k_agg_pool(
    const unsigned char* __restrict__ q8_in, const float* __restrict__ scl_in,
    const int* __restrict__ col, const int* __restrict__ rowptr,
    const float* __restrict__ s_src_in, const float* __restrict__ s_dst_in,
    const float* __restrict__ bias, const int* __restrict__ batch,
    const float* __restrict__ W_out, float* __restrict__ pool_acc)
{
    __shared__ float2 stash[4][64];
    int wave = threadIdx.x >> 6;
    int lane = threadIdx.x & 63;
    int node = blockIdx.x * 4 + wave;
    if (node >= N_NODES) return;

    int row = rowptr[node];
    int end = rowptr[node + 1];
    int deg = end - row;
    float sdi = s_dst_in[node];
    float* rep = pool_acc + (blockIdx.x & (NREP - 1)) * REP_STRIDE;
    const char* hb = (const char*)q8_in;

    if (deg <= 64) {
        int c = 0;
        float p = 0.f, sc = 0.f;
        if (lane < deg) {
            c = col[row + lane] & 0x1FFFF;
            float ee = s_src_in[c] + sdi;
            ee = (ee >= 0.f) ? ee : NEG_SLOPE * ee;
            p = __expf(ee);
            sc = scl_in[c];
        }
        stash[wave][lane] = make_float2(p * sc, __int_as_float(c * 64));

        int q = lane >> 4;
        int f = lane & 15;
        int f4 = f * 4;
        float a0 = 0.f, a1 = 0.f, a2 = 0.f, a3 = 0.f;
        int degr = (deg + 15) & ~15;
        for (int j = q; j < degr; j += 16) {
            float2 e0 = stash[wave][j];
            float2 e1 = stash[wave][j + 4];
            float2 e2 = stash[wave][j + 8];
            float2 e3 = stash[wave][j + 12];
            unsigned v0 = *(const unsigned*)(hb + (__float_as_int(e0.y) + f4));
            unsigned v1 = *(const unsigned*)(hb + (__float_as_int(e1.y) + f4));
            unsigned v2 = *(const unsigned*)(hb + (__float_as_int(e2.y) + f4));
            unsigned v3 = *(const unsigned*)(hb + (__float_as_int(e3.y) + f4));
            a0 = fmaf(e0.x, (float)sb0(v0), a0);
            a1 = fmaf(e0.x, (float)sb1(v0), a1);
            a2 = fmaf(e0.x, (float)sb2(v0), a2);
            a3 = fmaf(e0.x, (float)sb3(v0), a3);
            a0 = fmaf(e1.x, (float)sb0(v1), a0);
            a1 = fmaf(e1.x, (float)sb1(v1), a1);
            a2 = fmaf(e1.x, (float)sb2(v1), a2);
            a3 = fmaf(e1.x, (float)sb3(v1), a3);
            a0 = fmaf(e2.x, (float)sb0(v2), a0);
            a1 = fmaf(e2.x, (float)sb1(v2), a1);
            a2 = fmaf(e2.x, (float)sb2(v2), a2);
            a3 = fmaf(e2.x, (float)sb3(v2), a3);
            a0 = fmaf(e3.x, (float)sb0(v3), a0);
            a1 = fmaf(e3.x, (float)sb1(v3), a1);
            a2 = fmaf(e3.x, (float)sb2(v3), a2);
            a3 = fmaf(e3.x, (float)sb3(v3), a3);
        }
        float denom = p;
#pragma unroll
        for (int off = 32; off >= 1; off >>= 1) denom += __shfl_xor(denom, off);
        float inv = 1.f / denom;
        a0 += __shfl_xor(a0, 16); a0 += __shfl_xor(a0, 32);
        a1 += __shfl_xor(a1, 16); a1 += __shfl_xor(a1, 32);
        a2 += __shfl_xor(a2, 16); a2 += __shfl_xor(a2, 32);
        a3 += __shfl_xor(a3, 16); a3 += __shfl_xor(a3, 32);

        float p0 = 0.f, p1 = 0.f;
        if (lane < 16) {
            float4 bb = *(const float4*)&bias[4 * f];
            float o0 = fmaf(a0, inv, bb.x), o1 = fmaf(a1, inv, bb.y);
            float o2 = fmaf(a2, inv, bb.z), o3 = fmaf(a3, inv, bb.w);
            float4 wa = *(const float4*)&W_out[8 * f];
            float4 wb = *(const float4*)&W_out[8 * f + 4];
            p0 = o0 * wa.x + o1 * wa.z + o2 * wb.x + o3 * wb.z;
            p1 = o0 * wa.y + o1 * wa.w + o2 * wb.y + o3 * wb.w;
        }
#pragma unroll
        for (int off = 8; off >= 1; off >>= 1) {
            p0 += __shfl_xor(p0, off);
            p1 += __shfl_xor(p1, off);
        }
        if (lane == 0) {
            int g = batch[node];
            atomicAdd(&rep[g * 2], p0);
            atomicAdd(&rep[g * 2 + 1], p1);
        }
    } else {
        float m = -FLT_MAX;
        for (int j = row + lane; j < end; j += 64) {
            float ee = s_src_in[col[j] & 0x1FFFF] + sdi;
            ee = (ee >= 0.f) ? ee : NEG_SLOPE * ee;
            m = fmaxf(m, ee);
        }
#pragma unroll
        for (int off = 32; off >= 1; off >>= 1) m = fmaxf(m, __shfl_xor(m, off));
        float denom = 0.f;
        for (int j = row + lane; j < end; j += 64) {
            float ee = s_src_in[col[j] & 0x1FFFF] + sdi;
            ee = (ee >= 0.f) ? ee : NEG_SLOPE * ee;
            denom += __expf(ee - m);
        }
#pragma unroll
        for (int off = 32; off >= 1; off >>= 1) denom += __shfl_xor(denom, off);
        float inv = 1.f / denom;
        float acc = 0.f;
        for (int j = row; j < end; ++j) {
            int cc = col[j] & 0x1FFFF;
            float ee = s_src_in[cc] + sdi;
            ee = (ee >= 0.f) ? ee : NEG_SLOPE * ee;
            float v = (float)((int)(signed char)q8_in[cc * 64 + lane]) * scl_in[cc];
            acc = fmaf(__expf(ee - m) * inv, v, acc);
        }
        float o = acc + bias[lane];
        float p0 = o * W_out[lane * 2];
        float p1 = o * W_out[lane * 2 + 1];
#pragma unroll
        for (int off = 32; off >= 1; off >>= 1) {
            p0 += __shfl_xor(p0, off);
            p1 += __shfl_xor(p1, off);
        }
        if (lane == 0) {
            int g = batch[node];
            atomicAdd(&rep[g * 2], p0);
            atomicAdd(&rep[g * 2 + 1], p1);
        }
    }
}

// ---------------- head: reduce replicas, divide by count, add b_out ----------------

__device__ __forceinline__ int lower_bound_dev(const int* __restrict__ a, int n, int v) {
    int lo = 0, hi = n;
    while (lo < hi) {
        int mid = (lo + hi) >> 1;
        if (a[mid] < v) lo = mid + 1; else hi = mid;
    }
    return lo;
}

__global__ void k_head(const float* __restrict__ pool_acc,
                       const int* __restrict__ batch,
                       const float* __restrict__ b_out,
                       float* __restrict__ out)
{
    int t = threadIdx.x;
    if (t < 2 * N_GRAPHS) {
        float s = 0.f;
#pragma unroll 8
        for (int r = 0; r < NREP; ++r) s += pool_acc[r * REP_STRIDE + t];
        int g = t >> 1, c = t & 1;
        int start = lower_bound_dev(batch, N_NODES, g);
        int end = lower_bound_dev(batch, N_NODES, g + 1);
        float cnt = fmaxf((float)(end - start), 1.f);
        out[t] = s / cnt + b_out[c];
    }
}

// ---------------- launch ----------------

extern "C" void kernel_launch(void* const* d_in, const int* in_sizes, int n_in,
                              void* d_out, int out_size, void* d_ws, size_t ws_size,
                              hipStream_t stream) {
    const int*   x       = (const int*)d_in[0];
    const int*   edge    = (const int*)d_in[1];   // [2][E]
    const int*   batch   = (const int*)d_in[2];
    const float* embed   = (const float*)d_in[3];
    const float* Ws      = (const float*)d_in[4];
    const float* a_srcs  = (const float*)d_in[5];
    const float* a_dsts  = (const float*)d_in[6];
    const float* biases  = (const float*)d_in[7];
    const float* W_out   = (const float*)d_in[8];
    const float* b_out   = (const float*)d_in[9];
    float* out = (float*)d_out;

    char* ws = (char*)d_ws;
    size_t off = 0;
    auto alloc = [&](size_t bytes) -> void* {
        void* p = ws + off;
        off += (bytes + 255) & ~(size_t)255;
        return p;
    };
    unsigned char*  qA    = (unsigned char*)alloc((size_t)N_NODES * 64);
    unsigned short* hout  = (unsigned short*)alloc((size_t)N_NODES * 64 * sizeof(unsigned short));
    float* sclA     = (float*)alloc((size_t)N_NODES * sizeof(float));
    float* s_src0   = (float*)alloc((size_t)N_NODES * sizeof(float));
    float* s_dst0   = (float*)alloc((size_t)N_NODES * sizeof(float));
    unsigned short* cidx = (unsigned short*)alloc((size_t)N_NODES * sizeof(unsigned short));
    int*   rowptr   = (int*)alloc((size_t)(N_NODES + 1) * sizeof(int));
    int*   colA     = (int*)alloc((size_t)ETOT * sizeof(int));
    int*   blockcnt = (int*)alloc((size_t)PAIR_BLOCKS * NB * sizeof(int));
    int*   btot     = (int*)alloc((size_t)NB * sizeof(int));
    int*   pstart   = (int*)alloc((size_t)(NB + 1) * sizeof(int));
    float* pool_acc = (float*)alloc((size_t)(NREP * REP_STRIDE) * sizeof(float));
    unsigned* xb    = (unsigned*)alloc((size_t)3200 * sizeof(unsigned));
    unsigned char* Tq8 = (unsigned char*)alloc((size_t)NLVL * 64);
    float* Tscl     = (float*)alloc((size_t)NLVL * sizeof(float));
    float* Ts1s     = (float*)alloc((size_t)NLVL * sizeof(float));
    float* Ts1d     = (float*)alloc((size_t)NLVL * sizeof(float));
    float* sparams  = (float*)alloc((size_t)4 * sizeof(float));
    int*   pairs    = (int*)alloc((size_t)N_EDGES * sizeof(int));  // dead after CSR build

    const int* e0 = edge;
    const int* e1 = edge + N_EDGES;

    // x bitmask + bucketed CSR build (col carries x-bit at bit 17)
    k_xbit<<<(N_NODES + 255) / 256, 256, 0, stream>>>(x, xb);
    k_count<<<PAIR_BLOCKS, 256, 0, stream>>>(e1, blockcnt, pool_acc);
    k_scan_bases<<<NB, 64, 0, stream>>>(blockcnt, btot);
    k_scan_buckets<<<1, 256, 0, stream>>>(btot, pstart);
    k_pair_scatter<<<PAIR_BLOCKS, 256, 0, stream>>>(e0, e1, xb, blockcnt, pstart, pairs);
    k_csr_bucket<<<NB, 512, 0, stream>>>(pairs, pstart, x, rowptr, colA);

    // layer-1 table (512 c1-levels) + layer-0 score scalars
    k_table<<<NLVL, 64, 0, stream>>>(embed, Ws, biases, a_srcs, a_dsts,
                                     Tq8, Tscl, Ts1s, Ts1d, sparams);
    // layer 0: count -> c1 index
    k_l0<<<(N_NODES + 3) / 4, 256, 0, stream>>>(colA, rowptr, sparams, cidx);
    // layer 1: table-based aggregation -> bf16 hout
    k_agg1<<<1024, 256, 0, stream>>>(Tq8, Tscl, Ts1s, Ts1d, cidx, colA, rowptr,
                                     biases + 64, hout);
    // layer 2: GEMM + scores -> int8, then agg + pool
    k_gemm_score<<<(N_NODES + 63) / 64, 256, 0, stream>>>(
        (const unsigned*)hout, Ws + 8192, a_srcs + 128, a_dsts + 128,
        qA, sclA, s_src0, s_dst0);
    k_agg_pool<<<(N_NODES + 3) / 4, 256, 0, stream>>>(
        qA, sclA, colA, rowptr, s_src0, s_dst0, biases + 128, batch, W_out, pool_acc);
    k_head<<<1, 256, 0, stream>>>(pool_acc, batch, b_out, out);
}

// Round 13
// 253.030 us; speedup vs baseline: 1.7760x; 1.1021x over previous
//
#include <hip/hip_runtime.h>
#include <hip/hip_bf16.h>
#include <float.h>

#define N_NODES 100000
#define N_EDGES 1600000
#define HIDDEN 64
#define N_GRAPHS 128
#define NEG_SLOPE 0.2f
#define ETOT (N_EDGES + N_NODES)

#define BSHIFT 9
#define NB ((N_NODES + 511) >> BSHIFT)    // 196 buckets of 512 nodes
#define PAIR_CHUNK 4096
#define PAIR_BLOCKS ((N_EDGES + PAIR_CHUNK - 1) / PAIR_CHUNK)  // 391

#define NREP 64           // pool accumulator replicas (atomic contention spreading)
#define REP_STRIDE 272    // 256 floats + 16 pad
#define NLVL 512          // c1 quantization levels (layer-1 table)

__device__ __forceinline__ unsigned short f2bf(float f) {
    unsigned u = __float_as_uint(f);
    unsigned r = (u + 0x7FFFu + ((u >> 16) & 1u)) >> 16;  // RNE
    return (unsigned short)r;
}
__device__ __forceinline__ float blo(unsigned u) { return __uint_as_float(u << 16); }
__device__ __forceinline__ float bhi(unsigned u) { return __uint_as_float(u & 0xFFFF0000u); }
__device__ __forceinline__ int sb0(unsigned u) { return (int)((unsigned)(u << 24)) >> 24; }
__device__ __forceinline__ int sb1(unsigned u) { return (int)((unsigned)(u << 16)) >> 24; }
__device__ __forceinline__ int sb2(unsigned u) { return (int)((unsigned)(u << 8)) >> 24; }
__device__ __forceinline__ int sb3(unsigned u) { return (int)u >> 24; }

// ---------------- x bitmask ----------------

__global__ __launch_bounds__(256) void k_xbit(const int* __restrict__ x,
                                              unsigned* __restrict__ xb) {
    int i = blockIdx.x * blockDim.x + threadIdx.x;
    int lane = threadIdx.x & 63;
    bool b = (i < N_NODES) && (x[i] != 0);
    unsigned long long m = __ballot(b);
    int wid = i >> 6;
    if (lane == 0) xb[wid * 2] = (unsigned)m;
    if (lane == 32) xb[wid * 2 + 1] = (unsigned)(m >> 32);
}

// ---------------- CSR build: per-chunk bucket counts (also zeroes pool_acc) ----------------

__global__ __launch_bounds__(256) void k_count(const int* __restrict__ e1,
                                               int* __restrict__ blockcnt,
                                               float* __restrict__ pool_acc) {
    __shared__ int h[NB];
    int t = threadIdx.x, b = blockIdx.x;
    if (t < NB) h[t] = 0;
    if (b < NREP && t < 2 * N_GRAPHS) pool_acc[b * REP_STRIDE + t] = 0.f;
    __syncthreads();
    int ebase = b * PAIR_CHUNK;
    int ecount = min(PAIR_CHUNK, N_EDGES - ebase);
    for (int i = t; i < ecount; i += 256)
        atomicAdd(&h[e1[ebase + i] >> BSHIFT], 1);
    __syncthreads();
    if (t < NB) blockcnt[b * NB + t] = h[t];
}

__global__ __launch_bounds__(64) void k_scan_bases(int* __restrict__ blockcnt,
                                                   int* __restrict__ btot) {
    int b = blockIdx.x;
    int lane = threadIdx.x;
    int s = 0;
    for (int base = 0; base < PAIR_BLOCKS; base += 64) {
        int c = base + lane;
        int v = (c < PAIR_BLOCKS) ? blockcnt[c * NB + b] : 0;
        int xv = v;
#pragma unroll
        for (int off = 1; off < 64; off <<= 1) {
            int y = __shfl_up(xv, off);
            if (lane >= off) xv += y;
        }
        if (c < PAIR_BLOCKS) blockcnt[c * NB + b] = s + xv - v;
        s += __shfl(xv, 63);
    }
    if (lane == 0) btot[b] = s;
}

__global__ void k_scan_buckets(const int* __restrict__ btot, int* __restrict__ pair_start) {
    __shared__ int tot[256];
    int t = threadIdx.x;
    int v = (t < NB) ? btot[t] : 0;
    tot[t] = v;
    __syncthreads();
    for (int off = 1; off < 256; off <<= 1) {
        int u = (t >= off) ? tot[t - off] : 0;
        __syncthreads();
        tot[t] += u;
        __syncthreads();
    }
    if (t < NB) pair_start[t] = tot[t] - v;
    if (t == 0) pair_start[NB] = N_EDGES;
}

__global__ __launch_bounds__(256) void k_pair_scatter(
    const int* __restrict__ e0, const int* __restrict__ e1,
    const unsigned* __restrict__ xb,
    const int* __restrict__ blockcnt, const int* __restrict__ pair_start,
    int* __restrict__ pairs)
{
    __shared__ int cnt[NB];
    __shared__ int base[NB];
    int t = threadIdx.x, b = blockIdx.x;
    if (t < NB) {
        cnt[t] = 0;
        base[t] = pair_start[t] + blockcnt[b * NB + t];
    }
    __syncthreads();
    int ebase = b * PAIR_CHUNK;
    int ecount = min(PAIR_CHUNK, N_EDGES - ebase);
    for (int i = t; i < ecount; i += 256) {
        int s = e0[ebase + i];
        int d = e1[ebase + i];
        int xv = (xb[s >> 5] >> (s & 31)) & 1;
        int B = d >> BSHIFT;
        int idx = atomicAdd(&cnt[B], 1);
        pairs[base[B] + idx] = (xv << 26) | ((d & 511) << 17) | s;  // x|9b dst|17b src
    }
}

// One block (512 thr) per bucket. Self loop at slot 0.
// Pass 1 packs degree (lo16) + x-count (hi16) in one atomic; also emits cidx
// (layer-0 result) directly -> k_l0 kernel eliminated.
__global__ __launch_bounds__(512) void k_csr_bucket(
    const int* __restrict__ pairs, const int* __restrict__ pair_start,
    const int* __restrict__ x, const float* __restrict__ sparams,
    int* __restrict__ rowptr, int* __restrict__ col,
    unsigned short* __restrict__ cidx)
{
    __shared__ int deg[512];
    __shared__ int excl[512];
    __shared__ int cnt2[512];
    __shared__ int wsum[8];
    int b = blockIdx.x;
    int t = threadIdx.x;
    int nb = b << BSHIFT;
    int nodes = min(512, N_NODES - nb);

    int xself = (t < nodes) ? (x[nb + t] & 1) : 0;
    deg[t] = (t < nodes) ? (1 | (xself << 16)) : 0;   // self loop contributes
    cnt2[t] = 1;  // scatter counter starts past self-loop slot
    __syncthreads();
    int p0 = pair_start[b], p1 = pair_start[b + 1];
    for (int i = p0 + t; i < p1; i += 512) {
        int p = pairs[i];
        atomicAdd(&deg[(p >> 17) & 511], 1 | (((p >> 26) & 1) << 16));
    }
    __syncthreads();

    int packed = deg[t];
    int val = packed & 0xFFFF;          // degree incl self loop
    int kx = packed >> 16;              // #neighbors with x=1 (incl self)
    // layer-0: c1 index
    if (t < nodes) {
        float ss0 = sparams[0], ss1 = sparams[1];
        float sd = xself ? sparams[3] : sparams[2];
        float e0 = ss0 + sd; e0 = (e0 >= 0.f) ? e0 : NEG_SLOPE * e0;
        float e1 = ss1 + sd; e1 = (e1 >= 0.f) ? e1 : NEG_SLOPE * e1;
        float pp0 = __expf(e0), pp1 = __expf(e1);
        float kn = (float)kx, dn = (float)(val - kx);
        float c1 = kn * pp1 / (dn * pp0 + kn * pp1);
        cidx[nb + t] = (unsigned short)__float2int_rn(c1 * (float)(NLVL - 1));
    }

    int xx = val;
#pragma unroll
    for (int off = 1; off < 64; off <<= 1) {
        int y = __shfl_up(xx, off);
        if ((t & 63) >= off) xx += y;
    }
    if ((t & 63) == 63) wsum[t >> 6] = xx;
    __syncthreads();
    if (t == 0) {
        int s = 0;
#pragma unroll
        for (int i = 0; i < 8; ++i) { int v = wsum[i]; wsum[i] = s; s += v; }
    }
    __syncthreads();
    int ex = xx - val + wsum[t >> 6];
    excl[t] = ex;

    int colbase = p0 + nb;
    if (t < nodes) {
        rowptr[nb + t] = colbase + ex;
        col[colbase + ex] = nb + t;  // self loop at slot 0
    }
    if (b == NB - 1 && t == 0) rowptr[N_NODES] = ETOT;
    __syncthreads();
    for (int i = p0 + t; i < p1; i += 512) {
        int p = pairs[i];
        int li = (p >> 17) & 511;
        int pos = colbase + excl[li] + atomicAdd(&cnt2[li], 1);
        col[pos] = p & 0x1FFFF;
    }
}

// ---------------- layer-1 table build + layer-0 score scalars + head const ----------------

__global__ __launch_bounds__(64) void k_table(
    const float* __restrict__ embed, const float* __restrict__ Ws,
    const float* __restrict__ biases, const float* __restrict__ a_srcs,
    const float* __restrict__ a_dsts, const float* __restrict__ W_out,
    unsigned char* __restrict__ Tq8, float* __restrict__ Tscl,
    float* __restrict__ Ts1s, float* __restrict__ Ts1d,
    float* __restrict__ sparams)
{
    __shared__ float o[64];
    int f = threadIdx.x;
    int l = blockIdx.x;
    float r0 = 0.f, r1 = 0.f;
#pragma unroll 8
    for (int k = 0; k < 64; ++k) {
        float w = Ws[k * 64 + f];
        r0 = fmaf(embed[k], w, r0);
        r1 = fmaf(embed[64 + k], w, r1);
    }
    if (l == 0) {  // layer-0 score scalars ss0, ss1, sd0, sd1
        float as = a_srcs[f], ad = a_dsts[f];
        float t0 = r0 * as, t1 = r1 * as, t2 = r0 * ad, t3 = r1 * ad;
#pragma unroll
        for (int off = 32; off >= 1; off >>= 1) {
            t0 += __shfl_xor(t0, off); t1 += __shfl_xor(t1, off);
            t2 += __shfl_xor(t2, off); t3 += __shfl_xor(t3, off);
        }
        if (f == 0) { sparams[0] = t0; sparams[1] = t1; sparams[2] = t2; sparams[3] = t3; }
    }
    if (l == 1) {  // head constant: b2 @ W_out
        float b2 = biases[128 + f];
        float t4 = b2 * W_out[f * 2];
        float t5 = b2 * W_out[f * 2 + 1];
#pragma unroll
        for (int off = 32; off >= 1; off >>= 1) {
            t4 += __shfl_xor(t4, off); t5 += __shfl_xor(t5, off);
        }
        if (f == 0) { sparams[4] = t4; sparams[5] = t5; }
    }
    float c1 = (float)l * (1.f / (NLVL - 1));
    o[f] = fmaxf(biases[f] + r0 + c1 * (r1 - r0), 0.f);
    __syncthreads();
    const float* W1 = Ws + 4096;
    float h = 0.f;
#pragma unroll 8
    for (int k = 0; k < 64; ++k) h = fmaf(o[k], W1[k * 64 + f], h);
    float ss = h * a_srcs[64 + f];
    float sd = h * a_dsts[64 + f];
    float am = fabsf(h);
#pragma unroll
    for (int off = 32; off >= 1; off >>= 1) {
        ss += __shfl_xor(ss, off);
        sd += __shfl_xor(sd, off);
        am = fmaxf(am, __shfl_xor(am, off));
    }
    float iscl = (am > 0.f) ? 127.f / am : 0.f;
    Tq8[l * 64 + f] = (unsigned char)(__float2int_rn(h * iscl) & 255);
    if (f == 0) { Tscl[l] = am * (1.f / 127.f); Ts1s[l] = ss; Ts1d[l] = sd; }
}

// ---------------- layer-1 agg via LDS table (zero global row gather) ----------------

__global__ __launch_bounds__(256) void k_agg1(
    const unsigned char* __restrict__ Tq8, const float* __restrict__ Tscl,
    const float* __restrict__ Ts1s, const float* __restrict__ Ts1d,
    const unsigned short* __restrict__ cidx, const int* __restrict__ col,
    const int* __restrict__ rowptr, const float* __restrict__ bias,
    unsigned short* __restrict__ hout)
{
    __shared__ unsigned TqL[NLVL * 16];   // 32 KB
    __shared__ float TsclL[NLVL];
    __shared__ float Ts1sL[NLVL];
    __shared__ float Ts1dL[NLVL];
    __shared__ float2 stash[4][64];
    int t = threadIdx.x;
    for (int i = t; i < NLVL * 16; i += 256) TqL[i] = ((const unsigned*)Tq8)[i];
    for (int i = t; i < NLVL; i += 256) {
        TsclL[i] = Tscl[i]; Ts1sL[i] = Ts1s[i]; Ts1dL[i] = Ts1d[i];
    }
    __syncthreads();

    int wave = t >> 6, lane = t & 63;
    for (int node = blockIdx.x * 4 + wave; node < N_NODES; node += gridDim.x * 4) {
        int row = rowptr[node], end = rowptr[node + 1];
        int deg = end - row;
        if (deg <= 64) {
            int idx = 0;
            float p = 0.f;
            if (lane < deg) idx = cidx[col[row + lane]];
            float sdi = Ts1dL[__shfl(idx, 0)];   // slot 0 = self loop
            if (lane < deg) {
                float ee = Ts1sL[idx] + sdi;
                ee = (ee >= 0.f) ? ee : NEG_SLOPE * ee;
                p = __expf(ee);
            }
            stash[wave][lane] = make_float2(p * TsclL[idx], __int_as_float(idx * 16));

            int q = lane >> 4;
            int f = lane & 15;
            float a0 = 0.f, a1 = 0.f, a2 = 0.f, a3 = 0.f;
            int degr = (deg + 15) & ~15;
            for (int j = q; j < degr; j += 16) {
                float2 e0 = stash[wave][j];
                float2 e1 = stash[wave][j + 4];
                float2 e2 = stash[wave][j + 8];
                float2 e3 = stash[wave][j + 12];
                unsigned v0 = TqL[__float_as_int(e0.y) + f];
                unsigned v1 = TqL[__float_as_int(e1.y) + f];
                unsigned v2 = TqL[__float_as_int(e2.y) + f];
                unsigned v3 = TqL[__float_as_int(e3.y) + f];
                a0 = fmaf(e0.x, (float)sb0(v0), a0);
                a1 = fmaf(e0.x, (float)sb1(v0), a1);
                a2 = fmaf(e0.x, (float)sb2(v0), a2);
                a3 = fmaf(e0.x, (float)sb3(v0), a3);
                a0 = fmaf(e1.x, (float)sb0(v1), a0);
                a1 = fmaf(e1.x, (float)sb1(v1), a1);
                a2 = fmaf(e1.x, (float)sb2(v1), a2);
                a3 = fmaf(e1.x, (float)sb3(v1), a3);
                a0 = fmaf(e2.x, (float)sb0(v2), a0);
                a1 = fmaf(e2.x, (float)sb1(v2), a1);
                a2 = fmaf(e2.x, (float)sb2(v2), a2);
                a3 = fmaf(e2.x, (float)sb3(v2), a3);
                a0 = fmaf(e3.x, (float)sb0(v3), a0);
                a1 = fmaf(e3.x, (float)sb1(v3), a1);
                a2 = fmaf(e3.x, (float)sb2(v3), a2);
                a3 = fmaf(e3.x, (float)sb3(v3), a3);
            }
            float denom = p;
#pragma unroll
            for (int off = 32; off >= 1; off >>= 1) denom += __shfl_xor(denom, off);
            float inv = 1.f / denom;
            a0 += __shfl_xor(a0, 16); a0 += __shfl_xor(a0, 32);
            a1 += __shfl_xor(a1, 16); a1 += __shfl_xor(a1, 32);
            a2 += __shfl_xor(a2, 16); a2 += __shfl_xor(a2, 32);
            a3 += __shfl_xor(a3, 16); a3 += __shfl_xor(a3, 32);
            if (lane < 16) {
                float4 bb = *(const float4*)&bias[4 * f];
                ushort4 pk;
                pk.x = f2bf(fmaxf(fmaf(a0, inv, bb.x), 0.f));
                pk.y = f2bf(fmaxf(fmaf(a1, inv, bb.y), 0.f));
                pk.z = f2bf(fmaxf(fmaf(a2, inv, bb.z), 0.f));
                pk.w = f2bf(fmaxf(fmaf(a3, inv, bb.w), 0.f));
                *(ushort4*)&hout[node * 64 + 4 * f] = pk;
            }
        } else {
            // generic path (deg > 64): statistically never hit
            float sdi = Ts1dL[cidx[node]];
            float m = -FLT_MAX;
            for (int j = row + lane; j < end; j += 64) {
                float ee = Ts1sL[cidx[col[j]]] + sdi;
                ee = (ee >= 0.f) ? ee : NEG_SLOPE * ee;
                m = fmaxf(m, ee);
            }
#pragma unroll
            for (int off = 32; off >= 1; off >>= 1) m = fmaxf(m, __shfl_xor(m, off));
            float denom = 0.f;
            for (int j = row + lane; j < end; j += 64) {
                float ee = Ts1sL[cidx[col[j]]] + sdi;
                ee = (ee >= 0.f) ? ee : NEG_SLOPE * ee;
                denom += __expf(ee - m);
            }
#pragma unroll
            for (int off = 32; off >= 1; off >>= 1) denom += __shfl_xor(denom, off);
            float inv = 1.f / denom;
            float acc = 0.f;
            for (int j = row; j < end; ++j) {
                int idxj = cidx[col[j]];
                float ee = Ts1sL[idxj] + sdi;
                ee = (ee >= 0.f) ? ee : NEG_SLOPE * ee;
                float w = __expf(ee - m) * inv * TsclL[idxj];
                unsigned wv = TqL[idxj * 16 + (lane >> 2)];
                int bq = (int)(signed char)((wv >> ((lane & 3) * 8)) & 255);
                acc = fmaf(w, (float)bq, acc);
            }
            hout[node * 64 + lane] = f2bf(fmaxf(acc + bias[lane], 0.f));
        }
    }
}

// ---------------- layer-2 GEMM: scores + z = h2 @ W_out (8 B per node!) ----------------

__global__ __launch_bounds__(256) void k_gemm2(
    const unsigned* __restrict__ h32, const float* __restrict__ W,
    const float* __restrict__ a_s, const float* __restrict__ a_d,
    const float* __restrict__ W_out,
    float2* __restrict__ z2, float* __restrict__ s_src, float* __restrict__ s_dst)
{
    __shared__ float Wl[64 * 64];
    __shared__ float hT[64 * 68];  // [k][r], pitch 68
    int t = threadIdx.x;
    int r0 = blockIdx.x * 64;

    for (int i = t; i < 4096; i += 256) Wl[i] = W[i];
    for (int i = t; i < 2048; i += 256) {
        int r = i >> 5, m = i & 31;
        int row = r0 + r;
        unsigned u = (row < N_NODES) ? h32[row * 32 + m] : 0u;
        hT[(2 * m) * 68 + r]     = blo(u);
        hT[(2 * m + 1) * 68 + r] = bhi(u);
    }
    __syncthreads();

    int tcol = t & 15;
    int trow = t >> 4;
    float acc[4][4];
#pragma unroll
    for (int i = 0; i < 4; ++i)
#pragma unroll
        for (int j = 0; j < 4; ++j) acc[i][j] = 0.f;

    for (int k = 0; k < 64; ++k) {
        float4 va = *(const float4*)&hT[k * 68 + trow * 4];
        float4 vb = *(const float4*)&Wl[k * 64 + tcol * 4];
        float a[4] = {va.x, va.y, va.z, va.w};
        float bb[4] = {vb.x, vb.y, vb.z, vb.w};
#pragma unroll
        for (int i = 0; i < 4; ++i)
#pragma unroll
            for (int j = 0; j < 4; ++j) acc[i][j] = fmaf(a[i], bb[j], acc[i][j]);
    }

    float4 as4 = *(const float4*)&a_s[tcol * 4];
    float4 ad4 = *(const float4*)&a_d[tcol * 4];
    float asr[4] = {as4.x, as4.y, as4.z, as4.w};
    float adr[4] = {ad4.x, ad4.y, ad4.z, ad4.w};
    float4 wa = *(const float4*)&W_out[8 * tcol];      // rows 4t, 4t+1
    float4 wb = *(const float4*)&W_out[8 * tcol + 4];  // rows 4t+2, 4t+3

#pragma unroll
    for (int i = 0; i < 4; ++i) {
        int row = r0 + trow * 4 + i;
        float ps = 0.f, pd = 0.f;
#pragma unroll
        for (int j = 0; j < 4; ++j) {
            ps = fmaf(acc[i][j], asr[j], ps);
            pd = fmaf(acc[i][j], adr[j], pd);
        }
        float z0 = acc[i][0] * wa.x + acc[i][1] * wa.z + acc[i][2] * wb.x + acc[i][3] * wb.z;
        float z1 = acc[i][0] * wa.y + acc[i][1] * wa.w + acc[i][2] * wb.y + acc[i][3] * wb.w;
#pragma unroll
        for (int off = 8; off >= 1; off >>= 1) {
            ps += __shfl_xor(ps, off);
            pd += __shfl_xor(pd, off);
            z0 += __shfl_xor(z0, off);
            z1 += __shfl_xor(z1, off);
        }
        if (row < N_NODES && tcol == 0) {
            s_src[row] = ps; s_dst[row] = pd;
            z2[row] = make_float2(z0, z1);
        }
    }
}

// ---------------- last-layer agg + pool: gather 8-B z instead of 64-B rows ----------------

__global__ __launch_bounds__(256) void k_pool2(
    const float2* __restrict__ z2, const int* __restrict__ col,
    const int* __restrict__ rowptr, const float* __restrict__ s_src_in,
    const float* __restrict__ s_dst_in, const int* __restrict__ batch,
    float* __restrict__ pool_acc)
{
    int wave = threadIdx.x >> 6;
    int lane = threadIdx.x & 63;
    int node = blockIdx.x * 4 + wave;
    if (node >= N_NODES) return;

    int row = rowptr[node];
    int end = rowptr[node + 1];
    int deg = end - row;
    float sdi = s_dst_in[node];
    float* rep = pool_acc + (blockIdx.x & (NREP - 1)) * REP_STRIDE;

    float num0, num1, den;
    if (deg <= 64) {
        float p = 0.f;
        float2 zv = make_float2(0.f, 0.f);
        if (lane < deg) {
            int c = col[row + lane];
            float ee = s_src_in[c] + sdi;
            ee = (ee >= 0.f) ? ee : NEG_SLOPE * ee;
            p = __expf(ee);
            zv = z2[c];
        }
        num0 = p * zv.x; num1 = p * zv.y; den = p;
    } else {
        num0 = num1 = den = 0.f;
        for (int j = row + lane; j < end; j += 64) {
            int c = col[j];
            float ee = s_src_in[c] + sdi;
            ee = (ee >= 0.f) ? ee : NEG_SLOPE * ee;
            float p = __expf(ee);
            float2 zv = z2[c];
            num0 = fmaf(p, zv.x, num0);
            num1 = fmaf(p, zv.y, num1);
            den += p;
        }
    }
#pragma unroll
    for (int off = 32; off >= 1; off >>= 1) {
        num0 += __shfl_xor(num0, off);
        num1 += __shfl_xor(num1, off);
        den += __shfl_xor(den, off);
    }
    if (lane == 0) {
        float inv = 1.f / den;
        int g = batch[node];
        atomicAdd(&rep[g * 2], num0 * inv);
        atomicAdd(&rep[g * 2 + 1], num1 * inv);
    }
}

// ---------------- head: reduce replicas, divide by count, add consts ----------------

__device__ __forceinline__ int lower_bound_dev(const int* __restrict__ a, int n, int v) {
    int lo = 0, hi = n;
    while (lo < hi) {
        int mid = (lo + hi) >> 1;
        if (a[mid] < v) lo = mid + 1; else hi = mid;
    }
    return lo;
}

__global__ void k_head(const float* __restrict__ pool_acc,
                       const int* __restrict__ batch,
                       const float* __restrict__ b_out,
                       const float* __restrict__ sparams,
                       float* __restrict__ out)
{
    int t = threadIdx.x;
    if (t < 2 * N_GRAPHS) {
        float s = 0.f;
#pragma unroll 8
        for (int r = 0; r < NREP; ++r) s += pool_acc[r * REP_STRIDE + t];
        int g = t >> 1, c = t & 1;
        int start = lower_bound_dev(batch, N_NODES, g);
        int end = lower_bound_dev(batch, N_NODES, g + 1);
        float cnt = fmaxf((float)(end - start), 1.f);
        out[t] = s / cnt + sparams[4 + c] + b_out[c];
    }
}

// ---------------- launch ----------------

extern "C" void kernel_launch(void* const* d_in, const int* in_sizes, int n_in,
                              void* d_out, int out_size, void* d_ws, size_t ws_size,
                              hipStream_t stream) {
    const int*   x       = (const int*)d_in[0];
    const int*   edge    = (const int*)d_in[1];   // [2][E]
    const int*   batch   = (const int*)d_in[2];
    const float* embed   = (const float*)d_in[3];
    const float* Ws      = (const float*)d_in[4];
    const float* a_srcs  = (const float*)d_in[5];
    const float* a_dsts  = (const float*)d_in[6];
    const float* biases  = (const float*)d_in[7];
    const float* W_out   = (const float*)d_in[8];
    const float* b_out   = (const float*)d_in[9];
    float* out = (float*)d_out;

    char* ws = (char*)d_ws;
    size_t off = 0;
    auto alloc = [&](size_t bytes) -> void* {
        void* p = ws + off;
        off += (bytes + 255) & ~(size_t)255;
        return p;
    };
    unsigned short* hout  = (unsigned short*)alloc((size_t)N_NODES * 64 * sizeof(unsigned short));
    float2* z2      = (float2*)alloc((size_t)N_NODES * sizeof(float2));
    float* s_src0   = (float*)alloc((size_t)N_NODES * sizeof(float));
    float* s_dst0   = (float*)alloc((size_t)N_NODES * sizeof(float));
    unsigned short* cidx = (unsigned short*)alloc((size_t)N_NODES * sizeof(unsigned short));
    int*   rowptr   = (int*)alloc((size_t)(N_NODES + 1) * sizeof(int));
    int*   colA     = (int*)alloc((size_t)ETOT * sizeof(int));
    int*   blockcnt = (int*)alloc((size_t)PAIR_BLOCKS * NB * sizeof(int));
    int*   btot     = (int*)alloc((size_t)NB * sizeof(int));
    int*   pstart   = (int*)alloc((size_t)(NB + 1) * sizeof(int));
    float* pool_acc = (float*)alloc((size_t)(NREP * REP_STRIDE) * sizeof(float));
    unsigned* xb    = (unsigned*)alloc((size_t)3200 * sizeof(unsigned));
    unsigned char* Tq8 = (unsigned char*)alloc((size_t)NLVL * 64);
    float* Tscl     = (float*)alloc((size_t)NLVL * sizeof(float));
    float* Ts1s     = (float*)alloc((size_t)NLVL * sizeof(float));
    float* Ts1d     = (float*)alloc((size_t)NLVL * sizeof(float));
    float* sparams  = (float*)alloc((size_t)8 * sizeof(float));
    int*   pairs    = (int*)alloc((size_t)N_EDGES * sizeof(int));  // dead after CSR build

    const int* e0 = edge;
    const int* e1 = edge + N_EDGES;

    // x bitmask + weight-only table (independent of graph)
    k_xbit<<<(N_NODES + 255) / 256, 256, 0, stream>>>(x, xb);
    k_table<<<NLVL, 64, 0, stream>>>(embed, Ws, biases, a_srcs, a_dsts, W_out,
                                     Tq8, Tscl, Ts1s, Ts1d, sparams);
    // bucketed CSR build (by dst, self loops at slot 0; emits cidx inline)
    k_count<<<PAIR_BLOCKS, 256, 0, stream>>>(e1, blockcnt, pool_acc);
    k_scan_bases<<<NB, 64, 0, stream>>>(blockcnt, btot);
    k_scan_buckets<<<1, 256, 0, stream>>>(btot, pstart);
    k_pair_scatter<<<PAIR_BLOCKS, 256, 0, stream>>>(e0, e1, xb, blockcnt, pstart, pairs);
    k_csr_bucket<<<NB, 512, 0, stream>>>(pairs, pstart, x, sparams, rowptr, colA, cidx);

    // layer 1: table-based aggregation -> bf16 hout
    k_agg1<<<1024, 256, 0, stream>>>(Tq8, Tscl, Ts1s, Ts1d, cidx, colA, rowptr,
                                     biases + 64, hout);
    // layer 2: GEMM -> scores + z (h2 @ W_out), then 8-B-gather pool
    k_gemm2<<<(N_NODES + 63) / 64, 256, 0, stream>>>(
        (const unsigned*)hout, Ws + 8192, a_srcs + 128, a_dsts + 128, W_out,
        z2, s_src0, s_dst0);
    k_pool2<<<(N_NODES + 3) / 4, 256, 0, stream>>>(
        z2, colA, rowptr, s_src0, s_dst0, batch, pool_acc);
    k_head<<<1, 256, 0, stream>>>(pool_acc, batch, b_out, sparams, out);
}

// Round 14
// 245.079 us; speedup vs baseline: 1.8337x; 1.0324x over previous
//
#include <hip/hip_runtime.h>
#include <hip/hip_bf16.h>
#include <float.h>

#define N_NODES 100000
#define N_EDGES 1600000
#define HIDDEN 64
#define N_GRAPHS 128
#define NEG_SLOPE 0.2f
#define ETOT (N_EDGES + N_NODES)

#define BSHIFT 9
#define NB ((N_NODES + 511) >> BSHIFT)    // 196 buckets of 512 nodes
#define PAIR_CHUNK 4096
#define PAIR_BLOCKS ((N_EDGES + PAIR_CHUNK - 1) / PAIR_CHUNK)  // 391

#define NREP 64           // pool accumulator replicas (atomic contention spreading)
#define REP_STRIDE 272    // 256 floats + 16 pad
#define NLVL 512          // c1 quantization levels (layer-1 table)

__device__ __forceinline__ unsigned short f2bf(float f) {
    unsigned u = __float_as_uint(f);
    unsigned r = (u + 0x7FFFu + ((u >> 16) & 1u)) >> 16;  // RNE
    return (unsigned short)r;
}
__device__ __forceinline__ float blo(unsigned u) { return __uint_as_float(u << 16); }
__device__ __forceinline__ float bhi(unsigned u) { return __uint_as_float(u & 0xFFFF0000u); }
__device__ __forceinline__ int sb0(unsigned u) { return (int)((unsigned)(u << 24)) >> 24; }
__device__ __forceinline__ int sb1(unsigned u) { return (int)((unsigned)(u << 16)) >> 24; }
__device__ __forceinline__ int sb2(unsigned u) { return (int)((unsigned)(u << 8)) >> 24; }
__device__ __forceinline__ int sb3(unsigned u) { return (int)u >> 24; }

// ---------------- x bitmask ----------------

__global__ __launch_bounds__(256) void k_xbit(const int* __restrict__ x,
                                              unsigned* __restrict__ xb) {
    int i = blockIdx.x * blockDim.x + threadIdx.x;
    int lane = threadIdx.x & 63;
    bool b = (i < N_NODES) && (x[i] != 0);
    unsigned long long m = __ballot(b);
    int wid = i >> 6;
    if (lane == 0) xb[wid * 2] = (unsigned)m;
    if (lane == 32) xb[wid * 2 + 1] = (unsigned)(m >> 32);
}

// ---------------- CSR build: per-chunk bucket counts (also zeroes pool_acc) ----------------

__global__ __launch_bounds__(256) void k_count(const int* __restrict__ e1,
                                               int* __restrict__ blockcnt,
                                               float* __restrict__ pool_acc) {
    __shared__ int h[NB];
    int t = threadIdx.x, b = blockIdx.x;
    if (t < NB) h[t] = 0;
    if (b < NREP && t < 2 * N_GRAPHS) pool_acc[b * REP_STRIDE + t] = 0.f;
    __syncthreads();
    int ebase = b * PAIR_CHUNK;
    int ecount = min(PAIR_CHUNK, N_EDGES - ebase);
    for (int i = t; i < ecount; i += 256)
        atomicAdd(&h[e1[ebase + i] >> BSHIFT], 1);
    __syncthreads();
    if (t < NB) blockcnt[b * NB + t] = h[t];
}

__global__ __launch_bounds__(64) void k_scan_bases(int* __restrict__ blockcnt,
                                                   int* __restrict__ btot) {
    int b = blockIdx.x;
    int lane = threadIdx.x;
    int s = 0;
    for (int base = 0; base < PAIR_BLOCKS; base += 64) {
        int c = base + lane;
        int v = (c < PAIR_BLOCKS) ? blockcnt[c * NB + b] : 0;
        int xv = v;
#pragma unroll
        for (int off = 1; off < 64; off <<= 1) {
            int y = __shfl_up(xv, off);
            if (lane >= off) xv += y;
        }
        if (c < PAIR_BLOCKS) blockcnt[c * NB + b] = s + xv - v;
        s += __shfl(xv, 63);
    }
    if (lane == 0) btot[b] = s;
}

__global__ void k_scan_buckets(const int* __restrict__ btot, int* __restrict__ pair_start) {
    __shared__ int tot[256];
    int t = threadIdx.x;
    int v = (t < NB) ? btot[t] : 0;
    tot[t] = v;
    __syncthreads();
    for (int off = 1; off < 256; off <<= 1) {
        int u = (t >= off) ? tot[t - off] : 0;
        __syncthreads();
        tot[t] += u;
        __syncthreads();
    }
    if (t < NB) pair_start[t] = tot[t] - v;
    if (t == 0) pair_start[NB] = N_EDGES;
}

__global__ __launch_bounds__(256) void k_pair_scatter(
    const int* __restrict__ e0, const int* __restrict__ e1,
    const unsigned* __restrict__ xb,
    const int* __restrict__ blockcnt, const int* __restrict__ pair_start,
    int* __restrict__ pairs)
{
    __shared__ int cnt[NB];
    __shared__ int base[NB];
    int t = threadIdx.x, b = blockIdx.x;
    if (t < NB) {
        cnt[t] = 0;
        base[t] = pair_start[t] + blockcnt[b * NB + t];
    }
    __syncthreads();
    int ebase = b * PAIR_CHUNK;
    int ecount = min(PAIR_CHUNK, N_EDGES - ebase);
    for (int i = t; i < ecount; i += 256) {
        int s = e0[ebase + i];
        int d = e1[ebase + i];
        int xv = (xb[s >> 5] >> (s & 31)) & 1;
        int B = d >> BSHIFT;
        int idx = atomicAdd(&cnt[B], 1);
        pairs[base[B] + idx] = (xv << 26) | ((d & 511) << 17) | s;  // x|9b dst|17b src
    }
}

// One block (512 thr) per bucket. Self loop at slot 0.
// Pass 1 packs degree (lo16) + x-count (hi16) in one atomic; emits cidx inline.
__global__ __launch_bounds__(512) void k_csr_bucket(
    const int* __restrict__ pairs, const int* __restrict__ pair_start,
    const int* __restrict__ x, const float* __restrict__ sparams,
    int* __restrict__ rowptr, int* __restrict__ col,
    unsigned short* __restrict__ cidx)
{
    __shared__ int deg[512];
    __shared__ int excl[512];
    __shared__ int cnt2[512];
    __shared__ int wsum[8];
    int b = blockIdx.x;
    int t = threadIdx.x;
    int nb = b << BSHIFT;
    int nodes = min(512, N_NODES - nb);

    int xself = (t < nodes) ? (x[nb + t] & 1) : 0;
    deg[t] = (t < nodes) ? (1 | (xself << 16)) : 0;   // self loop contributes
    cnt2[t] = 1;  // scatter counter starts past self-loop slot
    __syncthreads();
    int p0 = pair_start[b], p1 = pair_start[b + 1];
    for (int i = p0 + t; i < p1; i += 512) {
        int p = pairs[i];
        atomicAdd(&deg[(p >> 17) & 511], 1 | (((p >> 26) & 1) << 16));
    }
    __syncthreads();

    int packed = deg[t];
    int val = packed & 0xFFFF;          // degree incl self loop
    int kx = packed >> 16;              // #neighbors with x=1 (incl self)
    if (t < nodes) {
        float ss0 = sparams[0], ss1 = sparams[1];
        float sd = xself ? sparams[3] : sparams[2];
        float e0 = ss0 + sd; e0 = (e0 >= 0.f) ? e0 : NEG_SLOPE * e0;
        float e1 = ss1 + sd; e1 = (e1 >= 0.f) ? e1 : NEG_SLOPE * e1;
        float pp0 = __expf(e0), pp1 = __expf(e1);
        float kn = (float)kx, dn = (float)(val - kx);
        float c1 = kn * pp1 / (dn * pp0 + kn * pp1);
        cidx[nb + t] = (unsigned short)__float2int_rn(c1 * (float)(NLVL - 1));
    }

    int xx = val;
#pragma unroll
    for (int off = 1; off < 64; off <<= 1) {
        int y = __shfl_up(xx, off);
        if ((t & 63) >= off) xx += y;
    }
    if ((t & 63) == 63) wsum[t >> 6] = xx;
    __syncthreads();
    if (t == 0) {
        int s = 0;
#pragma unroll
        for (int i = 0; i < 8; ++i) { int v = wsum[i]; wsum[i] = s; s += v; }
    }
    __syncthreads();
    int ex = xx - val + wsum[t >> 6];
    excl[t] = ex;

    int colbase = p0 + nb;
    if (t < nodes) {
        rowptr[nb + t] = colbase + ex;
        col[colbase + ex] = nb + t;  // self loop at slot 0
    }
    if (b == NB - 1 && t == 0) rowptr[N_NODES] = ETOT;
    __syncthreads();
    for (int i = p0 + t; i < p1; i += 512) {
        int p = pairs[i];
        int li = (p >> 17) & 511;
        int pos = colbase + excl[li] + atomicAdd(&cnt2[li], 1);
        col[pos] = p & 0x1FFFF;
    }
}

// ---------------- layer-1 table build + layer-0 score scalars + head const ----------------

__global__ __launch_bounds__(64) void k_table(
    const float* __restrict__ embed, const float* __restrict__ Ws,
    const float* __restrict__ biases, const float* __restrict__ a_srcs,
    const float* __restrict__ a_dsts, const float* __restrict__ W_out,
    unsigned char* __restrict__ Tq8, float* __restrict__ Tscl,
    float* __restrict__ Ts1s, float* __restrict__ Ts1d,
    float* __restrict__ sparams)
{
    __shared__ float o[64];
    int f = threadIdx.x;
    int l = blockIdx.x;
    float r0 = 0.f, r1 = 0.f;
#pragma unroll 8
    for (int k = 0; k < 64; ++k) {
        float w = Ws[k * 64 + f];
        r0 = fmaf(embed[k], w, r0);
        r1 = fmaf(embed[64 + k], w, r1);
    }
    if (l == 0) {  // layer-0 score scalars ss0, ss1, sd0, sd1
        float as = a_srcs[f], ad = a_dsts[f];
        float t0 = r0 * as, t1 = r1 * as, t2 = r0 * ad, t3 = r1 * ad;
#pragma unroll
        for (int off = 32; off >= 1; off >>= 1) {
            t0 += __shfl_xor(t0, off); t1 += __shfl_xor(t1, off);
            t2 += __shfl_xor(t2, off); t3 += __shfl_xor(t3, off);
        }
        if (f == 0) { sparams[0] = t0; sparams[1] = t1; sparams[2] = t2; sparams[3] = t3; }
    }
    if (l == 1) {  // head constant: b2 @ W_out
        float b2 = biases[128 + f];
        float t4 = b2 * W_out[f * 2];
        float t5 = b2 * W_out[f * 2 + 1];
#pragma unroll
        for (int off = 32; off >= 1; off >>= 1) {
            t4 += __shfl_xor(t4, off); t5 += __shfl_xor(t5, off);
        }
        if (f == 0) { sparams[4] = t4; sparams[5] = t5; }
    }
    float c1 = (float)l * (1.f / (NLVL - 1));
    o[f] = fmaxf(biases[f] + r0 + c1 * (r1 - r0), 0.f);
    __syncthreads();
    const float* W1 = Ws + 4096;
    float h = 0.f;
#pragma unroll 8
    for (int k = 0; k < 64; ++k) h = fmaf(o[k], W1[k * 64 + f], h);
    float ss = h * a_srcs[64 + f];
    float sd = h * a_dsts[64 + f];
    float am = fabsf(h);
#pragma unroll
    for (int off = 32; off >= 1; off >>= 1) {
        ss += __shfl_xor(ss, off);
        sd += __shfl_xor(sd, off);
        am = fmaxf(am, __shfl_xor(am, off));
    }
    float iscl = (am > 0.f) ? 127.f / am : 0.f;
    Tq8[l * 64 + f] = (unsigned char)(__float2int_rn(h * iscl) & 255);
    if (f == 0) { Tscl[l] = am * (1.f / 127.f); Ts1s[l] = ss; Ts1d[l] = sd; }
}

// ---------------- layer-1 agg: table reads through L1 (32 KB table, no LDS staging) ----------------
// LDS = 2 KB stash only -> full occupancy, zero bank conflicts.

__global__ __launch_bounds__(256) void k_agg1(
    const unsigned char* __restrict__ Tq8, const float* __restrict__ Tscl,
    const float* __restrict__ Ts1s, const float* __restrict__ Ts1d,
    const unsigned short* __restrict__ cidx, const int* __restrict__ col,
    const int* __restrict__ rowptr, const float* __restrict__ bias,
    unsigned short* __restrict__ hout)
{
    __shared__ float2 stash[4][64];
    int t = threadIdx.x;
    int wave = t >> 6, lane = t & 63;
    int node = blockIdx.x * 4 + wave;
    if (node >= N_NODES) return;
    const char* hb = (const char*)Tq8;

    int row = rowptr[node], end = rowptr[node + 1];
    int deg = end - row;
    if (deg <= 64) {
        int idx = 0;
        float p = 0.f, sc = 0.f;
        if (lane < deg) idx = cidx[col[row + lane]];
        float sdi = Ts1d[__shfl(idx, 0)];   // slot 0 = self loop
        if (lane < deg) {
            float ee = Ts1s[idx] + sdi;
            ee = (ee >= 0.f) ? ee : NEG_SLOPE * ee;
            p = __expf(ee);
            sc = Tscl[idx];
        }
        stash[wave][lane] = make_float2(p * sc, __int_as_float(idx * 64));

        int q = lane >> 4;
        int f = lane & 15;
        int f4 = f * 4;
        float a0 = 0.f, a1 = 0.f, a2 = 0.f, a3 = 0.f;
        int degr = (deg + 15) & ~15;
        for (int j = q; j < degr; j += 16) {
            float2 e0 = stash[wave][j];
            float2 e1 = stash[wave][j + 4];
            float2 e2 = stash[wave][j + 8];
            float2 e3 = stash[wave][j + 12];
            unsigned v0 = *(const unsigned*)(hb + (__float_as_int(e0.y) + f4));
            unsigned v1 = *(const unsigned*)(hb + (__float_as_int(e1.y) + f4));
            unsigned v2 = *(const unsigned*)(hb + (__float_as_int(e2.y) + f4));
            unsigned v3 = *(const unsigned*)(hb + (__float_as_int(e3.y) + f4));
            a0 = fmaf(e0.x, (float)sb0(v0), a0);
            a1 = fmaf(e0.x, (float)sb1(v0), a1);
            a2 = fmaf(e0.x, (float)sb2(v0), a2);
            a3 = fmaf(e0.x, (float)sb3(v0), a3);
            a0 = fmaf(e1.x, (float)sb0(v1), a0);
            a1 = fmaf(e1.x, (float)sb1(v1), a1);
            a2 = fmaf(e1.x, (float)sb2(v1), a2);
            a3 = fmaf(e1.x, (float)sb3(v1), a3);
            a0 = fmaf(e2.x, (float)sb0(v2), a0);
            a1 = fmaf(e2.x, (float)sb1(v2), a1);
            a2 = fmaf(e2.x, (float)sb2(v2), a2);
            a3 = fmaf(e2.x, (float)sb3(v2), a3);
            a0 = fmaf(e3.x, (float)sb0(v3), a0);
            a1 = fmaf(e3.x, (float)sb1(v3), a1);
            a2 = fmaf(e3.x, (float)sb2(v3), a2);
            a3 = fmaf(e3.x, (float)sb3(v3), a3);
        }
        float p2 = p;
        float denom = p2;
#pragma unroll
        for (int off = 32; off >= 1; off >>= 1) denom += __shfl_xor(denom, off);
        float inv = 1.f / denom;
        a0 += __shfl_xor(a0, 16); a0 += __shfl_xor(a0, 32);
        a1 += __shfl_xor(a1, 16); a1 += __shfl_xor(a1, 32);
        a2 += __shfl_xor(a2, 16); a2 += __shfl_xor(a2, 32);
        a3 += __shfl_xor(a3, 16); a3 += __shfl_xor(a3, 32);
        if (lane < 16) {
            float4 bb = *(const float4*)&bias[4 * f];
            ushort4 pk;
            pk.x = f2bf(fmaxf(fmaf(a0, inv, bb.x), 0.f));
            pk.y = f2bf(fmaxf(fmaf(a1, inv, bb.y), 0.f));
            pk.z = f2bf(fmaxf(fmaf(a2, inv, bb.z), 0.f));
            pk.w = f2bf(fmaxf(fmaf(a3, inv, bb.w), 0.f));
            *(ushort4*)&hout[node * 64 + 4 * f] = pk;
        }
    } else {
        // generic path (deg > 64): statistically never hit
        float sdi = Ts1d[cidx[node]];
        float m = -FLT_MAX;
        for (int j = row + lane; j < end; j += 64) {
            float ee = Ts1s[cidx[col[j]]] + sdi;
            ee = (ee >= 0.f) ? ee : NEG_SLOPE * ee;
            m = fmaxf(m, ee);
        }
#pragma unroll
        for (int off = 32; off >= 1; off >>= 1) m = fmaxf(m, __shfl_xor(m, off));
        float denom = 0.f;
        for (int j = row + lane; j < end; j += 64) {
            float ee = Ts1s[cidx[col[j]]] + sdi;
            ee = (ee >= 0.f) ? ee : NEG_SLOPE * ee;
            denom += __expf(ee - m);
        }
#pragma unroll
        for (int off = 32; off >= 1; off >>= 1) denom += __shfl_xor(denom, off);
        float inv = 1.f / denom;
        float acc = 0.f;
        for (int j = row; j < end; ++j) {
            int idxj = cidx[col[j]];
            float ee = Ts1s[idxj] + sdi;
            ee = (ee >= 0.f) ? ee : NEG_SLOPE * ee;
            float w = __expf(ee - m) * inv * Tscl[idxj];
            int bq = (int)(signed char)Tq8[idxj * 64 + lane];
            acc = fmaf(w, (float)bq, acc);
        }
        hout[node * 64 + lane] = f2bf(fmaxf(acc + bias[lane], 0.f));
    }
}

// ---------------- layer-2 GEMM: scores + z = h2 @ W_out (8 B per node) ----------------

__global__ __launch_bounds__(256) void k_gemm2(
    const unsigned* __restrict__ h32, const float* __restrict__ W,
    const float* __restrict__ a_s, const float* __restrict__ a_d,
    const float* __restrict__ W_out,
    float2* __restrict__ z2, float* __restrict__ s_src, float* __restrict__ s_dst)
{
    __shared__ float Wl[64 * 64];
    __shared__ float hT[64 * 68];  // [k][r], pitch 68
    int t = threadIdx.x;
    int r0 = blockIdx.x * 64;

    for (int i = t; i < 4096; i += 256) Wl[i] = W[i];
    for (int i = t; i < 2048; i += 256) {
        int r = i >> 5, m = i & 31;
        int row = r0 + r;
        unsigned u = (row < N_NODES) ? h32[row * 32 + m] : 0u;
        hT[(2 * m) * 68 + r]     = blo(u);
        hT[(2 * m + 1) * 68 + r] = bhi(u);
    }
    __syncthreads();

    int tcol = t & 15;
    int trow = t >> 4;
    float acc[4][4];
#pragma unroll
    for (int i = 0; i < 4; ++i)
#pragma unroll
        for (int j = 0; j < 4; ++j) acc[i][j] = 0.f;

    for (int k = 0; k < 64; ++k) {
        float4 va = *(const float4*)&hT[k * 68 + trow * 4];
        float4 vb = *(const float4*)&Wl[k * 64 + tcol * 4];
        float a[4] = {va.x, va.y, va.z, va.w};
        float bb[4] = {vb.x, vb.y, vb.z, vb.w};
#pragma unroll
        for (int i = 0; i < 4; ++i)
#pragma unroll
            for (int j = 0; j < 4; ++j) acc[i][j] = fmaf(a[i], bb[j], acc[i][j]);
    }

    float4 as4 = *(const float4*)&a_s[tcol * 4];
    float4 ad4 = *(const float4*)&a_d[tcol * 4];
    float asr[4] = {as4.x, as4.y, as4.z, as4.w};
    float adr[4] = {ad4.x, ad4.y, ad4.z, ad4.w};
    float4 wa = *(const float4*)&W_out[8 * tcol];      // rows 4t, 4t+1
    float4 wb = *(const float4*)&W_out[8 * tcol + 4];  // rows 4t+2, 4t+3

#pragma unroll
    for (int i = 0; i < 4; ++i) {
        int row = r0 + trow * 4 + i;
        float ps = 0.f, pd = 0.f;
#pragma unroll
        for (int j = 0; j < 4; ++j) {
            ps = fmaf(acc[i][j], asr[j], ps);
            pd = fmaf(acc[i][j], adr[j], pd);
        }
        float z0 = acc[i][0] * wa.x + acc[i][1] * wa.z + acc[i][2] * wb.x + acc[i][3] * wb.z;
        float z1 = acc[i][0] * wa.y + acc[i][1] * wa.w + acc[i][2] * wb.y + acc[i][3] * wb.w;
#pragma unroll
        for (int off = 8; off >= 1; off >>= 1) {
            ps += __shfl_xor(ps, off);
            pd += __shfl_xor(pd, off);
            z0 += __shfl_xor(z0, off);
            z1 += __shfl_xor(z1, off);
        }
        if (row < N_NODES && tcol == 0) {
            s_src[row] = ps; s_dst[row] = pd;
            z2[row] = make_float2(z0, z1);
        }
    }
}

// ---------------- last-layer agg + pool: gather 8-B z ----------------

__global__ __launch_bounds__(256) void k_pool2(
    const float2* __restrict__ z2, const int* __restrict__ col,
    const int* __restrict__ rowptr, const float* __restrict__ s_src_in,
    const float* __restrict__ s_dst_in, const int* __restrict__ batch,
    float* __restrict__ pool_acc)
{
    int wave = threadIdx.x >> 6;
    int lane = threadIdx.x & 63;
    int node = blockIdx.x * 4 + wave;
    if (node >= N_NODES) return;

    int row = rowptr[node];
    int end = rowptr[node + 1];
    int deg = end - row;
    float sdi = s_dst_in[node];
    float* rep = pool_acc + (blockIdx.x & (NREP - 1)) * REP_STRIDE;

    float num0, num1, den;
    if (deg <= 64) {
        float p = 0.f;
        float2 zv = make_float2(0.f, 0.f);
        if (lane < deg) {
            int c = col[row + lane];
            float ee = s_src_in[c] + sdi;
            ee = (ee >= 0.f) ? ee : NEG_SLOPE * ee;
            p = __expf(ee);
            zv = z2[c];
        }
        num0 = p * zv.x; num1 = p * zv.y; den = p;
    } else {
        num0 = num1 = den = 0.f;
        for (int j = row + lane; j < end; j += 64) {
            int c = col[j];
            float ee = s_src_in[c] + sdi;
            ee = (ee >= 0.f) ? ee : NEG_SLOPE * ee;
            float p = __expf(ee);
            float2 zv = z2[c];
            num0 = fmaf(p, zv.x, num0);
            num1 = fmaf(p, zv.y, num1);
            den += p;
        }
    }
#pragma unroll
    for (int off = 32; off >= 1; off >>= 1) {
        num0 += __shfl_xor(num0, off);
        num1 += __shfl_xor(num1, off);
        den += __shfl_xor(den, off);
    }
    if (lane == 0) {
        float inv = 1.f / den;
        int g = batch[node];
        atomicAdd(&rep[g * 2], num0 * inv);
        atomicAdd(&rep[g * 2 + 1], num1 * inv);
    }
}

// ---------------- head: reduce replicas, divide by count, add consts ----------------

__device__ __forceinline__ int lower_bound_dev(const int* __restrict__ a, int n, int v) {
    int lo = 0, hi = n;
    while (lo < hi) {
        int mid = (lo + hi) >> 1;
        if (a[mid] < v) lo = mid + 1; else hi = mid;
    }
    return lo;
}

__global__ void k_head(const float* __restrict__ pool_acc,
                       const int* __restrict__ batch,
                       const float* __restrict__ b_out,
                       const float* __restrict__ sparams,
                       float* __restrict__ out)
{
    int t = threadIdx.x;
    if (t < 2 * N_GRAPHS) {
        float s = 0.f;
#pragma unroll 8
        for (int r = 0; r < NREP; ++r) s += pool_acc[r * REP_STRIDE + t];
        int g = t >> 1, c = t & 1;
        int start = lower_bound_dev(batch, N_NODES, g);
        int end = lower_bound_dev(batch, N_NODES, g + 1);
        float cnt = fmaxf((float)(end - start), 1.f);
        out[t] = s / cnt + sparams[4 + c] + b_out[c];
    }
}

// ---------------- launch ----------------

extern "C" void kernel_launch(void* const* d_in, const int* in_sizes, int n_in,
                              void* d_out, int out_size, void* d_ws, size_t ws_size,
                              hipStream_t stream) {
    const int*   x       = (const int*)d_in[0];
    const int*   edge    = (const int*)d_in[1];   // [2][E]
    const int*   batch   = (const int*)d_in[2];
    const float* embed   = (const float*)d_in[3];
    const float* Ws      = (const float*)d_in[4];
    const float* a_srcs  = (const float*)d_in[5];
    const float* a_dsts  = (const float*)d_in[6];
    const float* biases  = (const float*)d_in[7];
    const float* W_out   = (const float*)d_in[8];
    const float* b_out   = (const float*)d_in[9];
    float* out = (float*)d_out;

    char* ws = (char*)d_ws;
    size_t off = 0;
    auto alloc = [&](size_t bytes) -> void* {
        void* p = ws + off;
        off += (bytes + 255) & ~(size_t)255;
        return p;
    };
    unsigned short* hout  = (unsigned short*)alloc((size_t)N_NODES * 64 * sizeof(unsigned short));
    float2* z2      = (float2*)alloc((size_t)N_NODES * sizeof(float2));
    float* s_src0   = (float*)alloc((size_t)N_NODES * sizeof(float));
    float* s_dst0   = (float*)alloc((size_t)N_NODES * sizeof(float));
    unsigned short* cidx = (unsigned short*)alloc((size_t)N_NODES * sizeof(unsigned short));
    int*   rowptr   = (int*)alloc((size_t)(N_NODES + 1) * sizeof(int));
    int*   colA     = (int*)alloc((size_t)ETOT * sizeof(int));
    int*   blockcnt = (int*)alloc((size_t)PAIR_BLOCKS * NB * sizeof(int));
    int*   btot     = (int*)alloc((size_t)NB * sizeof(int));
    int*   pstart   = (int*)alloc((size_t)(NB + 1) * sizeof(int));
    float* pool_acc = (float*)alloc((size_t)(NREP * REP_STRIDE) * sizeof(float));
    unsigned* xb    = (unsigned*)alloc((size_t)3200 * sizeof(unsigned));
    unsigned char* Tq8 = (unsigned char*)alloc((size_t)NLVL * 64);
    float* Tscl     = (float*)alloc((size_t)NLVL * sizeof(float));
    float* Ts1s     = (float*)alloc((size_t)NLVL * sizeof(float));
    float* Ts1d     = (float*)alloc((size_t)NLVL * sizeof(float));
    float* sparams  = (float*)alloc((size_t)8 * sizeof(float));
    int*   pairs    = (int*)alloc((size_t)N_EDGES * sizeof(int));  // dead after CSR build

    const int* e0 = edge;
    const int* e1 = edge + N_EDGES;

    // x bitmask + weight-only table (independent of graph)
    k_xbit<<<(N_NODES + 255) / 256, 256, 0, stream>>>(x, xb);
    k_table<<<NLVL, 64, 0, stream>>>(embed, Ws, biases, a_srcs, a_dsts, W_out,
                                     Tq8, Tscl, Ts1s, Ts1d, sparams);
    // bucketed CSR build (by dst, self loops at slot 0; emits cidx inline)
    k_count<<<PAIR_BLOCKS, 256, 0, stream>>>(e1, blockcnt, pool_acc);
    k_scan_bases<<<NB, 64, 0, stream>>>(blockcnt, btot);
    k_scan_buckets<<<1, 256, 0, stream>>>(btot, pstart);
    k_pair_scatter<<<PAIR_BLOCKS, 256, 0, stream>>>(e0, e1, xb, blockcnt, pstart, pairs);
    k_csr_bucket<<<NB, 512, 0, stream>>>(pairs, pstart, x, sparams, rowptr, colA, cidx);

    // layer 1: table-based aggregation (tables via L1) -> bf16 hout
    k_agg1<<<(N_NODES + 3) / 4, 256, 0, stream>>>(
        Tq8, Tscl, Ts1s, Ts1d, cidx, colA, rowptr, biases + 64, hout);
    // layer 2: GEMM -> scores + z (h2 @ W_out), then 8-B-gather pool
    k_gemm2<<<(N_NODES + 63) / 64, 256, 0, stream>>>(
        (const unsigned*)hout, Ws + 8192, a_srcs + 128, a_dsts + 128, W_out,
        z2, s_src0, s_dst0);
    k_pool2<<<(N_NODES + 3) / 4, 256, 0, stream>>>(
        z2, colA, rowptr, s_src0, s_dst0, batch, pool_acc);
    k_head<<<1, 256, 0, stream>>>(pool_acc, batch, b_out, sparams, out);
}

// Round 15
// 223.922 us; speedup vs baseline: 2.0069x; 1.0945x over previous
//
#include <hip/hip_runtime.h>
#include <hip/hip_bf16.h>
#include <float.h>

#define N_NODES 100000
#define N_EDGES 1600000
#define HIDDEN 64
#define N_GRAPHS 128
#define NEG_SLOPE 0.2f
#define ETOT (N_EDGES + N_NODES)

#define BSHIFT 9
#define NB ((N_NODES + 511) >> BSHIFT)    // 196 buckets of 512 nodes
#define PAIR_CHUNK 4096
#define PAIR_BLOCKS ((N_EDGES + PAIR_CHUNK - 1) / PAIR_CHUNK)  // 391

#define NREP 64           // pool accumulator replicas (atomic contention spreading)
#define REP_STRIDE 272    // 256 floats + 16 pad
#define NLVL 512          // c1 quantization levels (layer-1 table)

__device__ __forceinline__ unsigned short f2bf(float f) {
    unsigned u = __float_as_uint(f);
    unsigned r = (u + 0x7FFFu + ((u >> 16) & 1u)) >> 16;  // RNE
    return (unsigned short)r;
}
__device__ __forceinline__ float blo(unsigned u) { return __uint_as_float(u << 16); }
__device__ __forceinline__ float bhi(unsigned u) { return __uint_as_float(u & 0xFFFF0000u); }
__device__ __forceinline__ int sb0(unsigned u) { return (int)((unsigned)(u << 24)) >> 24; }
__device__ __forceinline__ int sb1(unsigned u) { return (int)((unsigned)(u << 16)) >> 24; }
__device__ __forceinline__ int sb2(unsigned u) { return (int)((unsigned)(u << 8)) >> 24; }
__device__ __forceinline__ int sb3(unsigned u) { return (int)u >> 24; }

// ---------------- x bitmask ----------------

__global__ __launch_bounds__(256) void k_xbit(const int* __restrict__ x,
                                              unsigned* __restrict__ xb) {
    int i = blockIdx.x * blockDim.x + threadIdx.x;
    int lane = threadIdx.x & 63;
    bool b = (i < N_NODES) && (x[i] != 0);
    unsigned long long m = __ballot(b);
    int wid = i >> 6;
    if (lane == 0) xb[wid * 2] = (unsigned)m;
    if (lane == 32) xb[wid * 2 + 1] = (unsigned)(m >> 32);
}

// ---------------- CSR build: per-chunk bucket counts (also zeroes pool_acc) ----------------

__global__ __launch_bounds__(256) void k_count(const int* __restrict__ e1,
                                               int* __restrict__ blockcnt,
                                               float* __restrict__ pool_acc) {
    __shared__ int h[NB];
    int t = threadIdx.x, b = blockIdx.x;
    if (t < NB) h[t] = 0;
    if (b < NREP && t < 2 * N_GRAPHS) pool_acc[b * REP_STRIDE + t] = 0.f;
    __syncthreads();
    int ebase = b * PAIR_CHUNK;
    int ecount = min(PAIR_CHUNK, N_EDGES - ebase);
    for (int i = t; i < ecount; i += 256)
        atomicAdd(&h[e1[ebase + i] >> BSHIFT], 1);
    __syncthreads();
    if (t < NB) blockcnt[b * NB + t] = h[t];
}

__global__ __launch_bounds__(64) void k_scan_bases(int* __restrict__ blockcnt,
                                                   int* __restrict__ btot) {
    int b = blockIdx.x;
    int lane = threadIdx.x;
    int s = 0;
    for (int base = 0; base < PAIR_BLOCKS; base += 64) {
        int c = base + lane;
        int v = (c < PAIR_BLOCKS) ? blockcnt[c * NB + b] : 0;
        int xv = v;
#pragma unroll
        for (int off = 1; off < 64; off <<= 1) {
            int y = __shfl_up(xv, off);
            if (lane >= off) xv += y;
        }
        if (c < PAIR_BLOCKS) blockcnt[c * NB + b] = s + xv - v;
        s += __shfl(xv, 63);
    }
    if (lane == 0) btot[b] = s;
}

__global__ void k_scan_buckets(const int* __restrict__ btot, int* __restrict__ pair_start) {
    __shared__ int tot[256];
    int t = threadIdx.x;
    int v = (t < NB) ? btot[t] : 0;
    tot[t] = v;
    __syncthreads();
    for (int off = 1; off < 256; off <<= 1) {
        int u = (t >= off) ? tot[t - off] : 0;
        __syncthreads();
        tot[t] += u;
        __syncthreads();
    }
    if (t < NB) pair_start[t] = tot[t] - v;
    if (t == 0) pair_start[NB] = N_EDGES;
}

__global__ __launch_bounds__(256) void k_pair_scatter(
    const int* __restrict__ e0, const int* __restrict__ e1,
    const unsigned* __restrict__ xb,
    const int* __restrict__ blockcnt, const int* __restrict__ pair_start,
    int* __restrict__ pairs)
{
    __shared__ int cnt[NB];
    __shared__ int base[NB];
    int t = threadIdx.x, b = blockIdx.x;
    if (t < NB) {
        cnt[t] = 0;
        base[t] = pair_start[t] + blockcnt[b * NB + t];
    }
    __syncthreads();
    int ebase = b * PAIR_CHUNK;
    int ecount = min(PAIR_CHUNK, N_EDGES - ebase);
    for (int i = t; i < ecount; i += 256) {
        int s = e0[ebase + i];
        int d = e1[ebase + i];
        int xv = (xb[s >> 5] >> (s & 31)) & 1;
        int B = d >> BSHIFT;
        int idx = atomicAdd(&cnt[B], 1);
        pairs[base[B] + idx] = (xv << 26) | ((d & 511) << 17) | s;  // x|9b dst|17b src
    }
}

// One block (512 thr) per bucket. Self loop at slot 0.
// Pass 1 packs degree (lo16) + x-count (hi16) in one atomic; emits cidx inline.
__global__ __launch_bounds__(512) void k_csr_bucket(
    const int* __restrict__ pairs, const int* __restrict__ pair_start,
    const int* __restrict__ x, const float* __restrict__ sparams,
    int* __restrict__ rowptr, int* __restrict__ col,
    unsigned short* __restrict__ cidx)
{
    __shared__ int deg[512];
    __shared__ int excl[512];
    __shared__ int cnt2[512];
    __shared__ int wsum[8];
    int b = blockIdx.x;
    int t = threadIdx.x;
    int nb = b << BSHIFT;
    int nodes = min(512, N_NODES - nb);

    int xself = (t < nodes) ? (x[nb + t] & 1) : 0;
    deg[t] = (t < nodes) ? (1 | (xself << 16)) : 0;   // self loop contributes
    cnt2[t] = 1;  // scatter counter starts past self-loop slot
    __syncthreads();
    int p0 = pair_start[b], p1 = pair_start[b + 1];
    for (int i = p0 + t; i < p1; i += 512) {
        int p = pairs[i];
        atomicAdd(&deg[(p >> 17) & 511], 1 | (((p >> 26) & 1) << 16));
    }
    __syncthreads();

    int packed = deg[t];
    int val = packed & 0xFFFF;          // degree incl self loop
    int kx = packed >> 16;              // #neighbors with x=1 (incl self)
    if (t < nodes) {
        float ss0 = sparams[0], ss1 = sparams[1];
        float sd = xself ? sparams[3] : sparams[2];
        float e0 = ss0 + sd; e0 = (e0 >= 0.f) ? e0 : NEG_SLOPE * e0;
        float e1 = ss1 + sd; e1 = (e1 >= 0.f) ? e1 : NEG_SLOPE * e1;
        float pp0 = __expf(e0), pp1 = __expf(e1);
        float kn = (float)kx, dn = (float)(val - kx);
        float c1 = kn * pp1 / (dn * pp0 + kn * pp1);
        cidx[nb + t] = (unsigned short)__float2int_rn(c1 * (float)(NLVL - 1));
    }

    int xx = val;
#pragma unroll
    for (int off = 1; off < 64; off <<= 1) {
        int y = __shfl_up(xx, off);
        if ((t & 63) >= off) xx += y;
    }
    if ((t & 63) == 63) wsum[t >> 6] = xx;
    __syncthreads();
    if (t == 0) {
        int s = 0;
#pragma unroll
        for (int i = 0; i < 8; ++i) { int v = wsum[i]; wsum[i] = s; s += v; }
    }
    __syncthreads();
    int ex = xx - val + wsum[t >> 6];
    excl[t] = ex;

    int colbase = p0 + nb;
    if (t < nodes) {
        rowptr[nb + t] = colbase + ex;
        col[colbase + ex] = nb + t;  // self loop at slot 0
    }
    if (b == NB - 1 && t == 0) rowptr[N_NODES] = ETOT;
    __syncthreads();
    for (int i = p0 + t; i < p1; i += 512) {
        int p = pairs[i];
        int li = (p >> 17) & 511;
        int pos = colbase + excl[li] + atomicAdd(&cnt2[li], 1);
        col[pos] = p & 0x1FFFF;
    }
}

// ---------------- layer-1 table build + layer-0 score scalars + head const ----------------

__global__ __launch_bounds__(64) void k_table(
    const float* __restrict__ embed, const float* __restrict__ Ws,
    const float* __restrict__ biases, const float* __restrict__ a_srcs,
    const float* __restrict__ a_dsts, const float* __restrict__ W_out,
    unsigned char* __restrict__ Tq8, float* __restrict__ Tscl,
    float* __restrict__ Ts1s, float* __restrict__ Ts1d,
    float* __restrict__ sparams)
{
    __shared__ float o[64];
    int f = threadIdx.x;
    int l = blockIdx.x;
    float r0 = 0.f, r1 = 0.f;
#pragma unroll 8
    for (int k = 0; k < 64; ++k) {
        float w = Ws[k * 64 + f];
        r0 = fmaf(embed[k], w, r0);
        r1 = fmaf(embed[64 + k], w, r1);
    }
    if (l == 0) {  // layer-0 score scalars ss0, ss1, sd0, sd1
        float as = a_srcs[f], ad = a_dsts[f];
        float t0 = r0 * as, t1 = r1 * as, t2 = r0 * ad, t3 = r1 * ad;
#pragma unroll
        for (int off = 32; off >= 1; off >>= 1) {
            t0 += __shfl_xor(t0, off); t1 += __shfl_xor(t1, off);
            t2 += __shfl_xor(t2, off); t3 += __shfl_xor(t3, off);
        }
        if (f == 0) { sparams[0] = t0; sparams[1] = t1; sparams[2] = t2; sparams[3] = t3; }
    }
    if (l == 1) {  // head constant: b2 @ W_out
        float b2 = biases[128 + f];
        float t4 = b2 * W_out[f * 2];
        float t5 = b2 * W_out[f * 2 + 1];
#pragma unroll
        for (int off = 32; off >= 1; off >>= 1) {
            t4 += __shfl_xor(t4, off); t5 += __shfl_xor(t5, off);
        }
        if (f == 0) { sparams[4] = t4; sparams[5] = t5; }
    }
    float c1 = (float)l * (1.f / (NLVL - 1));
    o[f] = fmaxf(biases[f] + r0 + c1 * (r1 - r0), 0.f);
    __syncthreads();
    const float* W1 = Ws + 4096;
    float h = 0.f;
#pragma unroll 8
    for (int k = 0; k < 64; ++k) h = fmaf(o[k], W1[k * 64 + f], h);
    float ss = h * a_srcs[64 + f];
    float sd = h * a_dsts[64 + f];
    float am = fabsf(h);
#pragma unroll
    for (int off = 32; off >= 1; off >>= 1) {
        ss += __shfl_xor(ss, off);
        sd += __shfl_xor(sd, off);
        am = fmaxf(am, __shfl_xor(am, off));
    }
    float iscl = (am > 0.f) ? 127.f / am : 0.f;
    Tq8[l * 64 + f] = (unsigned char)(__float2int_rn(h * iscl) & 255);
    if (f == 0) { Tscl[l] = am * (1.f / 127.f); Ts1s[l] = ss; Ts1d[l] = sd; }
}

// ---------------- layer-1 agg: table reads through L1 (32 KB table, no LDS staging) ----------------

__global__ __launch_bounds__(256) void k_agg1(
    const unsigned char* __restrict__ Tq8, const float* __restrict__ Tscl,
    const float* __restrict__ Ts1s, const float* __restrict__ Ts1d,
    const unsigned short* __restrict__ cidx, const int* __restrict__ col,
    const int* __restrict__ rowptr, const float* __restrict__ bias,
    unsigned short* __restrict__ hout)
{
    __shared__ float2 stash[4][64];
    int t = threadIdx.x;
    int wave = t >> 6, lane = t & 63;
    int node = blockIdx.x * 4 + wave;
    if (node >= N_NODES) return;
    const char* hb = (const char*)Tq8;

    int row = rowptr[node], end = rowptr[node + 1];
    int deg = end - row;
    if (deg <= 64) {
        int idx = 0;
        float p = 0.f, sc = 0.f;
        if (lane < deg) idx = cidx[col[row + lane]];
        float sdi = Ts1d[__shfl(idx, 0)];   // slot 0 = self loop
        if (lane < deg) {
            float ee = Ts1s[idx] + sdi;
            ee = (ee >= 0.f) ? ee : NEG_SLOPE * ee;
            p = __expf(ee);
            sc = Tscl[idx];
        }
        stash[wave][lane] = make_float2(p * sc, __int_as_float(idx * 64));

        int q = lane >> 4;
        int f = lane & 15;
        int f4 = f * 4;
        float a0 = 0.f, a1 = 0.f, a2 = 0.f, a3 = 0.f;
        int degr = (deg + 15) & ~15;
        for (int j = q; j < degr; j += 16) {
            float2 e0 = stash[wave][j];
            float2 e1 = stash[wave][j + 4];
            float2 e2 = stash[wave][j + 8];
            float2 e3 = stash[wave][j + 12];
            unsigned v0 = *(const unsigned*)(hb + (__float_as_int(e0.y) + f4));
            unsigned v1 = *(const unsigned*)(hb + (__float_as_int(e1.y) + f4));
            unsigned v2 = *(const unsigned*)(hb + (__float_as_int(e2.y) + f4));
            unsigned v3 = *(const unsigned*)(hb + (__float_as_int(e3.y) + f4));
            a0 = fmaf(e0.x, (float)sb0(v0), a0);
            a1 = fmaf(e0.x, (float)sb1(v0), a1);
            a2 = fmaf(e0.x, (float)sb2(v0), a2);
            a3 = fmaf(e0.x, (float)sb3(v0), a3);
            a0 = fmaf(e1.x, (float)sb0(v1), a0);
            a1 = fmaf(e1.x, (float)sb1(v1), a1);
            a2 = fmaf(e1.x, (float)sb2(v1), a2);
            a3 = fmaf(e1.x, (float)sb3(v1), a3);
            a0 = fmaf(e2.x, (float)sb0(v2), a0);
            a1 = fmaf(e2.x, (float)sb1(v2), a1);
            a2 = fmaf(e2.x, (float)sb2(v2), a2);
            a3 = fmaf(e2.x, (float)sb3(v2), a3);
            a0 = fmaf(e3.x, (float)sb0(v3), a0);
            a1 = fmaf(e3.x, (float)sb1(v3), a1);
            a2 = fmaf(e3.x, (float)sb2(v3), a2);
            a3 = fmaf(e3.x, (float)sb3(v3), a3);
        }
        float denom = p;
#pragma unroll
        for (int off = 32; off >= 1; off >>= 1) denom += __shfl_xor(denom, off);
        float inv = 1.f / denom;
        a0 += __shfl_xor(a0, 16); a0 += __shfl_xor(a0, 32);
        a1 += __shfl_xor(a1, 16); a1 += __shfl_xor(a1, 32);
        a2 += __shfl_xor(a2, 16); a2 += __shfl_xor(a2, 32);
        a3 += __shfl_xor(a3, 16); a3 += __shfl_xor(a3, 32);
        if (lane < 16) {
            float4 bb = *(const float4*)&bias[4 * f];
            ushort4 pk;
            pk.x = f2bf(fmaxf(fmaf(a0, inv, bb.x), 0.f));
            pk.y = f2bf(fmaxf(fmaf(a1, inv, bb.y), 0.f));
            pk.z = f2bf(fmaxf(fmaf(a2, inv, bb.z), 0.f));
            pk.w = f2bf(fmaxf(fmaf(a3, inv, bb.w), 0.f));
            *(ushort4*)&hout[node * 64 + 4 * f] = pk;
        }
    } else {
        // generic path (deg > 64): statistically never hit
        float sdi = Ts1d[cidx[node]];
        float m = -FLT_MAX;
        for (int j = row + lane; j < end; j += 64) {
            float ee = Ts1s[cidx[col[j]]] + sdi;
            ee = (ee >= 0.f) ? ee : NEG_SLOPE * ee;
            m = fmaxf(m, ee);
        }
#pragma unroll
        for (int off = 32; off >= 1; off >>= 1) m = fmaxf(m, __shfl_xor(m, off));
        float denom = 0.f;
        for (int j = row + lane; j < end; j += 64) {
            float ee = Ts1s[cidx[col[j]]] + sdi;
            ee = (ee >= 0.f) ? ee : NEG_SLOPE * ee;
            denom += __expf(ee - m);
        }
#pragma unroll
        for (int off = 32; off >= 1; off >>= 1) denom += __shfl_xor(denom, off);
        float inv = 1.f / denom;
        float acc = 0.f;
        for (int j = row; j < end; ++j) {
            int idxj = cidx[col[j]];
            float ee = Ts1s[idxj] + sdi;
            ee = (ee >= 0.f) ? ee : NEG_SLOPE * ee;
            float w = __expf(ee - m) * inv * Tscl[idxj];
            int bq = (int)(signed char)Tq8[idxj * 64 + lane];
            acc = fmaf(w, (float)bq, acc);
        }
        hout[node * 64 + lane] = f2bf(fmaxf(acc + bias[lane], 0.f));
    }
}

// ---------------- layer-2 GEMM: scores + z = h2 @ W_out (8 B per node) ----------------

__global__ __launch_bounds__(256) void k_gemm2(
    const unsigned* __restrict__ h32, const float* __restrict__ W,
    const float* __restrict__ a_s, const float* __restrict__ a_d,
    const float* __restrict__ W_out,
    float2* __restrict__ z2, float* __restrict__ s_src, float* __restrict__ s_dst)
{
    __shared__ float Wl[64 * 64];
    __shared__ float hT[64 * 68];  // [k][r], pitch 68
    int t = threadIdx.x;
    int r0 = blockIdx.x * 64;

    for (int i = t; i < 4096; i += 256) Wl[i] = W[i];
    for (int i = t; i < 2048; i += 256) {
        int r = i >> 5, m = i & 31;
        int row = r0 + r;
        unsigned u = (row < N_NODES) ? h32[row * 32 + m] : 0u;
        hT[(2 * m) * 68 + r]     = blo(u);
        hT[(2 * m + 1) * 68 + r] = bhi(u);
    }
    __syncthreads();

    int tcol = t & 15;
    int trow = t >> 4;
    float acc[4][4];
#pragma unroll
    for (int i = 0; i < 4; ++i)
#pragma unroll
        for (int j = 0; j < 4; ++j) acc[i][j] = 0.f;

    for (int k = 0; k < 64; ++k) {
        float4 va = *(const float4*)&hT[k * 68 + trow * 4];
        float4 vb = *(const float4*)&Wl[k * 64 + tcol * 4];
        float a[4] = {va.x, va.y, va.z, va.w};
        float bb[4] = {vb.x, vb.y, vb.z, vb.w};
#pragma unroll
        for (int i = 0; i < 4; ++i)
#pragma unroll
            for (int j = 0; j < 4; ++j) acc[i][j] = fmaf(a[i], bb[j], acc[i][j]);
    }

    float4 as4 = *(const float4*)&a_s[tcol * 4];
    float4 ad4 = *(const float4*)&a_d[tcol * 4];
    float asr[4] = {as4.x, as4.y, as4.z, as4.w};
    float adr[4] = {ad4.x, ad4.y, ad4.z, ad4.w};
    float4 wa = *(const float4*)&W_out[8 * tcol];      // rows 4t, 4t+1
    float4 wb = *(const float4*)&W_out[8 * tcol + 4];  // rows 4t+2, 4t+3

#pragma unroll
    for (int i = 0; i < 4; ++i) {
        int row = r0 + trow * 4 + i;
        float ps = 0.f, pd = 0.f;
#pragma unroll
        for (int j = 0; j < 4; ++j) {
            ps = fmaf(acc[i][j], asr[j], ps);
            pd = fmaf(acc[i][j], adr[j], pd);
        }
        float z0 = acc[i][0] * wa.x + acc[i][1] * wa.z + acc[i][2] * wb.x + acc[i][3] * wb.z;
        float z1 = acc[i][0] * wa.y + acc[i][1] * wa.w + acc[i][2] * wb.y + acc[i][3] * wb.w;
#pragma unroll
        for (int off = 8; off >= 1; off >>= 1) {
            ps += __shfl_xor(ps, off);
            pd += __shfl_xor(pd, off);
            z0 += __shfl_xor(z0, off);
            z1 += __shfl_xor(z1, off);
        }
        if (row < N_NODES && tcol == 0) {
            s_src[row] = ps; s_dst[row] = pd;
            z2[row] = make_float2(z0, z1);
        }
    }
}

// ---------------- last-layer agg + pool: 2 nodes/wave x 4 pairs, register g-accumulation ----------------

__global__ __launch_bounds__(256) void k_pool2(
    const float2* __restrict__ z2, const int* __restrict__ col,
    const int* __restrict__ rowptr, const float* __restrict__ s_src_in,
    const float* __restrict__ s_dst_in, const int* __restrict__ batch,
    float* __restrict__ pool_acc)
{
    int t = threadIdx.x;
    int wave = t >> 6, lane = t & 63;
    int h = lane >> 5, hl = lane & 31;
    int base0 = blockIdx.x * 32 + wave * 8;
    if (base0 >= N_NODES) return;
    float* rep = pool_acc + ((blockIdx.x * 4 + wave) & (NREP - 1)) * REP_STRIDE;

    int gcur = -1;
    float acc0 = 0.f, acc1 = 0.f;

#pragma unroll
    for (int i = 0; i < 4; ++i) {
        int node = base0 + 2 * i + h;
        bool valid = (node < N_NODES);
        int row = 0, end = 0;
        if (valid) { row = rowptr[node]; end = rowptr[node + 1]; }
        int deg = end - row;
        int degO = __shfl_xor(deg, 32);
        bool fast = (deg <= 32) && (degO <= 32);   // wave-uniform
        float r0 = 0.f, r1 = 0.f;

        if (fast) {
            float sdi = valid ? s_dst_in[node] : 0.f;
            float p = 0.f;
            float2 zv = make_float2(0.f, 0.f);
            if (hl < deg) {
                int c = col[row + hl];
                float ee = s_src_in[c] + sdi;
                ee = (ee >= 0.f) ? ee : NEG_SLOPE * ee;
                p = __expf(ee);
                zv = z2[c];
            }
            float n0 = p * zv.x, n1 = p * zv.y, dn = p;
#pragma unroll
            for (int off = 16; off >= 1; off >>= 1) {
                n0 += __shfl_xor(n0, off);
                n1 += __shfl_xor(n1, off);
                dn += __shfl_xor(dn, off);
            }
            float inv = 1.f / dn;
            r0 = n0 * inv; r1 = n1 * inv;
        } else {
            // rare: process both nodes of the pair full-wave
            float rr0[2], rr1[2];
#pragma unroll
            for (int s = 0; s < 2; ++s) {
                rr0[s] = rr1[s] = 0.f;
                int nd = base0 + 2 * i + s;
                if (nd >= N_NODES) continue;
                int r = rowptr[nd], e = rowptr[nd + 1];
                float sdi = s_dst_in[nd];
                float n0 = 0.f, n1 = 0.f, dn = 0.f;
                for (int j = r + lane; j < e; j += 64) {
                    int c = col[j];
                    float ee = s_src_in[c] + sdi;
                    ee = (ee >= 0.f) ? ee : NEG_SLOPE * ee;
                    float p = __expf(ee);
                    float2 zv = z2[c];
                    n0 = fmaf(p, zv.x, n0);
                    n1 = fmaf(p, zv.y, n1);
                    dn += p;
                }
#pragma unroll
                for (int off = 32; off >= 1; off >>= 1) {
                    n0 += __shfl_xor(n0, off);
                    n1 += __shfl_xor(n1, off);
                    dn += __shfl_xor(dn, off);
                }
                float inv = 1.f / dn;
                rr0[s] = n0 * inv; rr1[s] = n1 * inv;
            }
            r0 = rr0[h]; r1 = rr1[h];
        }

        if (hl == 0 && valid) {
            int g = batch[node];
            if (g != gcur) {
                if (gcur >= 0) {
                    atomicAdd(&rep[gcur * 2], acc0);
                    atomicAdd(&rep[gcur * 2 + 1], acc1);
                }
                gcur = g; acc0 = r0; acc1 = r1;
            } else {
                acc0 += r0; acc1 += r1;
            }
        }
    }
    if (hl == 0 && gcur >= 0) {
        atomicAdd(&rep[gcur * 2], acc0);
        atomicAdd(&rep[gcur * 2 + 1], acc1);
    }
}

// ---------------- head: reduce replicas, divide by count, add consts ----------------

__device__ __forceinline__ int lower_bound_dev(const int* __restrict__ a, int n, int v) {
    int lo = 0, hi = n;
    while (lo < hi) {
        int mid = (lo + hi) >> 1;
        if (a[mid] < v) lo = mid + 1; else hi = mid;
    }
    return lo;
}

__global__ void k_head(const float* __restrict__ pool_acc,
                       const int* __restrict__ batch,
                       const float* __restrict__ b_out,
                       const float* __restrict__ sparams,
                       float* __restrict__ out)
{
    int t = threadIdx.x;
    if (t < 2 * N_GRAPHS) {
        float s = 0.f;
#pragma unroll 8
        for (int r = 0; r < NREP; ++r) s += pool_acc[r * REP_STRIDE + t];
        int g = t >> 1, c = t & 1;
        int start = lower_bound_dev(batch, N_NODES, g);
        int end = lower_bound_dev(batch, N_NODES, g + 1);
        float cnt = fmaxf((float)(end - start), 1.f);
        out[t] = s / cnt + sparams[4 + c] + b_out[c];
    }
}

// ---------------- launch ----------------

extern "C" void kernel_launch(void* const* d_in, const int* in_sizes, int n_in,
                              void* d_out, int out_size, void* d_ws, size_t ws_size,
                              hipStream_t stream) {
    const int*   x       = (const int*)d_in[0];
    const int*   edge    = (const int*)d_in[1];   // [2][E]
    const int*   batch   = (const int*)d_in[2];
    const float* embed   = (const float*)d_in[3];
    const float* Ws      = (const float*)d_in[4];
    const float* a_srcs  = (const float*)d_in[5];
    const float* a_dsts  = (const float*)d_in[6];
    const float* biases  = (const float*)d_in[7];
    const float* W_out   = (const float*)d_in[8];
    const float* b_out   = (const float*)d_in[9];
    float* out = (float*)d_out;

    char* ws = (char*)d_ws;
    size_t off = 0;
    auto alloc = [&](size_t bytes) -> void* {
        void* p = ws + off;
        off += (bytes + 255) & ~(size_t)255;
        return p;
    };
    unsigned short* hout  = (unsigned short*)alloc((size_t)N_NODES * 64 * sizeof(unsigned short));
    float2* z2      = (float2*)alloc((size_t)N_NODES * sizeof(float2));
    float* s_src0   = (float*)alloc((size_t)N_NODES * sizeof(float));
    float* s_dst0   = (float*)alloc((size_t)N_NODES * sizeof(float));
    unsigned short* cidx = (unsigned short*)alloc((size_t)N_NODES * sizeof(unsigned short));
    int*   rowptr   = (int*)alloc((size_t)(N_NODES + 1) * sizeof(int));
    int*   colA     = (int*)alloc((size_t)ETOT * sizeof(int));
    int*   blockcnt = (int*)alloc((size_t)PAIR_BLOCKS * NB * sizeof(int));
    int*   btot     = (int*)alloc((size_t)NB * sizeof(int));
    int*   pstart   = (int*)alloc((size_t)(NB + 1) * sizeof(int));
    float* pool_acc = (float*)alloc((size_t)(NREP * REP_STRIDE) * sizeof(float));
    unsigned* xb    = (unsigned*)alloc((size_t)3200 * sizeof(unsigned));
    unsigned char* Tq8 = (unsigned char*)alloc((size_t)NLVL * 64);
    float* Tscl     = (float*)alloc((size_t)NLVL * sizeof(float));
    float* Ts1s     = (float*)alloc((size_t)NLVL * sizeof(float));
    float* Ts1d     = (float*)alloc((size_t)NLVL * sizeof(float));
    float* sparams  = (float*)alloc((size_t)8 * sizeof(float));
    int*   pairs    = (int*)alloc((size_t)N_EDGES * sizeof(int));  // dead after CSR build

    const int* e0 = edge;
    const int* e1 = edge + N_EDGES;

    // x bitmask + weight-only table (independent of graph)
    k_xbit<<<(N_NODES + 255) / 256, 256, 0, stream>>>(x, xb);
    k_table<<<NLVL, 64, 0, stream>>>(embed, Ws, biases, a_srcs, a_dsts, W_out,
                                     Tq8, Tscl, Ts1s, Ts1d, sparams);
    // bucketed CSR build (by dst, self loops at slot 0; emits cidx inline)
    k_count<<<PAIR_BLOCKS, 256, 0, stream>>>(e1, blockcnt, pool_acc);
    k_scan_bases<<<NB, 64, 0, stream>>>(blockcnt, btot);
    k_scan_buckets<<<1, 256, 0, stream>>>(btot, pstart);
    k_pair_scatter<<<PAIR_BLOCKS, 256, 0, stream>>>(e0, e1, xb, blockcnt, pstart, pairs);
    k_csr_bucket<<<NB, 512, 0, stream>>>(pairs, pstart, x, sparams, rowptr, colA, cidx);

    // layer 1: table-based aggregation (tables via L1) -> bf16 hout
    k_agg1<<<(N_NODES + 3) / 4, 256, 0, stream>>>(
        Tq8, Tscl, Ts1s, Ts1d, cidx, colA, rowptr, biases + 64, hout);
    // layer 2: GEMM -> scores + z (h2 @ W_out), then 8-B-gather pool
    k_gemm2<<<(N_NODES + 63) / 64, 256, 0, stream>>>(
        (const unsigned*)hout, Ws + 8192, a_srcs + 128, a_dsts + 128, W_out,
        z2, s_src0, s_dst0);
    k_pool2<<<(N_NODES + 31) / 32, 256, 0, stream>>>(
        z2, colA, rowptr, s_src0, s_dst0, batch, pool_acc);
    k_head<<<1, 256, 0, stream>>>(pool_acc, batch, b_out, sparams, out);
}

// Round 16
// 214.769 us; speedup vs baseline: 2.0925x; 1.0426x over previous
//
#include <hip/hip_runtime.h>
#include <hip/hip_bf16.h>
#include <float.h>

#define N_NODES 100000
#define N_EDGES 1600000
#define HIDDEN 64
#define N_GRAPHS 128
#define NEG_SLOPE 0.2f
#define ETOT (N_EDGES + N_NODES)

#define BSHIFT 9
#define NB ((N_NODES + 511) >> BSHIFT)    // 196 buckets of 512 nodes
#define PAIR_CHUNK 4096
#define PAIR_BLOCKS ((N_EDGES + PAIR_CHUNK - 1) / PAIR_CHUNK)  // 391
#define XBIT_BLOCKS ((N_NODES + 255) / 256)                     // 391
#define TBL_BLOCKS (NLVL / 4)                                   // 128

#define NREP 64           // pool accumulator replicas
#define REP_STRIDE 272
#define NLVL 512          // c1 quantization levels (layer-1 table)

__device__ __forceinline__ unsigned short f2bf(float f) {
    unsigned u = __float_as_uint(f);
    unsigned r = (u + 0x7FFFu + ((u >> 16) & 1u)) >> 16;  // RNE
    return (unsigned short)r;
}
__device__ __forceinline__ float blo(unsigned u) { return __uint_as_float(u << 16); }
__device__ __forceinline__ float bhi(unsigned u) { return __uint_as_float(u & 0xFFFF0000u); }
__device__ __forceinline__ int sb0(unsigned u) { return (int)((unsigned)(u << 24)) >> 24; }
__device__ __forceinline__ int sb1(unsigned u) { return (int)((unsigned)(u << 16)) >> 24; }
__device__ __forceinline__ int sb2(unsigned u) { return (int)((unsigned)(u << 8)) >> 24; }
__device__ __forceinline__ int sb3(unsigned u) { return (int)u >> 24; }

// ---------------- fused prep: edge bucket counts | layer-1 table | x bitmask ----------------

__global__ __launch_bounds__(256) void k_prep(
    const int* __restrict__ e1, const int* __restrict__ x,
    const float* __restrict__ embed, const float* __restrict__ Ws,
    const float* __restrict__ biases, const float* __restrict__ a_srcs,
    const float* __restrict__ a_dsts, const float* __restrict__ W_out,
    int* __restrict__ blockcnt, float* __restrict__ pool_acc,
    unsigned* __restrict__ xb,
    unsigned char* __restrict__ Tq8, float* __restrict__ Tscl,
    float* __restrict__ Ts1s, float* __restrict__ Ts1d,
    float* __restrict__ sparams)
{
    __shared__ int hcnt[NB];
    int t = threadIdx.x, b = blockIdx.x;

    if (b < PAIR_BLOCKS) {
        // ---- bucket counts for chunk b (+ zero pool_acc replicas) ----
        if (t < NB) hcnt[t] = 0;
        if (b < NREP && t < 2 * N_GRAPHS) pool_acc[b * REP_STRIDE + t] = 0.f;
        __syncthreads();
        int ebase = b * PAIR_CHUNK;
        int ecount = min(PAIR_CHUNK, N_EDGES - ebase);
        for (int i = t; i < ecount; i += 256)
            atomicAdd(&hcnt[e1[ebase + i] >> BSHIFT], 1);
        __syncthreads();
        if (t < NB) blockcnt[b * NB + t] = hcnt[t];
    } else if (b < PAIR_BLOCKS + TBL_BLOCKS) {
        // ---- layer-1 table, 4 levels per block (one per wave, shuffle-only) ----
        int l = (b - PAIR_BLOCKS) * 4 + (t >> 6);
        int f = t & 63;
        float r0 = 0.f, r1 = 0.f;
#pragma unroll 8
        for (int k = 0; k < 64; ++k) {
            float w = Ws[k * 64 + f];
            r0 = fmaf(embed[k], w, r0);
            r1 = fmaf(embed[64 + k], w, r1);
        }
        if (l == 0) {  // layer-0 score scalars
            float as = a_srcs[f], ad = a_dsts[f];
            float t0 = r0 * as, t1 = r1 * as, t2 = r0 * ad, t3 = r1 * ad;
#pragma unroll
            for (int off = 32; off >= 1; off >>= 1) {
                t0 += __shfl_xor(t0, off); t1 += __shfl_xor(t1, off);
                t2 += __shfl_xor(t2, off); t3 += __shfl_xor(t3, off);
            }
            if (f == 0) { sparams[0] = t0; sparams[1] = t1; sparams[2] = t2; sparams[3] = t3; }
        }
        if (l == 1) {  // head constant: b2 @ W_out
            float b2 = biases[128 + f];
            float t4 = b2 * W_out[f * 2];
            float t5 = b2 * W_out[f * 2 + 1];
#pragma unroll
            for (int off = 32; off >= 1; off >>= 1) {
                t4 += __shfl_xor(t4, off); t5 += __shfl_xor(t5, off);
            }
            if (f == 0) { sparams[4] = t4; sparams[5] = t5; }
        }
        float c1 = (float)l * (1.f / (NLVL - 1));
        float o = fmaxf(biases[f] + r0 + c1 * (r1 - r0), 0.f);
        const float* W1 = Ws + 4096;
        float h = 0.f;
#pragma unroll 8
        for (int k = 0; k < 64; ++k) h = fmaf(__shfl(o, k), W1[k * 64 + f], h);
        float ss = h * a_srcs[64 + f];
        float sd = h * a_dsts[64 + f];
        float am = fabsf(h);
#pragma unroll
        for (int off = 32; off >= 1; off >>= 1) {
            ss += __shfl_xor(ss, off);
            sd += __shfl_xor(sd, off);
            am = fmaxf(am, __shfl_xor(am, off));
        }
        float iscl = (am > 0.f) ? 127.f / am : 0.f;
        Tq8[l * 64 + f] = (unsigned char)(__float2int_rn(h * iscl) & 255);
        if (f == 0) { Tscl[l] = am * (1.f / 127.f); Ts1s[l] = ss; Ts1d[l] = sd; }
    } else {
        // ---- x bitmask ----
        int i = (b - PAIR_BLOCKS - TBL_BLOCKS) * 256 + t;
        int lane = t & 63;
        bool bb = (i < N_NODES) && (x[i] != 0);
        unsigned long long m = __ballot(bb);
        int wid = i >> 6;
        if (i < N_NODES + 64) {
            if (lane == 0) xb[wid * 2] = (unsigned)m;
            if (lane == 32) xb[wid * 2 + 1] = (unsigned)(m >> 32);
        }
    }
}

// one wave per bucket: exclusive scan over its chunk counts (in place) + total
__global__ __launch_bounds__(64) void k_scan_bases(int* __restrict__ blockcnt,
                                                   int* __restrict__ btot) {
    int b = blockIdx.x;
    int lane = threadIdx.x;
    int s = 0;
    for (int base = 0; base < PAIR_BLOCKS; base += 64) {
        int c = base + lane;
        int v = (c < PAIR_BLOCKS) ? blockcnt[c * NB + b] : 0;
        int xv = v;
#pragma unroll
        for (int off = 1; off < 64; off <<= 1) {
            int y = __shfl_up(xv, off);
            if (lane >= off) xv += y;
        }
        if (c < PAIR_BLOCKS) blockcnt[c * NB + b] = s + xv - v;
        s += __shfl(xv, 63);
    }
    if (lane == 0) btot[b] = s;
}

__global__ __launch_bounds__(256) void k_pair_scatter(
    const int* __restrict__ e0, const int* __restrict__ e1,
    const unsigned* __restrict__ xb, const int* __restrict__ btot,
    const int* __restrict__ blockcnt, int* __restrict__ pairs)
{
    __shared__ int tot[256];
    __shared__ int cnt[NB];
    __shared__ int base[NB];
    int t = threadIdx.x, b = blockIdx.x;
    // local exclusive scan of bucket totals -> pair_start
    int v = (t < NB) ? btot[t] : 0;
    tot[t] = v;
    __syncthreads();
    for (int off = 1; off < 256; off <<= 1) {
        int u = (t >= off) ? tot[t - off] : 0;
        __syncthreads();
        tot[t] += u;
        __syncthreads();
    }
    if (t < NB) {
        cnt[t] = 0;
        base[t] = (tot[t] - v) + blockcnt[b * NB + t];
    }
    __syncthreads();
    int ebase = b * PAIR_CHUNK;
    int ecount = min(PAIR_CHUNK, N_EDGES - ebase);
    for (int i = t; i < ecount; i += 256) {
        int s = e0[ebase + i];
        int d = e1[ebase + i];
        int xv = (xb[s >> 5] >> (s & 31)) & 1;
        int B = d >> BSHIFT;
        int idx = atomicAdd(&cnt[B], 1);
        pairs[base[B] + idx] = (xv << 26) | ((d & 511) << 17) | s;  // x|9b dst|17b src
    }
}

// One block (512 thr) per bucket. Self loop at slot 0. Emits cidx inline.
__global__ __launch_bounds__(512) void k_csr_bucket(
    const int* __restrict__ pairs, const int* __restrict__ btot,
    const int* __restrict__ x, const float* __restrict__ sparams,
    int* __restrict__ rowptr, int* __restrict__ col,
    unsigned short* __restrict__ cidx)
{
    __shared__ int deg[512];
    __shared__ int excl[512];
    __shared__ int cnt2[512];
    __shared__ int wsum[8];
    __shared__ int p0sh;
    int b = blockIdx.x;
    int t = threadIdx.x;
    int nb = b << BSHIFT;
    int nodes = min(512, N_NODES - nb);

    // local reduce: p0 = sum of btot[0..b)
    int pv = (t < b) ? btot[t] : 0;   // b < NB <= 196 < 512
#pragma unroll
    for (int off = 32; off >= 1; off >>= 1) pv += __shfl_xor(pv, off);
    if ((t & 63) == 0) wsum[t >> 6] = pv;
    __syncthreads();
    if (t == 0) {
        int s = 0;
#pragma unroll
        for (int i = 0; i < 8; ++i) s += wsum[i];
        p0sh = s;
    }

    int xself = (t < nodes) ? (x[nb + t] & 1) : 0;
    deg[t] = (t < nodes) ? (1 | (xself << 16)) : 0;   // self loop contributes
    cnt2[t] = 1;
    __syncthreads();
    int p0 = p0sh;
    int p1 = p0 + btot[b];
    for (int i = p0 + t; i < p1; i += 512) {
        int p = pairs[i];
        atomicAdd(&deg[(p >> 17) & 511], 1 | (((p >> 26) & 1) << 16));
    }
    __syncthreads();

    int packed = deg[t];
    int val = packed & 0xFFFF;
    int kx = packed >> 16;
    if (t < nodes) {
        float ss0 = sparams[0], ss1 = sparams[1];
        float sd = xself ? sparams[3] : sparams[2];
        float e0 = ss0 + sd; e0 = (e0 >= 0.f) ? e0 : NEG_SLOPE * e0;
        float e1 = ss1 + sd; e1 = (e1 >= 0.f) ? e1 : NEG_SLOPE * e1;
        float pp0 = __expf(e0), pp1 = __expf(e1);
        float kn = (float)kx, dn = (float)(val - kx);
        float c1 = kn * pp1 / (dn * pp0 + kn * pp1);
        cidx[nb + t] = (unsigned short)__float2int_rn(c1 * (float)(NLVL - 1));
    }

    int xx = val;
#pragma unroll
    for (int off = 1; off < 64; off <<= 1) {
        int y = __shfl_up(xx, off);
        if ((t & 63) >= off) xx += y;
    }
    __syncthreads();
    if ((t & 63) == 63) wsum[t >> 6] = xx;
    __syncthreads();
    if (t == 0) {
        int s = 0;
#pragma unroll
        for (int i = 0; i < 8; ++i) { int v = wsum[i]; wsum[i] = s; s += v; }
    }
    __syncthreads();
    int ex = xx - val + wsum[t >> 6];
    excl[t] = ex;

    int colbase = p0 + nb;
    if (t < nodes) {
        rowptr[nb + t] = colbase + ex;
        col[colbase + ex] = nb + t;  // self loop at slot 0
    }
    if (b == NB - 1 && t == 0) rowptr[N_NODES] = ETOT;
    __syncthreads();
    for (int i = p0 + t; i < p1; i += 512) {
        int p = pairs[i];
        int li = (p >> 17) & 511;
        int pos = colbase + excl[li] + atomicAdd(&cnt2[li], 1);
        col[pos] = p & 0x1FFFF;
    }
}

// ---------------- layer-1 agg: 2 nodes per wave, tables via L1 ----------------

__global__ __launch_bounds__(256) void k_agg1(
    const unsigned char* __restrict__ Tq8, const float* __restrict__ Tscl,
    const float* __restrict__ Ts1s, const float* __restrict__ Ts1d,
    const unsigned short* __restrict__ cidx, const int* __restrict__ col,
    const int* __restrict__ rowptr, const float* __restrict__ bias,
    unsigned short* __restrict__ hout)
{
    __shared__ float2 stash[4][64];
    int t = threadIdx.x;
    int wave = t >> 6, lane = t & 63;
    int h = lane >> 5, hl = lane & 31;
    int base = blockIdx.x * 8 + wave * 2;
    if (base >= N_NODES) return;
    const char* hb = (const char*)Tq8;

    int node = base + h;
    bool valid = (node < N_NODES);
    int row = 0, end = 0;
    if (valid) { row = rowptr[node]; end = rowptr[node + 1]; }
    int deg = end - row;
    int degO = __shfl_xor(deg, 32);
    bool fast = (deg <= 32) && (degO <= 32);

    if (fast) {
        int idx = 0;
        float p = 0.f, sc = 0.f;
        if (hl < deg) idx = cidx[col[row + hl]];
        float sdi = Ts1d[__shfl(idx, h * 32)];   // slot 0 = self loop
        if (hl < deg) {
            float ee = Ts1s[idx] + sdi;
            ee = (ee >= 0.f) ? ee : NEG_SLOPE * ee;
            p = __expf(ee);
            sc = Tscl[idx];
        }
        stash[wave][lane] = make_float2(p * sc, __int_as_float(idx * 64));

        int q = hl >> 4;
        int f = hl & 15;
        int f4 = f * 4;
        int sb = h * 32;
        float a0 = 0.f, a1 = 0.f, a2 = 0.f, a3 = 0.f;
        int degr = (deg + 7) & ~7;
        for (int j = q; j < degr; j += 8) {
            float2 e0 = stash[wave][sb + j];
            float2 e1 = stash[wave][sb + j + 2];
            float2 e2 = stash[wave][sb + j + 4];
            float2 e3 = stash[wave][sb + j + 6];
            unsigned v0 = *(const unsigned*)(hb + (__float_as_int(e0.y) + f4));
            unsigned v1 = *(const unsigned*)(hb + (__float_as_int(e1.y) + f4));
            unsigned v2 = *(const unsigned*)(hb + (__float_as_int(e2.y) + f4));
            unsigned v3 = *(const unsigned*)(hb + (__float_as_int(e3.y) + f4));
            a0 = fmaf(e0.x, (float)sb0(v0), a0);
            a1 = fmaf(e0.x, (float)sb1(v0), a1);
            a2 = fmaf(e0.x, (float)sb2(v0), a2);
            a3 = fmaf(e0.x, (float)sb3(v0), a3);
            a0 = fmaf(e1.x, (float)sb0(v1), a0);
            a1 = fmaf(e1.x, (float)sb1(v1), a1);
            a2 = fmaf(e1.x, (float)sb2(v1), a2);
            a3 = fmaf(e1.x, (float)sb3(v1), a3);
            a0 = fmaf(e2.x, (float)sb0(v2), a0);
            a1 = fmaf(e2.x, (float)sb1(v2), a1);
            a2 = fmaf(e2.x, (float)sb2(v2), a2);
            a3 = fmaf(e2.x, (float)sb3(v2), a3);
            a0 = fmaf(e3.x, (float)sb0(v3), a0);
            a1 = fmaf(e3.x, (float)sb1(v3), a1);
            a2 = fmaf(e3.x, (float)sb2(v3), a2);
            a3 = fmaf(e3.x, (float)sb3(v3), a3);
        }
        float denom = p;
#pragma unroll
        for (int off = 16; off >= 1; off >>= 1) denom += __shfl_xor(denom, off);
        float inv = 1.f / denom;
        a0 += __shfl_xor(a0, 16);
        a1 += __shfl_xor(a1, 16);
        a2 += __shfl_xor(a2, 16);
        a3 += __shfl_xor(a3, 16);
        if (hl < 16 && valid) {
            float4 bb = *(const float4*)&bias[4 * f];
            ushort4 pk;
            pk.x = f2bf(fmaxf(fmaf(a0, inv, bb.x), 0.f));
            pk.y = f2bf(fmaxf(fmaf(a1, inv, bb.y), 0.f));
            pk.z = f2bf(fmaxf(fmaf(a2, inv, bb.z), 0.f));
            pk.w = f2bf(fmaxf(fmaf(a3, inv, bb.w), 0.f));
            *(ushort4*)&hout[node * 64 + 4 * f] = pk;
        }
    } else {
        // rare: per-pair generic full-wave path
        for (int s = 0; s < 2; ++s) {
            int nd = base + s;
            if (nd >= N_NODES) continue;
            int r = rowptr[nd], e = rowptr[nd + 1];
            float sdi = Ts1d[cidx[nd]];
            float m = -FLT_MAX;
            for (int j = r + lane; j < e; j += 64) {
                float ee = Ts1s[cidx[col[j]]] + sdi;
                ee = (ee >= 0.f) ? ee : NEG_SLOPE * ee;
                m = fmaxf(m, ee);
            }
#pragma unroll
            for (int off = 32; off >= 1; off >>= 1) m = fmaxf(m, __shfl_xor(m, off));
            float denom = 0.f;
            for (int j = r + lane; j < e; j += 64) {
                float ee = Ts1s[cidx[col[j]]] + sdi;
                ee = (ee >= 0.f) ? ee : NEG_SLOPE * ee;
                denom += __expf(ee - m);
            }
#pragma unroll
            for (int off = 32; off >= 1; off >>= 1) denom += __shfl_xor(denom, off);
            float inv = 1.f / denom;
            float acc = 0.f;
            for (int j = r; j < e; ++j) {
                int idxj = cidx[col[j]];
                float ee = Ts1s[idxj] + sdi;
                ee = (ee >= 0.f) ? ee : NEG_SLOPE * ee;
                float w = __expf(ee - m) * inv * Tscl[idxj];
                int bq = (int)(signed char)Tq8[idxj * 64 + lane];
                acc = fmaf(w, (float)bq, acc);
            }
            hout[nd * 64 + lane] = f2bf(fmaxf(acc + bias[lane], 0.f));
        }
    }
}

// ---------------- layer-2 GEMM: scores + z = h2 @ W_out (8 B per node) ----------------

__global__ __launch_bounds__(256) void k_gemm2(
    const unsigned* __restrict__ h32, const float* __restrict__ W,
    const float* __restrict__ a_s, const float* __restrict__ a_d,
    const float* __restrict__ W_out,
    float2* __restrict__ z2, float* __restrict__ s_src, float* __restrict__ s_dst)
{
    __shared__ float Wl[64 * 64];
    __shared__ float hT[64 * 68];  // [k][r], pitch 68
    int t = threadIdx.x;
    int r0 = blockIdx.x * 64;

    for (int i = t; i < 4096; i += 256) Wl[i] = W[i];
    for (int i = t; i < 2048; i += 256) {
        int r = i >> 5, m = i & 31;
        int row = r0 + r;
        unsigned u = (row < N_NODES) ? h32[row * 32 + m] : 0u;
        hT[(2 * m) * 68 + r]     = blo(u);
        hT[(2 * m + 1) * 68 + r] = bhi(u);
    }
    __syncthreads();

    int tcol = t & 15;
    int trow = t >> 4;
    float acc[4][4];
#pragma unroll
    for (int i = 0; i < 4; ++i)
#pragma unroll
        for (int j = 0; j < 4; ++j) acc[i][j] = 0.f;

    for (int k = 0; k < 64; ++k) {
        float4 va = *(const float4*)&hT[k * 68 + trow * 4];
        float4 vb = *(const float4*)&Wl[k * 64 + tcol * 4];
        float a[4] = {va.x, va.y, va.z, va.w};
        float bb[4] = {vb.x, vb.y, vb.z, vb.w};
#pragma unroll
        for (int i = 0; i < 4; ++i)
#pragma unroll
            for (int j = 0; j < 4; ++j) acc[i][j] = fmaf(a[i], bb[j], acc[i][j]);
    }

    float4 as4 = *(const float4*)&a_s[tcol * 4];
    float4 ad4 = *(const float4*)&a_d[tcol * 4];
    float asr[4] = {as4.x, as4.y, as4.z, as4.w};
    float adr[4] = {ad4.x, ad4.y, ad4.z, ad4.w};
    float4 wa = *(const float4*)&W_out[8 * tcol];
    float4 wb = *(const float4*)&W_out[8 * tcol + 4];

#pragma unroll
    for (int i = 0; i < 4; ++i) {
        int row = r0 + trow * 4 + i;
        float ps = 0.f, pd = 0.f;
#pragma unroll
        for (int j = 0; j < 4; ++j) {
            ps = fmaf(acc[i][j], asr[j], ps);
            pd = fmaf(acc[i][j], adr[j], pd);
        }
        float z0 = acc[i][0] * wa.x + acc[i][1] * wa.z + acc[i][2] * wb.x + acc[i][3] * wb.z;
        float z1 = acc[i][0] * wa.y + acc[i][1] * wa.w + acc[i][2] * wb.y + acc[i][3] * wb.w;
#pragma unroll
        for (int off = 8; off >= 1; off >>= 1) {
            ps += __shfl_xor(ps, off);
            pd += __shfl_xor(pd, off);
            z0 += __shfl_xor(z0, off);
            z1 += __shfl_xor(z1, off);
        }
        if (row < N_NODES && tcol == 0) {
            s_src[row] = ps; s_dst[row] = pd;
            z2[row] = make_float2(z0, z1);
        }
    }
}

// ---------------- last-layer agg + pool: 2 nodes/wave x 4 pairs, register g-accumulation ----------------

__global__ __launch_bounds__(256) void k_pool2(
    const float2* __restrict__ z2, const int* __restrict__ col,
    const int* __restrict__ rowptr, const float* __restrict__ s_src_in,
    const float* __restrict__ s_dst_in, const int* __restrict__ batch,
    float* __restrict__ pool_acc)
{
    int t = threadIdx.x;
    int wave = t >> 6, lane = t & 63;
    int h = lane >> 5, hl = lane & 31;
    int base0 = blockIdx.x * 32 + wave * 8;
    if (base0 >= N_NODES) return;
    float* rep = pool_acc + ((blockIdx.x * 4 + wave) & (NREP - 1)) * REP_STRIDE;

    int gcur = -1;
    float acc0 = 0.f, acc1 = 0.f;

#pragma unroll
    for (int i = 0; i < 4; ++i) {
        int node = base0 + 2 * i + h;
        bool valid = (node < N_NODES);
        int row = 0, end = 0;
        if (valid) { row = rowptr[node]; end = rowptr[node + 1]; }
        int deg = end - row;
        int degO = __shfl_xor(deg, 32);
        bool fast = (deg <= 32) && (degO <= 32);
        float r0 = 0.f, r1 = 0.f;

        if (fast) {
            float sdi = valid ? s_dst_in[node] : 0.f;
            float p = 0.f;
            float2 zv = make_float2(0.f, 0.f);
            if (hl < deg) {
                int c = col[row + hl];
                float ee = s_src_in[c] + sdi;
                ee = (ee >= 0.f) ? ee : NEG_SLOPE * ee;
                p = __expf(ee);
                zv = z2[c];
            }
            float n0 = p * zv.x, n1 = p * zv.y, dn = p;
#pragma unroll
            for (int off = 16; off >= 1; off >>= 1) {
                n0 += __shfl_xor(n0, off);
                n1 += __shfl_xor(n1, off);
                dn += __shfl_xor(dn, off);
            }
            float inv = 1.f / dn;
            r0 = n0 * inv; r1 = n1 * inv;
        } else {
            float rr0[2], rr1[2];
#pragma unroll
            for (int s = 0; s < 2; ++s) {
                rr0[s] = rr1[s] = 0.f;
                int nd = base0 + 2 * i + s;
                if (nd >= N_NODES) continue;
                int r = rowptr[nd], e = rowptr[nd + 1];
                float sdi = s_dst_in[nd];
                float n0 = 0.f, n1 = 0.f, dn = 0.f;
                for (int j = r + lane; j < e; j += 64) {
                    int c = col[j];
                    float ee = s_src_in[c] + sdi;
                    ee = (ee >= 0.f) ? ee : NEG_SLOPE * ee;
                    float p = __expf(ee);
                    float2 zv = z2[c];
                    n0 = fmaf(p, zv.x, n0);
                    n1 = fmaf(p, zv.y, n1);
                    dn += p;
                }
#pragma unroll
                for (int off = 32; off >= 1; off >>= 1) {
                    n0 += __shfl_xor(n0, off);
                    n1 += __shfl_xor(n1, off);
                    dn += __shfl_xor(dn, off);
                }
                float inv = 1.f / dn;
                rr0[s] = n0 * inv; rr1[s] = n1 * inv;
            }
            r0 = rr0[h]; r1 = rr1[h];
        }

        if (hl == 0 && valid) {
            int g = batch[node];
            if (g != gcur) {
                if (gcur >= 0) {
                    atomicAdd(&rep[gcur * 2], acc0);
                    atomicAdd(&rep[gcur * 2 + 1], acc1);
                }
                gcur = g; acc0 = r0; acc1 = r1;
            } else {
                acc0 += r0; acc1 += r1;
            }
        }
    }
    if (hl == 0 && gcur >= 0) {
        atomicAdd(&rep[gcur * 2], acc0);
        atomicAdd(&rep[gcur * 2 + 1], acc1);
    }
}

// ---------------- head: reduce replicas, divide by count, add consts ----------------

__device__ __forceinline__ int lower_bound_dev(const int* __restrict__ a, int n, int v) {
    int lo = 0, hi = n;
    while (lo < hi) {
        int mid = (lo + hi) >> 1;
        if (a[mid] < v) lo = mid + 1; else hi = mid;
    }
    return lo;
}

__global__ void k_head(const float* __restrict__ pool_acc,
                       const int* __restrict__ batch,
                       const float* __restrict__ b_out,
                       const float* __restrict__ sparams,
                       float* __restrict__ out)
{
    int t = threadIdx.x;
    if (t < 2 * N_GRAPHS) {
        float s = 0.f;
#pragma unroll 8
        for (int r = 0; r < NREP; ++r) s += pool_acc[r * REP_STRIDE + t];
        int g = t >> 1, c = t & 1;
        int start = lower_bound_dev(batch, N_NODES, g);
        int end = lower_bound_dev(batch, N_NODES, g + 1);
        float cnt = fmaxf((float)(end - start), 1.f);
        out[t] = s / cnt + sparams[4 + c] + b_out[c];
    }
}

// ---------------- launch ----------------

extern "C" void kernel_launch(void* const* d_in, const int* in_sizes, int n_in,
                              void* d_out, int out_size, void* d_ws, size_t ws_size,
                              hipStream_t stream) {
    const int*   x       = (const int*)d_in[0];
    const int*   edge    = (const int*)d_in[1];   // [2][E]
    const int*   batch   = (const int*)d_in[2];
    const float* embed   = (const float*)d_in[3];
    const float* Ws      = (const float*)d_in[4];
    const float* a_srcs  = (const float*)d_in[5];
    const float* a_dsts  = (const float*)d_in[6];
    const float* biases  = (const float*)d_in[7];
    const float* W_out   = (const float*)d_in[8];
    const float* b_out   = (const float*)d_in[9];
    float* out = (float*)d_out;

    char* ws = (char*)d_ws;
    size_t off = 0;
    auto alloc = [&](size_t bytes) -> void* {
        void* p = ws + off;
        off += (bytes + 255) & ~(size_t)255;
        return p;
    };
    unsigned short* hout  = (unsigned short*)alloc((size_t)N_NODES * 64 * sizeof(unsigned short));
    float2* z2      = (float2*)alloc((size_t)N_NODES * sizeof(float2));
    float* s_src0   = (float*)alloc((size_t)N_NODES * sizeof(float));
    float* s_dst0   = (float*)alloc((size_t)N_NODES * sizeof(float));
    unsigned short* cidx = (unsigned short*)alloc((size_t)N_NODES * sizeof(unsigned short));
    int*   rowptr   = (int*)alloc((size_t)(N_NODES + 1) * sizeof(int));
    int*   colA     = (int*)alloc((size_t)ETOT * sizeof(int));
    int*   blockcnt = (int*)alloc((size_t)PAIR_BLOCKS * NB * sizeof(int));
    int*   btot     = (int*)alloc((size_t)NB * sizeof(int));
    float* pool_acc = (float*)alloc((size_t)(NREP * REP_STRIDE) * sizeof(float));
    unsigned* xb    = (unsigned*)alloc((size_t)3232 * sizeof(unsigned));
    unsigned char* Tq8 = (unsigned char*)alloc((size_t)NLVL * 64);
    float* Tscl     = (float*)alloc((size_t)NLVL * sizeof(float));
    float* Ts1s     = (float*)alloc((size_t)NLVL * sizeof(float));
    float* Ts1d     = (float*)alloc((size_t)NLVL * sizeof(float));
    float* sparams  = (float*)alloc((size_t)8 * sizeof(float));
    int*   pairs    = (int*)alloc((size_t)N_EDGES * sizeof(int));  // dead after CSR build

    const int* e0 = edge;
    const int* e1 = edge + N_EDGES;

    // fused prep: bucket counts | layer-1 table | x bitmask
    k_prep<<<PAIR_BLOCKS + TBL_BLOCKS + XBIT_BLOCKS, 256, 0, stream>>>(
        e1, x, embed, Ws, biases, a_srcs, a_dsts, W_out,
        blockcnt, pool_acc, xb, Tq8, Tscl, Ts1s, Ts1d, sparams);
    k_scan_bases<<<NB, 64, 0, stream>>>(blockcnt, btot);
    k_pair_scatter<<<PAIR_BLOCKS, 256, 0, stream>>>(e0, e1, xb, btot, blockcnt, pairs);
    k_csr_bucket<<<NB, 512, 0, stream>>>(pairs, btot, x, sparams, rowptr, colA, cidx);

    // layer 1: table-based aggregation (2 nodes/wave) -> bf16 hout
    k_agg1<<<(N_NODES + 7) / 8, 256, 0, stream>>>(
        Tq8, Tscl, Ts1s, Ts1d, cidx, colA, rowptr, biases + 64, hout);
    // layer 2: GEMM -> scores + z, then 8-B-gather pool
    k_gemm2<<<(N_NODES + 63) / 64, 256, 0, stream>>>(
        (const unsigned*)hout, Ws + 8192, a_srcs + 128, a_dsts + 128, W_out,
        z2, s_src0, s_dst0);
    k_pool2<<<(N_NODES + 31) / 32, 256, 0, stream>>>(
        z2, colA, rowptr, s_src0, s_dst0, batch, pool_acc);
    k_head<<<1, 256, 0, stream>>>(pool_acc, batch, b_out, sparams, out);
}